// Round 1
// 3658.915 us; speedup vs baseline: 1.1580x; 1.1580x over previous
//
#include <hip/hip_runtime.h>
#include <math.h>

// ---- problem constants ----
#define BB 32
#define TT 720
#define CC 862
#define MM 4
#define LTOK 866          // C + M tokens
#define DD 512
#define HH 8
#define EE 64
#define FFD 2048
#define NTOK (BB * LTOK)  // 27712 = 433*64
#define NBH (BB * HH)     // 256
#define KPAD 736          // 720 padded to mult of 32 (embedding K)
#define NPADP 768         // 720 padded to mult of 128 (proj N tiles)
#define LSPLIT 4          // attn_sums l-split
#define LCHUNK 224        // ceil(866/4) rounded to mult of 32
#define KVSPLIT 8         // attn_kv s-split
#define KVCHUNK 112       // ceil(866/8) rounded to mult of 16

typedef unsigned short ushort_t;
typedef short s8v __attribute__((ext_vector_type(8)));
typedef float f4v __attribute__((ext_vector_type(4)));

__device__ __forceinline__ float wave_sum(float v) {
    #pragma unroll
    for (int off = 32; off; off >>= 1) v += __shfl_xor(v, off, 64);
    return v;
}
__device__ __forceinline__ float b2f(ushort_t u) {
    return __uint_as_float(((unsigned int)u) << 16);
}
__device__ __forceinline__ ushort_t f2b(float f) {
    unsigned int u = __float_as_uint(f);
    u = (u + 0x7FFFu + ((u >> 16) & 1u)) >> 16;
    return (ushort_t)u;
}

// ============ RevIN stats: mean/stdev per (b,c) over T ============
__global__ __launch_bounds__(256) void revin_stats(const float* __restrict__ x_enc,
                                                   float* __restrict__ mean,
                                                   float* __restrict__ stdev) {
    int b = blockIdx.y;
    int c = blockIdx.x * 64 + (threadIdx.x & 63);
    int g = threadIdx.x >> 6;
    float s = 0.f, s2 = 0.f;
    if (c < CC) {
        for (int t = g; t < TT; t += 4) {
            float v = x_enc[((size_t)b * TT + t) * CC + c];
            s += v; s2 += v * v;
        }
    }
    __shared__ float ls[4][64], ls2[4][64];
    ls[g][threadIdx.x & 63] = s; ls2[g][threadIdx.x & 63] = s2;
    __syncthreads();
    if (g == 0 && c < CC) {
        int cx = threadIdx.x & 63;
        s = ls[0][cx] + ls[1][cx] + ls[2][cx] + ls[3][cx];
        s2 = ls2[0][cx] + ls2[1][cx] + ls2[2][cx] + ls2[3][cx];
        float mu = s / (float)TT;
        float var = s2 / (float)TT - mu * mu;
        mean[b * CC + c] = mu;
        stdev[b * CC + c] = sqrtf(var + 1e-5f);
    }
}

// ============ build tokb[B,866,736] bf16: normalized channels + marks, K-padded ============
__global__ __launch_bounds__(256) void build_tok(const float* __restrict__ x_enc,
                                                 const float* __restrict__ x_mark,
                                                 const float* __restrict__ mean,
                                                 const float* __restrict__ stdev,
                                                 const float* __restrict__ rw,
                                                 const float* __restrict__ rb,
                                                 ushort_t* __restrict__ tok) {
    int b = blockIdx.z;
    int r0 = blockIdx.x * 32, t0 = blockIdx.y * 32;
    __shared__ float tile[32][33];
    int tx = threadIdx.x & 31, ty = threadIdx.x >> 5;
    #pragma unroll
    for (int kk = 0; kk < 4; kk++) {
        int t = t0 + ty + kk * 8, r = r0 + tx;
        float v = 0.f;
        if (t < TT && r < LTOK) {
            if (r < CC) {
                float xv = x_enc[((size_t)b * TT + t) * CC + r];
                v = (xv - mean[b * CC + r]) / stdev[b * CC + r] * rw[r] + rb[r];
            } else {
                v = x_mark[((size_t)b * TT + t) * MM + (r - CC)];
            }
        }
        tile[ty + kk * 8][tx] = v;
    }
    __syncthreads();
    #pragma unroll
    for (int kk = 0; kk < 4; kk++) {
        int r = r0 + ty + kk * 8, t = t0 + tx;
        if (r < LTOK && t < KPAD)
            tok[((size_t)b * LTOK + r) * KPAD + t] = f2b(tile[tx][ty + kk * 8]);
    }
}

// ============ weight convert+transpose: W[K,N] f32 -> Wt[NP,KP] bf16 (zero-padded) ============
__global__ __launch_bounds__(256) void convT(const float* __restrict__ W,
                                             ushort_t* __restrict__ Wt,
                                             int K, int N, int KP, int NP) {
    __shared__ float tile[32][33];
    int k0 = blockIdx.x * 32, n0 = blockIdx.y * 32;
    int tx = threadIdx.x & 31, ty = threadIdx.x >> 5;
    #pragma unroll
    for (int r = 0; r < 4; r++) {
        int k = k0 + ty + r * 8, n = n0 + tx;
        tile[ty + r * 8][tx] = (k < K && n < N) ? W[(size_t)k * N + n] : 0.f;
    }
    __syncthreads();
    #pragma unroll
    for (int r = 0; r < 4; r++) {
        int n = n0 + ty + r * 8, k = k0 + tx;
        if (n < NP && k < KP)
            Wt[(size_t)n * KP + k] = f2b(tile[tx][ty + r * 8]);
    }
}

// ============ bf16 MFMA GEMM: C = act(A[M,K] @ Bt[N,K]^T + bias) ============
// 128x128 tile, BK=32, 4 waves (2x2 of 64x64), mfma_f32_16x16x32_bf16.
// ACT: 0 none, 1 gelu(exact), 2 sigmoid. OF: write f32 Cf. OB: write bf16 Cb.
#define GLL(g, l) __builtin_amdgcn_global_load_lds( \
    (const __attribute__((address_space(1))) void*)(g), \
    (__attribute__((address_space(3))) void*)(l), 16, 0, 0)

template <int ACT, bool OF, bool OB>
__global__ __launch_bounds__(256) void bgemm(const ushort_t* __restrict__ A,
                                             const ushort_t* __restrict__ Bt,
                                             const float* __restrict__ bias,
                                             float* __restrict__ Cf,
                                             ushort_t* __restrict__ Cb,
                                             int Mdim, int Kdim, int Nout) {
    __shared__ ushort_t As[128 * 32];
    __shared__ ushort_t Bs[128 * 32];
    const int tid = threadIdx.x;
    const int lane = tid & 63;
    const int wid = tid >> 6;
    const int m0 = blockIdx.y * 128;
    const int n0 = blockIdx.x * 128;
    const int wm = wid & 1, wn = wid >> 1;

    f4v acc[4][4];
    #pragma unroll
    for (int i = 0; i < 4; i++)
        #pragma unroll
        for (int j = 0; j < 4; j++)
            acc[i][j] = (f4v){0.f, 0.f, 0.f, 0.f};

    // staging: per wave, 2 instructions for A (16 rows x 32k each) + 2 for B
    const int srow = wid * 16 + (lane >> 2);
    const int skq = (lane & 3) * 8;
    int ar0 = m0 + srow;       if (ar0 > Mdim - 1) ar0 = Mdim - 1;
    int ar1 = m0 + 64 + srow;  if (ar1 > Mdim - 1) ar1 = Mdim - 1;
    const ushort_t* gA0 = A + (size_t)ar0 * Kdim + skq;
    const ushort_t* gA1 = A + (size_t)ar1 * Kdim + skq;
    const ushort_t* gB0 = Bt + (size_t)(n0 + srow) * Kdim + skq;
    const ushort_t* gB1 = Bt + (size_t)(n0 + 64 + srow) * Kdim + skq;
    ushort_t* lA0 = &As[(wid * 16) * 32];
    ushort_t* lA1 = &As[(64 + wid * 16) * 32];
    ushort_t* lB0 = &Bs[(wid * 16) * 32];
    ushort_t* lB1 = &Bs[(64 + wid * 16) * 32];

    const int lr = lane & 15;
    const int kc = (lane >> 4) * 8;

    for (int k0 = 0; k0 < Kdim; k0 += 32) {
        GLL(gA0 + k0, lA0);
        GLL(gA1 + k0, lA1);
        GLL(gB0 + k0, lB0);
        GLL(gB1 + k0, lB1);
        __syncthreads();
        s8v af[4], bf[4];
        #pragma unroll
        for (int i = 0; i < 4; i++)
            af[i] = *(const s8v*)&As[(wm * 64 + i * 16 + lr) * 32 + kc];
        #pragma unroll
        for (int j = 0; j < 4; j++)
            bf[j] = *(const s8v*)&Bs[(wn * 64 + j * 16 + lr) * 32 + kc];
        #pragma unroll
        for (int i = 0; i < 4; i++)
            #pragma unroll
            for (int j = 0; j < 4; j++)
                acc[i][j] = __builtin_amdgcn_mfma_f32_16x16x32_bf16(af[i], bf[j], acc[i][j], 0, 0, 0);
        __syncthreads();
    }

    // epilogue: C/D layout col=lane&15, row=(lane>>4)*4+reg
    const int orow = (lane >> 4) * 4;
    #pragma unroll
    for (int j = 0; j < 4; j++) {
        int col = n0 + wn * 64 + j * 16 + lr;
        bool cok = col < Nout;
        float bb = cok ? bias[col] : 0.f;
        #pragma unroll
        for (int i = 0; i < 4; i++) {
            #pragma unroll
            for (int r = 0; r < 4; r++) {
                int row = m0 + wm * 64 + i * 16 + orow + r;
                if (cok && row < Mdim) {
                    float v = acc[i][j][r] + bb;
                    if (ACT == 1) v = 0.5f * v * (1.0f + erff(v * 0.70710678118654752f));
                    if (ACT == 2) v = 1.0f / (1.0f + expf(-v));
                    size_t idx = (size_t)row * Nout + col;
                    if (OF) Cf[idx] = v;
                    if (OB) Cb[idx] = f2b(v);
                }
            }
        }
    }
}

// ============ LayerNorm over D=512: x_f32 = LN(x + res_bf16); also write bf16 copy ============
__global__ __launch_bounds__(256) void ln_kernel(float* __restrict__ x,
                                                 const ushort_t* __restrict__ res,
                                                 const float* __restrict__ w,
                                                 const float* __restrict__ bp,
                                                 ushort_t* __restrict__ xb) {
    size_t base = (size_t)blockIdx.x * DD;
    int tid = threadIdx.x;
    float v0 = x[base + tid];
    float v1 = x[base + tid + 256];
    if (res != nullptr) { v0 += b2f(res[base + tid]); v1 += b2f(res[base + tid + 256]); }
    float s = wave_sum(v0 + v1);
    float s2 = wave_sum(v0 * v0 + v1 * v1);
    __shared__ float a1[4], a2[4];
    if ((tid & 63) == 0) { a1[tid >> 6] = s; a2[tid >> 6] = s2; }
    __syncthreads();
    s = a1[0] + a1[1] + a1[2] + a1[3];
    s2 = a2[0] + a2[1] + a2[2] + a2[3];
    float mu = s * (1.0f / DD);
    float var = s2 * (1.0f / DD) - mu * mu;
    float rs = rsqrtf(var + 1e-5f);
    float o0 = (v0 - mu) * rs * w[tid] + bp[tid];
    float o1 = (v1 - mu) * rs * w[tid + 256] + bp[tid + 256];
    x[base + tid] = o0;
    x[base + tid + 256] = o1;
    xb[base + tid] = f2b(o0);
    xb[base + tid + 256] = f2b(o1);
}

// ============ attention: per (b,h) column sums over l (optionally weighted) ============
// l-split LSPLIT-way: grid (NBH, LSPLIT); writes partials [sp][NBH*64].
// Vectorized: each thread reads 8 consecutive e's (16B); lanes: e-octet = lane&7,
// l-offset = lane>>3 (8 rows/wave in flight); xor-reduce over l-offset groups.
template <bool WEIGHTED>
__global__ __launch_bounds__(256) void attn_sums(const ushort_t* __restrict__ Q,
                                                 const ushort_t* __restrict__ Kp,
                                                 const float* __restrict__ wq,
                                                 const float* __restrict__ wk,
                                                 float* __restrict__ qsumP,
                                                 float* __restrict__ ksumP) {
    int bh = blockIdx.x;
    int sp = blockIdx.y;
    int b = bh >> 3, h = bh & 7;
    int lane = threadIdx.x & 63, g = threadIdx.x >> 6;
    int eo = (lane & 7) * 8;
    int lofs = lane >> 3;
    const size_t base = ((size_t)b * LTOK) * DD + h * 64 + eo;
    float aq[8] = {}, ak[8] = {};
    int lend = sp * LCHUNK + LCHUNK; if (lend > LTOK) lend = LTOK;
    for (int l = sp * LCHUNK + g * 8 + lofs; l < lend; l += 32) {
        s8v q8 = *(const s8v*)&Q[base + (size_t)l * DD];
        s8v k8 = *(const s8v*)&Kp[base + (size_t)l * DD];
        float wqv = 1.f, wkv = 1.f;
        if (WEIGHTED) { wqv = wq[bh * LTOK + l]; wkv = wk[bh * LTOK + l]; }
        #pragma unroll
        for (int j = 0; j < 8; j++) {
            aq[j] += b2f((ushort_t)q8[j]) * wqv;
            ak[j] += b2f((ushort_t)k8[j]) * wkv;
        }
    }
    // reduce over the 8 l-offset lane groups (same e-octet)
    #pragma unroll
    for (int off = 8; off < 64; off <<= 1) {
        #pragma unroll
        for (int j = 0; j < 8; j++) {
            aq[j] += __shfl_xor(aq[j], off, 64);
            ak[j] += __shfl_xor(ak[j], off, 64);
        }
    }
    __shared__ float sqs[4][64], sks[4][64];
    if (lofs == 0) {
        #pragma unroll
        for (int j = 0; j < 8; j++) { sqs[g][eo + j] = aq[j]; sks[g][eo + j] = ak[j]; }
    }
    __syncthreads();
    if (threadIdx.x < 64) {
        int e = threadIdx.x;
        float fq = sqs[0][e] + sqs[1][e] + sqs[2][e] + sqs[3][e];
        float fk = sks[0][e] + sks[1][e] + sks[2][e] + sks[3][e];
        qsumP[((size_t)sp * NBH + bh) * 64 + e] = fq;
        ksumP[((size_t)sp * NBH + bh) * 64 + e] = fk;
    }
}

// ============ attention: per-l dot with summed vector (sums LSPLIT partials) ============
template <int MODE>
__global__ __launch_bounds__(256) void attn_dots(const ushort_t* __restrict__ Q,
                                                 const ushort_t* __restrict__ Kp,
                                                 const float* __restrict__ Sq,
                                                 const float* __restrict__ Sk,
                                                 float* __restrict__ outq,
                                                 float* __restrict__ outk) {
    int bh = blockIdx.x;
    int b = bh >> 3, h = bh & 7;
    int lane = threadIdx.x & 63, w = threadIdx.x >> 6;
    float sq = 0.f, sk = 0.f;
    #pragma unroll
    for (int sp = 0; sp < LSPLIT; sp++) {
        sq += Sq[((size_t)sp * NBH + bh) * 64 + lane];
        sk += Sk[((size_t)sp * NBH + bh) * 64 + lane];
    }
    sq += 1e-6f; sk += 1e-6f;
    const size_t base = ((size_t)b * LTOK) * DD + h * 64 + lane;
    int l0 = blockIdx.y * 64 + w * 16;
    for (int i = 0; i < 16; i++) {
        int l = l0 + i;
        if (l >= LTOK) break;
        float dq = (b2f(Q[base + (size_t)l * DD]) + 1e-6f) * sq;
        float dk = (b2f(Kp[base + (size_t)l * DD]) + 1e-6f) * sk;
        dq = wave_sum(dq);
        dk = wave_sum(dk);
        if (lane == 0) {
            if (MODE == 0) { outq[bh * LTOK + l] = 1.0f / dq; outk[bh * LTOK + l] = 1.0f / dk; }
            else { outq[bh * LTOK + l] = 1.0f / (1.0f + expf(-dq)); outk[bh * LTOK + l] = dk; }
        }
    }
}

// ============ attention: softmax over s (in place), scaled by Ls ============
__global__ __launch_bounds__(256) void attn_softmax(float* __restrict__ buf) {
    float* p = buf + (size_t)blockIdx.x * LTOK;
    int tid = threadIdx.x;
    __shared__ float red[4];
    float mx = -1e30f;
    for (int l = tid; l < LTOK; l += 256) mx = fmaxf(mx, p[l]);
    #pragma unroll
    for (int off = 32; off; off >>= 1) mx = fmaxf(mx, __shfl_xor(mx, off, 64));
    if ((tid & 63) == 0) red[tid >> 6] = mx;
    __syncthreads();
    mx = fmaxf(fmaxf(red[0], red[1]), fmaxf(red[2], red[3]));
    __syncthreads();
    float s = 0.f;
    for (int l = tid; l < LTOK; l += 256) s += expf(p[l] - mx);
    s = wave_sum(s);
    if ((tid & 63) == 0) red[tid >> 6] = s;
    __syncthreads();
    s = red[0] + red[1] + red[2] + red[3];
    float scale = (float)LTOK / s;
    for (int l = tid; l < LTOK; l += 256) p[l] = expf(p[l] - mx) * scale;
}

// ============ attention: kv[e,d] = sum_s k[s,e] * v[s,d] * ncref[s] ============
// s-split KVSPLIT-way: grid (NBH, KVSPLIT), partials to kvpart[sp][bh][4096].
// Vectorized staging: waves 0-1 stage K (16B/lane), waves 2-3 stage V*ncref.
__global__ __launch_bounds__(256) void attn_kv_part(const ushort_t* __restrict__ Kp,
                                                    const ushort_t* __restrict__ V,
                                                    const float* __restrict__ ncref,
                                                    float* __restrict__ kvpart) {
    int bh = blockIdx.x;
    int sp = blockIdx.y;
    int b = bh >> 3, h = bh & 7;
    int d = threadIdx.x & 63, eg = threadIdx.x >> 6;
    __shared__ float ks[16][64], vs[16][64];
    float acc[16] = {};
    const size_t base = ((size_t)b * LTOK) * DD + h * 64;
    const int s_begin = sp * KVCHUNK;
    int s_end = s_begin + KVCHUNK; if (s_end > LTOK) s_end = LTOK;

    const bool isV = threadIdx.x >= 128;       // wave-uniform split
    const int slot = threadIdx.x & 127;        // 16 rows x 8 vec-slots
    const int srow = slot >> 3;
    const int e0 = (slot & 7) * 8;
    const ushort_t* src = isV ? V : Kp;

    for (int s0 = s_begin; s0 < s_end; s0 += 16) {
        __syncthreads();
        int s = s0 + srow;
        float vals[8] = {};
        if (s < s_end) {
            s8v raw = *(const s8v*)&src[base + (size_t)s * DD + e0];
            float mul = isV ? ncref[bh * LTOK + s] : 1.f;
            #pragma unroll
            for (int j = 0; j < 8; j++) vals[j] = b2f((ushort_t)raw[j]) * mul;
        }
        float (*dst)[64] = isV ? vs : ks;
        #pragma unroll
        for (int j = 0; j < 8; j++) dst[srow][e0 + j] = vals[j];
        __syncthreads();
        int nsi = s_end - s0; if (nsi > 16) nsi = 16;
        for (int si = 0; si < nsi; si++) {
            float vv = vs[si][d];
            #pragma unroll
            for (int i = 0; i < 16; i++) acc[i] += ks[si][eg * 16 + i] * vv;
        }
    }
    #pragma unroll
    for (int i = 0; i < 16; i++)
        kvpart[((size_t)sp * NBH + bh) * 4096 + (eg * 16 + i) * 64 + d] = acc[i];
}

// ============ reduce kv partials: kvbuf = sum_sp kvpart[sp] ============
__global__ __launch_bounds__(256) void kv_reduce(const float* __restrict__ part,
                                                 float* __restrict__ kvout) {
    size_t idx = (size_t)blockIdx.x * 256 + threadIdx.x;   // NBH*4096 total
    float s = 0.f;
    #pragma unroll
    for (int sp = 0; sp < KVSPLIT; sp++)
        s += part[(size_t)sp * ((size_t)NBH * 4096) + idx];
    kvout[idx] = s;
}

// ============ attention: out[l,d] = dot(q[l,:], kv[:,d]) * nr[l]*nrref[l], bf16 out ============
__global__ __launch_bounds__(256) void attn_out(const ushort_t* __restrict__ Q,
                                                const float* __restrict__ kv,
                                                const float* __restrict__ nr,
                                                const float* __restrict__ nrref,
                                                ushort_t* __restrict__ out) {
    int bh = blockIdx.x;
    int b = bh >> 3, h = bh & 7;
    int d = threadIdx.x & 63, lg = threadIdx.x >> 6;
    __shared__ float kvs[64][64];
    __shared__ float qs[64][64];
    #pragma unroll
    for (int j = 0; j < 16; j++) {
        int idx = threadIdx.x + j * 256;
        kvs[idx >> 6][idx & 63] = kv[(size_t)bh * 4096 + idx];
    }
    int l0 = blockIdx.y * 64;
    const size_t base = ((size_t)b * LTOK) * DD + h * 64;
    for (int j = 0; j < 16; j++) {
        int idx = threadIdx.x + j * 256;
        int lr = idx >> 6, e = idx & 63;
        int l = l0 + lr;
        qs[lr][e] = (l < LTOK) ? b2f(Q[base + (size_t)l * DD + e]) : 0.f;
    }
    __syncthreads();
    for (int i = 0; i < 16; i++) {
        int lr = lg * 16 + i;
        int l = l0 + lr;
        if (l >= LTOK) continue;
        float acc = 0.f;
        #pragma unroll
        for (int e = 0; e < 64; e++) acc += qs[lr][e] * kvs[e][d];
        float sc = nr[bh * LTOK + l] * nrref[bh * LTOK + l];
        out[base + (size_t)l * DD + d] = f2b(acc * sc);
    }
}

// ============ final: transpose from projb[NTOK,720] bf16, RevIN denorm ============
__global__ __launch_bounds__(256) void final_out(const ushort_t* __restrict__ p,
                                                 const float* __restrict__ mean,
                                                 const float* __restrict__ stdev,
                                                 const float* __restrict__ rw,
                                                 const float* __restrict__ rb,
                                                 float* __restrict__ out) {
    int b = blockIdx.z;
    int c0 = blockIdx.x * 32, t0 = blockIdx.y * 32;
    __shared__ float tile[32][33];
    int tx = threadIdx.x & 31, ty = threadIdx.x >> 5;
    #pragma unroll
    for (int kk = 0; kk < 4; kk++) {
        int c = c0 + ty + kk * 8, t = t0 + tx;
        float v = 0.f;
        if (c < CC && t < TT) v = b2f(p[((size_t)b * LTOK + c) * TT + t]);
        tile[ty + kk * 8][tx] = v;
    }
    __syncthreads();
    #pragma unroll
    for (int kk = 0; kk < 4; kk++) {
        int t = t0 + ty + kk * 8, c = c0 + tx;
        if (c < CC && t < TT) {
            float v = tile[tx][ty + kk * 8];
            v = (v - rb[c]) / (rw[c] + 1e-10f);
            v = v * stdev[b * CC + c] + mean[b * CC + c];
            out[((size_t)b * TT + t) * CC + c] = v;
        }
    }
}

extern "C" void kernel_launch(void* const* d_in, const int* in_sizes, int n_in,
                              void* d_out, int out_size, void* d_ws, size_t ws_size,
                              hipStream_t stream) {
    (void)in_sizes; (void)n_in; (void)out_size; (void)ws_size;
    const float* x_enc   = (const float*)d_in[0];
    const float* x_mark  = (const float*)d_in[1];
    const float* revin_w = (const float*)d_in[4];
    const float* revin_b = (const float*)d_in[5];
    const float* emb_W   = (const float*)d_in[6];
    const float* emb_b   = (const float*)d_in[7];
    const float* Wq = (const float*)d_in[8];
    const float* bq = (const float*)d_in[9];
    const float* Wk = (const float*)d_in[10];
    const float* bk = (const float*)d_in[11];
    const float* Wv = (const float*)d_in[12];
    const float* bv = (const float*)d_in[13];
    const float* Wo = (const float*)d_in[14];
    const float* bo = (const float*)d_in[15];
    const float* ff1_W = (const float*)d_in[16];
    const float* ff1_b = (const float*)d_in[17];
    const float* ff2_W = (const float*)d_in[18];
    const float* ff2_b = (const float*)d_in[19];
    const float* ln1_w = (const float*)d_in[20];
    const float* ln1_b = (const float*)d_in[21];
    const float* ln2_w = (const float*)d_in[22];
    const float* ln2_b = (const float*)d_in[23];
    const float* lnf_w = (const float*)d_in[24];
    const float* lnf_b = (const float*)d_in[25];
    const float* proj_W = (const float*)d_in[26];
    const float* proj_b = (const float*)d_in[27];
    float* out = (float*)d_out;

    // ---- workspace layout (~242 MB; kv partials alias the dead U buffer) ----
    char* wsb = (char*)d_ws;
    size_t off = 0;
    auto alloc = [&](size_t bytes) {
        off = (off + 63) & ~(size_t)63;
        void* p = wsb + off; off += bytes; return p;
    };
    float* mean  = (float*)alloc((size_t)BB * CC * 4);
    float* stdev = (float*)alloc((size_t)BB * CC * 4);
    float* qsumP  = (float*)alloc((size_t)LSPLIT * NBH * 64 * 4);
    float* ksumP  = (float*)alloc((size_t)LSPLIT * NBH * 64 * 4);
    float* qnsumP = (float*)alloc((size_t)LSPLIT * NBH * 64 * 4);
    float* knsumP = (float*)alloc((size_t)LSPLIT * NBH * 64 * 4);
    float* nr    = (float*)alloc((size_t)NBH * LTOK * 4);
    float* nc    = (float*)alloc((size_t)NBH * LTOK * 4);
    float* nrref = (float*)alloc((size_t)NBH * LTOK * 4);
    float* ncref = (float*)alloc((size_t)NBH * LTOK * 4);
    float* kvbuf = (float*)alloc((size_t)NBH * 4096 * 4);
    float* x     = (float*)alloc((size_t)NTOK * DD * 4);         // fp32 residual spine
    ushort_t* xb = (ushort_t*)alloc((size_t)NTOK * DD * 2);      // bf16 copy of x
    ushort_t* qb = (ushort_t*)alloc((size_t)NTOK * DD * 2);      // also Wo/FF2 output (tmpb)
    ushort_t* kb = (ushort_t*)alloc((size_t)NTOK * DD * 2);
    ushort_t* vb = (ushort_t*)alloc((size_t)NTOK * DD * 2);      // also attention output
    ushort_t* wbuf = (ushort_t*)alloc((size_t)10207232 * 2);     // all bf16 transposed weights
    ushort_t* U  = (ushort_t*)alloc((size_t)NTOK * KPAD * 2);    // union: tokb / ff-chunk / projb / kvpart

    // weight sub-buffers
    ushort_t* embT = wbuf;                          // [512,736]
    ushort_t* qT   = embT + (size_t)512 * KPAD;     // 3 x [512,512]
    ushort_t* kT   = qT + 3 * 262144;
    ushort_t* vT   = kT + 3 * 262144;
    ushort_t* oT   = vT + 3 * 262144;
    ushort_t* f1T  = oT + 3 * 262144;               // 3 x [2048,512]
    ushort_t* f2T  = f1T + (size_t)3 * 1048576;     // 3 x [512,2048]
    ushort_t* pT   = f2T + (size_t)3 * 1048576;     // [768,512]
    ushort_t* tokb  = U;                             // [NTOK, 736]
    ushort_t* ffb   = U;                             // chunk [6912, 2048]
    ushort_t* projb = U;                             // [NTOK, 720]
    float* kvpart   = (float*)U;                     // [KVSPLIT, NBH, 4096] = 33.5MB <= 40.8MB
    ushort_t* tmpb  = qb;                            // Wo/FF2 output

    dim3 blk(256);
    // ---- weight conversion (transpose to [N,K] bf16) ----
    auto cvt = [&](const float* W, ushort_t* Wt, int K, int N, int KP, int NP) {
        convT<<<dim3((KP + 31) / 32, (NP + 31) / 32), blk, 0, stream>>>(W, Wt, K, N, KP, NP);
    };
    cvt(emb_W, embT, TT, DD, KPAD, DD);
    for (int l = 0; l < 3; l++) {
        cvt(Wq + (size_t)l * DD * DD, qT + (size_t)l * 262144, DD, DD, DD, DD);
        cvt(Wk + (size_t)l * DD * DD, kT + (size_t)l * 262144, DD, DD, DD, DD);
        cvt(Wv + (size_t)l * DD * DD, vT + (size_t)l * 262144, DD, DD, DD, DD);
        cvt(Wo + (size_t)l * DD * DD, oT + (size_t)l * 262144, DD, DD, DD, DD);
        cvt(ff1_W + (size_t)l * DD * FFD, f1T + (size_t)l * 1048576, DD, FFD, DD, FFD);
        cvt(ff2_W + (size_t)l * FFD * DD, f2T + (size_t)l * 1048576, FFD, DD, FFD, DD);
    }
    cvt(proj_W, pT, DD, TT, DD, NPADP);

    // ---- RevIN + tokens + embedding ----
    revin_stats<<<dim3((CC + 63) / 64, BB), blk, 0, stream>>>(x_enc, mean, stdev);
    build_tok<<<dim3((LTOK + 31) / 32, (KPAD + 31) / 32, BB), blk, 0, stream>>>(
        x_enc, x_mark, mean, stdev, revin_w, revin_b, tokb);
    const int MT = (NTOK + 127) / 128;   // 217
    bgemm<0, true, true><<<dim3(DD / 128, MT), blk, 0, stream>>>(
        tokb, embT, emb_b, x, xb, NTOK, KPAD, DD);

    int ltiles = (LTOK + 63) / 64;
    for (int l = 0; l < 3; l++) {
        bgemm<2, false, true><<<dim3(DD / 128, MT), blk, 0, stream>>>(
            xb, qT + (size_t)l * 262144, bq + l * DD, nullptr, qb, NTOK, DD, DD);
        bgemm<2, false, true><<<dim3(DD / 128, MT), blk, 0, stream>>>(
            xb, kT + (size_t)l * 262144, bk + l * DD, nullptr, kb, NTOK, DD, DD);
        bgemm<0, false, true><<<dim3(DD / 128, MT), blk, 0, stream>>>(
            xb, vT + (size_t)l * 262144, bv + l * DD, nullptr, vb, NTOK, DD, DD);
        attn_sums<false><<<dim3(NBH, LSPLIT), blk, 0, stream>>>(
            qb, kb, nullptr, nullptr, qsumP, ksumP);
        attn_dots<0><<<dim3(NBH, ltiles), blk, 0, stream>>>(qb, kb, ksumP, qsumP, nr, nc);
        attn_sums<true><<<dim3(NBH, LSPLIT), blk, 0, stream>>>(
            qb, kb, nr, nc, qnsumP, knsumP);
        attn_dots<1><<<dim3(NBH, ltiles), blk, 0, stream>>>(qb, kb, knsumP, qnsumP, nrref, ncref);
        attn_softmax<<<NBH, blk, 0, stream>>>(ncref);
        attn_kv_part<<<dim3(NBH, KVSPLIT), blk, 0, stream>>>(kb, vb, ncref, kvpart);
        kv_reduce<<<dim3((NBH * 4096) / 256), blk, 0, stream>>>(kvpart, kvbuf);
        attn_out<<<dim3(NBH, ltiles), blk, 0, stream>>>(qb, kvbuf, nr, nrref, vb);
        // Wo: A = attention output (vb), out -> tmpb (qb, dead)
        bgemm<0, false, true><<<dim3(DD / 128, MT), blk, 0, stream>>>(
            vb, oT + (size_t)l * 262144, bo + l * DD, nullptr, tmpb, NTOK, DD, DD);
        ln_kernel<<<NTOK, blk, 0, stream>>>(x, tmpb, ln1_w + l * DD, ln1_b + l * DD, xb);
        // FF chunked over rows (ff activation fits in U)
        for (int t0 = 0; t0 < NTOK / 64; t0 += 108) {
            int nt = NTOK / 64 - t0; if (nt > 108) nt = 108;
            int rs = t0 * 64, mc = nt * 64;
            bgemm<1, false, true><<<dim3(FFD / 128, (mc + 127) / 128), blk, 0, stream>>>(
                xb + (size_t)rs * DD, f1T + (size_t)l * 1048576, ff1_b + l * FFD,
                nullptr, ffb, mc, DD, FFD);
            bgemm<0, false, true><<<dim3(DD / 128, (mc + 127) / 128), blk, 0, stream>>>(
                ffb, f2T + (size_t)l * 1048576, ff2_b + l * DD,
                nullptr, tmpb + (size_t)rs * DD, mc, FFD, DD);
        }
        ln_kernel<<<NTOK, blk, 0, stream>>>(x, tmpb, ln2_w + l * DD, ln2_b + l * DD, xb);
    }
    ln_kernel<<<NTOK, blk, 0, stream>>>(x, nullptr, lnf_w, lnf_b, xb);
    // projection: [NTOK,512] @ [512,768(pad)] -> projb [NTOK,720] bf16
    bgemm<0, false, true><<<dim3(NPADP / 128, MT), blk, 0, stream>>>(
        xb, pT, proj_b, nullptr, projb, NTOK, DD, TT);
    final_out<<<dim3((CC + 31) / 32, (TT + 31) / 32, BB), blk, 0, stream>>>(
        projb, mean, stdev, revin_w, revin_b, out);
}

// Round 2
// 3506.493 us; speedup vs baseline: 1.2084x; 1.0435x over previous
//
#include <hip/hip_runtime.h>
#include <math.h>

// ---- problem constants ----
#define BB 32
#define TT 720
#define CC 862
#define MM 4
#define LTOK 866          // C + M tokens
#define DD 512
#define HH 8
#define EE 64
#define FFD 2048
#define NTOK (BB * LTOK)  // 27712 = 433*64
#define NBH (BB * HH)     // 256
#define KPAD 736          // 720 padded to mult of 32 (embedding K)
#define NPADP 768         // 720 padded to mult of 128 (proj N tiles)
#define LSPLIT 4          // attn_sums l-split
#define LCHUNK 224        // ceil(866/4) rounded to mult of 32
#define KVSPLIT 8         // attn_kv s-split
#define KVCHUNK 112       // ceil(866/8) rounded to mult of 16

typedef unsigned short ushort_t;
typedef short s8v __attribute__((ext_vector_type(8)));
typedef float f4v __attribute__((ext_vector_type(4)));

__device__ __forceinline__ float wave_sum(float v) {
    #pragma unroll
    for (int off = 32; off; off >>= 1) v += __shfl_xor(v, off, 64);
    return v;
}
__device__ __forceinline__ float b2f(ushort_t u) {
    return __uint_as_float(((unsigned int)u) << 16);
}
__device__ __forceinline__ ushort_t f2b(float f) {
    unsigned int u = __float_as_uint(f);
    u = (u + 0x7FFFu + ((u >> 16) & 1u)) >> 16;
    return (ushort_t)u;
}

// ============ RevIN stats: mean/stdev per (b,c) over T ============
__global__ __launch_bounds__(256) void revin_stats(const float* __restrict__ x_enc,
                                                   float* __restrict__ mean,
                                                   float* __restrict__ stdev) {
    int b = blockIdx.y;
    int c = blockIdx.x * 64 + (threadIdx.x & 63);
    int g = threadIdx.x >> 6;
    float s = 0.f, s2 = 0.f;
    if (c < CC) {
        for (int t = g; t < TT; t += 4) {
            float v = x_enc[((size_t)b * TT + t) * CC + c];
            s += v; s2 += v * v;
        }
    }
    __shared__ float ls[4][64], ls2[4][64];
    ls[g][threadIdx.x & 63] = s; ls2[g][threadIdx.x & 63] = s2;
    __syncthreads();
    if (g == 0 && c < CC) {
        int cx = threadIdx.x & 63;
        s = ls[0][cx] + ls[1][cx] + ls[2][cx] + ls[3][cx];
        s2 = ls2[0][cx] + ls2[1][cx] + ls2[2][cx] + ls2[3][cx];
        float mu = s / (float)TT;
        float var = s2 / (float)TT - mu * mu;
        mean[b * CC + c] = mu;
        stdev[b * CC + c] = sqrtf(var + 1e-5f);
    }
}

// ============ build tokb[B,866,736] bf16: normalized channels + marks, K-padded ============
__global__ __launch_bounds__(256) void build_tok(const float* __restrict__ x_enc,
                                                 const float* __restrict__ x_mark,
                                                 const float* __restrict__ mean,
                                                 const float* __restrict__ stdev,
                                                 const float* __restrict__ rw,
                                                 const float* __restrict__ rb,
                                                 ushort_t* __restrict__ tok) {
    int b = blockIdx.z;
    int r0 = blockIdx.x * 32, t0 = blockIdx.y * 32;
    __shared__ float tile[32][33];
    int tx = threadIdx.x & 31, ty = threadIdx.x >> 5;
    #pragma unroll
    for (int kk = 0; kk < 4; kk++) {
        int t = t0 + ty + kk * 8, r = r0 + tx;
        float v = 0.f;
        if (t < TT && r < LTOK) {
            if (r < CC) {
                float xv = x_enc[((size_t)b * TT + t) * CC + r];
                v = (xv - mean[b * CC + r]) / stdev[b * CC + r] * rw[r] + rb[r];
            } else {
                v = x_mark[((size_t)b * TT + t) * MM + (r - CC)];
            }
        }
        tile[ty + kk * 8][tx] = v;
    }
    __syncthreads();
    #pragma unroll
    for (int kk = 0; kk < 4; kk++) {
        int r = r0 + ty + kk * 8, t = t0 + tx;
        if (r < LTOK && t < KPAD)
            tok[((size_t)b * LTOK + r) * KPAD + t] = f2b(tile[tx][ty + kk * 8]);
    }
}

// ============ weight convert+transpose: W[K,N] f32 -> Wt[NP,KP] bf16 (zero-padded) ============
__global__ __launch_bounds__(256) void convT(const float* __restrict__ W,
                                             ushort_t* __restrict__ Wt,
                                             int K, int N, int KP, int NP) {
    __shared__ float tile[32][33];
    int k0 = blockIdx.x * 32, n0 = blockIdx.y * 32;
    int tx = threadIdx.x & 31, ty = threadIdx.x >> 5;
    #pragma unroll
    for (int r = 0; r < 4; r++) {
        int k = k0 + ty + r * 8, n = n0 + tx;
        tile[ty + r * 8][tx] = (k < K && n < N) ? W[(size_t)k * N + n] : 0.f;
    }
    __syncthreads();
    #pragma unroll
    for (int r = 0; r < 4; r++) {
        int n = n0 + ty + r * 8, k = k0 + tx;
        if (n < NP && k < KP)
            Wt[(size_t)n * KP + k] = f2b(tile[tx][ty + r * 8]);
    }
}

// ============ bf16 MFMA GEMM: C = act(A[M,K] @ Bt[N,K]^T + bias) ============
// 128x128 tile, BK=32, 4 waves (2x2 of 64x64), mfma_f32_16x16x32_bf16.
// ACT: 0 none, 1 gelu(exact), 2 sigmoid. OF: write f32 Cf. OB: write bf16 Cb.
#define GLL(g, l) __builtin_amdgcn_global_load_lds( \
    (const __attribute__((address_space(1))) void*)(g), \
    (__attribute__((address_space(3))) void*)(l), 16, 0, 0)

template <int ACT, bool OF, bool OB>
__global__ __launch_bounds__(256) void bgemm(const ushort_t* __restrict__ A,
                                             const ushort_t* __restrict__ Bt,
                                             const float* __restrict__ bias,
                                             float* __restrict__ Cf,
                                             ushort_t* __restrict__ Cb,
                                             int Mdim, int Kdim, int Nout) {
    __shared__ ushort_t As[128 * 32];
    __shared__ ushort_t Bs[128 * 32];
    const int tid = threadIdx.x;
    const int lane = tid & 63;
    const int wid = tid >> 6;
    const int m0 = blockIdx.y * 128;
    const int n0 = blockIdx.x * 128;
    const int wm = wid & 1, wn = wid >> 1;

    f4v acc[4][4];
    #pragma unroll
    for (int i = 0; i < 4; i++)
        #pragma unroll
        for (int j = 0; j < 4; j++)
            acc[i][j] = (f4v){0.f, 0.f, 0.f, 0.f};

    // staging: per wave, 2 instructions for A (16 rows x 32k each) + 2 for B
    const int srow = wid * 16 + (lane >> 2);
    const int skq = (lane & 3) * 8;
    int ar0 = m0 + srow;       if (ar0 > Mdim - 1) ar0 = Mdim - 1;
    int ar1 = m0 + 64 + srow;  if (ar1 > Mdim - 1) ar1 = Mdim - 1;
    const ushort_t* gA0 = A + (size_t)ar0 * Kdim + skq;
    const ushort_t* gA1 = A + (size_t)ar1 * Kdim + skq;
    const ushort_t* gB0 = Bt + (size_t)(n0 + srow) * Kdim + skq;
    const ushort_t* gB1 = Bt + (size_t)(n0 + 64 + srow) * Kdim + skq;
    ushort_t* lA0 = &As[(wid * 16) * 32];
    ushort_t* lA1 = &As[(64 + wid * 16) * 32];
    ushort_t* lB0 = &Bs[(wid * 16) * 32];
    ushort_t* lB1 = &Bs[(64 + wid * 16) * 32];

    const int lr = lane & 15;
    const int kc = (lane >> 4) * 8;

    for (int k0 = 0; k0 < Kdim; k0 += 32) {
        GLL(gA0 + k0, lA0);
        GLL(gA1 + k0, lA1);
        GLL(gB0 + k0, lB0);
        GLL(gB1 + k0, lB1);
        __syncthreads();
        s8v af[4], bf[4];
        #pragma unroll
        for (int i = 0; i < 4; i++)
            af[i] = *(const s8v*)&As[(wm * 64 + i * 16 + lr) * 32 + kc];
        #pragma unroll
        for (int j = 0; j < 4; j++)
            bf[j] = *(const s8v*)&Bs[(wn * 64 + j * 16 + lr) * 32 + kc];
        #pragma unroll
        for (int i = 0; i < 4; i++)
            #pragma unroll
            for (int j = 0; j < 4; j++)
                acc[i][j] = __builtin_amdgcn_mfma_f32_16x16x32_bf16(af[i], bf[j], acc[i][j], 0, 0, 0);
        __syncthreads();
    }

    // epilogue: C/D layout col=lane&15, row=(lane>>4)*4+reg
    const int orow = (lane >> 4) * 4;
    #pragma unroll
    for (int j = 0; j < 4; j++) {
        int col = n0 + wn * 64 + j * 16 + lr;
        bool cok = col < Nout;
        float bb = cok ? bias[col] : 0.f;
        #pragma unroll
        for (int i = 0; i < 4; i++) {
            #pragma unroll
            for (int r = 0; r < 4; r++) {
                int row = m0 + wm * 64 + i * 16 + orow + r;
                if (cok && row < Mdim) {
                    float v = acc[i][j][r] + bb;
                    if (ACT == 1) v = 0.5f * v * (1.0f + erff(v * 0.70710678118654752f));
                    if (ACT == 2) v = 1.0f / (1.0f + expf(-v));
                    size_t idx = (size_t)row * Nout + col;
                    if (OF) Cf[idx] = v;
                    if (OB) Cb[idx] = f2b(v);
                }
            }
        }
    }
}

// ============ LayerNorm over D=512: x_f32 = LN(x + res_bf16); also write bf16 copy ============
__global__ __launch_bounds__(256) void ln_kernel(float* __restrict__ x,
                                                 const ushort_t* __restrict__ res,
                                                 const float* __restrict__ w,
                                                 const float* __restrict__ bp,
                                                 ushort_t* __restrict__ xb) {
    size_t base = (size_t)blockIdx.x * DD;
    int tid = threadIdx.x;
    float v0 = x[base + tid];
    float v1 = x[base + tid + 256];
    if (res != nullptr) { v0 += b2f(res[base + tid]); v1 += b2f(res[base + tid + 256]); }
    float s = wave_sum(v0 + v1);
    float s2 = wave_sum(v0 * v0 + v1 * v1);
    __shared__ float a1[4], a2[4];
    if ((tid & 63) == 0) { a1[tid >> 6] = s; a2[tid >> 6] = s2; }
    __syncthreads();
    s = a1[0] + a1[1] + a1[2] + a1[3];
    s2 = a2[0] + a2[1] + a2[2] + a2[3];
    float mu = s * (1.0f / DD);
    float var = s2 * (1.0f / DD) - mu * mu;
    float rs = rsqrtf(var + 1e-5f);
    float o0 = (v0 - mu) * rs * w[tid] + bp[tid];
    float o1 = (v1 - mu) * rs * w[tid + 256] + bp[tid + 256];
    x[base + tid] = o0;
    x[base + tid + 256] = o1;
    xb[base + tid] = f2b(o0);
    xb[base + tid + 256] = f2b(o1);
}

// ============ attention: per (b,h) column sums over l (optionally weighted) ============
// l-split LSPLIT-way: grid (NBH, LSPLIT); writes partials [sp][NBH*64].
template <bool WEIGHTED>
__global__ __launch_bounds__(256) void attn_sums(const ushort_t* __restrict__ Q,
                                                 const ushort_t* __restrict__ Kp,
                                                 const float* __restrict__ wq,
                                                 const float* __restrict__ wk,
                                                 float* __restrict__ qsumP,
                                                 float* __restrict__ ksumP) {
    int bh = blockIdx.x;
    int sp = blockIdx.y;
    int b = bh >> 3, h = bh & 7;
    int lane = threadIdx.x & 63, g = threadIdx.x >> 6;
    int eo = (lane & 7) * 8;
    int lofs = lane >> 3;
    const size_t base = ((size_t)b * LTOK) * DD + h * 64 + eo;
    float aq[8] = {}, ak[8] = {};
    int lend = sp * LCHUNK + LCHUNK; if (lend > LTOK) lend = LTOK;
    for (int l = sp * LCHUNK + g * 8 + lofs; l < lend; l += 32) {
        s8v q8 = *(const s8v*)&Q[base + (size_t)l * DD];
        s8v k8 = *(const s8v*)&Kp[base + (size_t)l * DD];
        float wqv = 1.f, wkv = 1.f;
        if (WEIGHTED) { wqv = wq[bh * LTOK + l]; wkv = wk[bh * LTOK + l]; }
        #pragma unroll
        for (int j = 0; j < 8; j++) {
            aq[j] += b2f((ushort_t)q8[j]) * wqv;
            ak[j] += b2f((ushort_t)k8[j]) * wkv;
        }
    }
    // reduce over the 8 l-offset lane groups (same e-octet)
    #pragma unroll
    for (int off = 8; off < 64; off <<= 1) {
        #pragma unroll
        for (int j = 0; j < 8; j++) {
            aq[j] += __shfl_xor(aq[j], off, 64);
            ak[j] += __shfl_xor(ak[j], off, 64);
        }
    }
    __shared__ float sqs[4][64], sks[4][64];
    if (lofs == 0) {
        #pragma unroll
        for (int j = 0; j < 8; j++) { sqs[g][eo + j] = aq[j]; sks[g][eo + j] = ak[j]; }
    }
    __syncthreads();
    if (threadIdx.x < 64) {
        int e = threadIdx.x;
        float fq = sqs[0][e] + sqs[1][e] + sqs[2][e] + sqs[3][e];
        float fk = sks[0][e] + sks[1][e] + sks[2][e] + sks[3][e];
        qsumP[((size_t)sp * NBH + bh) * 64 + e] = fq;
        ksumP[((size_t)sp * NBH + bh) * 64 + e] = fk;
    }
}

// ============ attention: per-l dot with summed vector (sums LSPLIT partials) ============
template <int MODE>
__global__ __launch_bounds__(256) void attn_dots(const ushort_t* __restrict__ Q,
                                                 const ushort_t* __restrict__ Kp,
                                                 const float* __restrict__ Sq,
                                                 const float* __restrict__ Sk,
                                                 float* __restrict__ outq,
                                                 float* __restrict__ outk) {
    int bh = blockIdx.x;
    int b = bh >> 3, h = bh & 7;
    int lane = threadIdx.x & 63, w = threadIdx.x >> 6;
    float sq = 0.f, sk = 0.f;
    #pragma unroll
    for (int sp = 0; sp < LSPLIT; sp++) {
        sq += Sq[((size_t)sp * NBH + bh) * 64 + lane];
        sk += Sk[((size_t)sp * NBH + bh) * 64 + lane];
    }
    sq += 1e-6f; sk += 1e-6f;
    const size_t base = ((size_t)b * LTOK) * DD + h * 64 + lane;
    int l0 = blockIdx.y * 64 + w * 16;
    for (int i = 0; i < 16; i++) {
        int l = l0 + i;
        if (l >= LTOK) break;
        float dq = (b2f(Q[base + (size_t)l * DD]) + 1e-6f) * sq;
        float dk = (b2f(Kp[base + (size_t)l * DD]) + 1e-6f) * sk;
        dq = wave_sum(dq);
        dk = wave_sum(dk);
        if (lane == 0) {
            if (MODE == 0) { outq[bh * LTOK + l] = 1.0f / dq; outk[bh * LTOK + l] = 1.0f / dk; }
            else { outq[bh * LTOK + l] = 1.0f / (1.0f + expf(-dq)); outk[bh * LTOK + l] = dk; }
        }
    }
}

// ============ attention: softmax over s (in place), scaled by Ls ============
__global__ __launch_bounds__(256) void attn_softmax(float* __restrict__ buf) {
    float* p = buf + (size_t)blockIdx.x * LTOK;
    int tid = threadIdx.x;
    __shared__ float red[4];
    float mx = -1e30f;
    for (int l = tid; l < LTOK; l += 256) mx = fmaxf(mx, p[l]);
    #pragma unroll
    for (int off = 32; off; off >>= 1) mx = fmaxf(mx, __shfl_xor(mx, off, 64));
    if ((tid & 63) == 0) red[tid >> 6] = mx;
    __syncthreads();
    mx = fmaxf(fmaxf(red[0], red[1]), fmaxf(red[2], red[3]));
    __syncthreads();
    float s = 0.f;
    for (int l = tid; l < LTOK; l += 256) s += expf(p[l] - mx);
    s = wave_sum(s);
    if ((tid & 63) == 0) red[tid >> 6] = s;
    __syncthreads();
    s = red[0] + red[1] + red[2] + red[3];
    float scale = (float)LTOK / s;
    for (int l = tid; l < LTOK; l += 256) p[l] = expf(p[l] - mx) * scale;
}

// ============ attention: kv[e,d] = sum_s k[s,e] * v[s,d] * ncref[s] ============
// s-split KVSPLIT-way: grid (NBH, KVSPLIT), partials to kvpart[sp][bh][4096].
__global__ __launch_bounds__(256) void attn_kv_part(const ushort_t* __restrict__ Kp,
                                                    const ushort_t* __restrict__ V,
                                                    const float* __restrict__ ncref,
                                                    float* __restrict__ kvpart) {
    int bh = blockIdx.x;
    int sp = blockIdx.y;
    int b = bh >> 3, h = bh & 7;
    int d = threadIdx.x & 63, eg = threadIdx.x >> 6;
    __shared__ float ks[16][64], vs[16][64];
    float acc[16] = {};
    const size_t base = ((size_t)b * LTOK) * DD + h * 64;
    const int s_begin = sp * KVCHUNK;
    int s_end = s_begin + KVCHUNK; if (s_end > LTOK) s_end = LTOK;

    const bool isV = threadIdx.x >= 128;       // wave-uniform split
    const int slot = threadIdx.x & 127;        // 16 rows x 8 vec-slots
    const int srow = slot >> 3;
    const int e0 = (slot & 7) * 8;
    const ushort_t* src = isV ? V : Kp;

    for (int s0 = s_begin; s0 < s_end; s0 += 16) {
        __syncthreads();
        int s = s0 + srow;
        float vals[8] = {};
        if (s < s_end) {
            s8v raw = *(const s8v*)&src[base + (size_t)s * DD + e0];
            float mul = isV ? ncref[bh * LTOK + s] : 1.f;
            #pragma unroll
            for (int j = 0; j < 8; j++) vals[j] = b2f((ushort_t)raw[j]) * mul;
        }
        float (*dst)[64] = isV ? vs : ks;
        #pragma unroll
        for (int j = 0; j < 8; j++) dst[srow][e0 + j] = vals[j];
        __syncthreads();
        int nsi = s_end - s0; if (nsi > 16) nsi = 16;
        for (int si = 0; si < nsi; si++) {
            float vv = vs[si][d];
            #pragma unroll
            for (int i = 0; i < 16; i++) acc[i] += ks[si][eg * 16 + i] * vv;
        }
    }
    #pragma unroll
    for (int i = 0; i < 16; i++)
        kvpart[((size_t)sp * NBH + bh) * 4096 + (eg * 16 + i) * 64 + d] = acc[i];
}

// ============ reduce kv partials -> kvT bf16: kvtb[bh][d][e] = sum_sp part[sp][bh][e*64+d] ============
__global__ __launch_bounds__(256) void kv_reduce(const float* __restrict__ part,
                                                 ushort_t* __restrict__ kvtb) {
    size_t idx = (size_t)blockIdx.x * 256 + threadIdx.x;   // NBH*4096 total, idx = bh*4096 + e*64 + d
    float s = 0.f;
    #pragma unroll
    for (int sp = 0; sp < KVSPLIT; sp++)
        s += part[(size_t)sp * ((size_t)NBH * 4096) + idx];
    size_t bhbase = idx & ~(size_t)4095;
    int e = (int)((idx >> 6) & 63), d = (int)(idx & 63);
    kvtb[bhbase + (size_t)d * 64 + e] = f2b(s);
}

// ============ attention out via MFMA: out[l,d] = (Q[l,:] @ kv[:,d]) * nr[l]*nrref[l] ============
// kvtb is [bh][d][e] bf16 (N-major = B^T layout). Per wave: 64 rows x 64 cols, K=64.
// grid (NBH, 4); block 256 = 4 waves x 64 rows. No LDS, no barriers.
__global__ __launch_bounds__(256) void attn_out_mfma(const ushort_t* __restrict__ Q,
                                                     const ushort_t* __restrict__ kvtb,
                                                     const float* __restrict__ nr,
                                                     const float* __restrict__ nrref,
                                                     ushort_t* __restrict__ out) {
    int bh = blockIdx.x;
    int b = bh >> 3, h = bh & 7;
    const int lane = threadIdx.x & 63;
    const int wid = threadIdx.x >> 6;
    const int m0 = blockIdx.y * 256 + wid * 64;
    const int lr = lane & 15;
    const int kq = (lane >> 4) * 8;
    const size_t qbase = ((size_t)b * LTOK) * DD + h * 64;

    // B-frags from kvtb (same fragment pattern as bgemm's Bt): row=d(n), col=e(k)
    s8v bf[2][4];
    #pragma unroll
    for (int ks = 0; ks < 2; ks++)
        #pragma unroll
        for (int j = 0; j < 4; j++)
            bf[ks][j] = *(const s8v*)&kvtb[(size_t)bh * 4096 + (size_t)(j * 16 + lr) * 64 + ks * 32 + kq];

    f4v acc[4][4];
    #pragma unroll
    for (int i = 0; i < 4; i++)
        #pragma unroll
        for (int j = 0; j < 4; j++)
            acc[i][j] = (f4v){0.f, 0.f, 0.f, 0.f};

    #pragma unroll
    for (int ks = 0; ks < 2; ks++) {
        #pragma unroll
        for (int i = 0; i < 4; i++) {
            int row = m0 + i * 16 + lr;
            if (row > LTOK - 1) row = LTOK - 1;   // clamp; those rows never written
            s8v af = *(const s8v*)&Q[qbase + (size_t)row * DD + ks * 32 + kq];
            #pragma unroll
            for (int j = 0; j < 4; j++)
                acc[i][j] = __builtin_amdgcn_mfma_f32_16x16x32_bf16(af, bf[ks][j], acc[i][j], 0, 0, 0);
        }
    }

    // epilogue: C/D layout col=lane&15, row=(lane>>4)*4+reg
    const int orow = (lane >> 4) * 4;
    #pragma unroll
    for (int i = 0; i < 4; i++) {
        #pragma unroll
        for (int r = 0; r < 4; r++) {
            int l = m0 + i * 16 + orow + r;
            if (l >= LTOK) continue;
            float sc = nr[bh * LTOK + l] * nrref[bh * LTOK + l];
            #pragma unroll
            for (int j = 0; j < 4; j++) {
                int d = j * 16 + lr;
                out[qbase + (size_t)l * DD + d] = f2b(acc[i][j][r] * sc);
            }
        }
    }
}

// ============ final: transpose from projb[NTOK,720] bf16, RevIN denorm ============
__global__ __launch_bounds__(256) void final_out(const ushort_t* __restrict__ p,
                                                 const float* __restrict__ mean,
                                                 const float* __restrict__ stdev,
                                                 const float* __restrict__ rw,
                                                 const float* __restrict__ rb,
                                                 float* __restrict__ out) {
    int b = blockIdx.z;
    int c0 = blockIdx.x * 32, t0 = blockIdx.y * 32;
    __shared__ float tile[32][33];
    int tx = threadIdx.x & 31, ty = threadIdx.x >> 5;
    #pragma unroll
    for (int kk = 0; kk < 4; kk++) {
        int c = c0 + ty + kk * 8, t = t0 + tx;
        float v = 0.f;
        if (c < CC && t < TT) v = b2f(p[((size_t)b * LTOK + c) * TT + t]);
        tile[ty + kk * 8][tx] = v;
    }
    __syncthreads();
    #pragma unroll
    for (int kk = 0; kk < 4; kk++) {
        int t = t0 + ty + kk * 8, c = c0 + tx;
        if (c < CC && t < TT) {
            float v = tile[tx][ty + kk * 8];
            v = (v - rb[c]) / (rw[c] + 1e-10f);
            v = v * stdev[b * CC + c] + mean[b * CC + c];
            out[((size_t)b * TT + t) * CC + c] = v;
        }
    }
}

extern "C" void kernel_launch(void* const* d_in, const int* in_sizes, int n_in,
                              void* d_out, int out_size, void* d_ws, size_t ws_size,
                              hipStream_t stream) {
    (void)in_sizes; (void)n_in; (void)out_size; (void)ws_size;
    const float* x_enc   = (const float*)d_in[0];
    const float* x_mark  = (const float*)d_in[1];
    const float* revin_w = (const float*)d_in[4];
    const float* revin_b = (const float*)d_in[5];
    const float* emb_W   = (const float*)d_in[6];
    const float* emb_b   = (const float*)d_in[7];
    const float* Wq = (const float*)d_in[8];
    const float* bq = (const float*)d_in[9];
    const float* Wk = (const float*)d_in[10];
    const float* bk = (const float*)d_in[11];
    const float* Wv = (const float*)d_in[12];
    const float* bv = (const float*)d_in[13];
    const float* Wo = (const float*)d_in[14];
    const float* bo = (const float*)d_in[15];
    const float* ff1_W = (const float*)d_in[16];
    const float* ff1_b = (const float*)d_in[17];
    const float* ff2_W = (const float*)d_in[18];
    const float* ff2_b = (const float*)d_in[19];
    const float* ln1_w = (const float*)d_in[20];
    const float* ln1_b = (const float*)d_in[21];
    const float* ln2_w = (const float*)d_in[22];
    const float* ln2_b = (const float*)d_in[23];
    const float* lnf_w = (const float*)d_in[24];
    const float* lnf_b = (const float*)d_in[25];
    const float* proj_W = (const float*)d_in[26];
    const float* proj_b = (const float*)d_in[27];
    float* out = (float*)d_out;

    // ---- workspace layout (~242 MB; kv partials alias the dead U buffer) ----
    char* wsb = (char*)d_ws;
    size_t off = 0;
    auto alloc = [&](size_t bytes) {
        off = (off + 63) & ~(size_t)63;
        void* p = wsb + off; off += bytes; return p;
    };
    float* mean  = (float*)alloc((size_t)BB * CC * 4);
    float* stdev = (float*)alloc((size_t)BB * CC * 4);
    float* qsumP  = (float*)alloc((size_t)LSPLIT * NBH * 64 * 4);
    float* ksumP  = (float*)alloc((size_t)LSPLIT * NBH * 64 * 4);
    float* qnsumP = (float*)alloc((size_t)LSPLIT * NBH * 64 * 4);
    float* knsumP = (float*)alloc((size_t)LSPLIT * NBH * 64 * 4);
    float* nr    = (float*)alloc((size_t)NBH * LTOK * 4);
    float* nc    = (float*)alloc((size_t)NBH * LTOK * 4);
    float* nrref = (float*)alloc((size_t)NBH * LTOK * 4);
    float* ncref = (float*)alloc((size_t)NBH * LTOK * 4);
    ushort_t* kvtb = (ushort_t*)alloc((size_t)NBH * 4096 * 2); // reduced kv, transposed [d][e], bf16
    float* x     = (float*)alloc((size_t)NTOK * DD * 4);         // fp32 residual spine
    ushort_t* xb = (ushort_t*)alloc((size_t)NTOK * DD * 2);      // bf16 copy of x
    ushort_t* qb = (ushort_t*)alloc((size_t)NTOK * DD * 2);      // also Wo/FF2 output (tmpb)
    ushort_t* kb = (ushort_t*)alloc((size_t)NTOK * DD * 2);
    ushort_t* vb = (ushort_t*)alloc((size_t)NTOK * DD * 2);      // also attention output
    ushort_t* wbuf = (ushort_t*)alloc((size_t)10207232 * 2);     // all bf16 transposed weights
    ushort_t* U  = (ushort_t*)alloc((size_t)NTOK * KPAD * 2);    // union: tokb / ff-chunk / projb / kvpart

    // weight sub-buffers
    ushort_t* embT = wbuf;                          // [512,736]
    ushort_t* qT   = embT + (size_t)512 * KPAD;     // 3 x [512,512]
    ushort_t* kT   = qT + 3 * 262144;
    ushort_t* vT   = kT + 3 * 262144;
    ushort_t* oT   = vT + 3 * 262144;
    ushort_t* f1T  = oT + 3 * 262144;               // 3 x [2048,512]
    ushort_t* f2T  = f1T + (size_t)3 * 1048576;     // 3 x [512,2048]
    ushort_t* pT   = f2T + (size_t)3 * 1048576;     // [768,512]
    ushort_t* tokb  = U;                             // [NTOK, 736]
    ushort_t* ffb   = U;                             // chunk [6912, 2048]
    ushort_t* projb = U;                             // [NTOK, 720]
    float* kvpart   = (float*)U;                     // [KVSPLIT, NBH, 4096] = 33.5MB <= 40.8MB
    ushort_t* tmpb  = qb;                            // Wo/FF2 output

    dim3 blk(256);
    // ---- weight conversion (transpose to [N,K] bf16) ----
    auto cvt = [&](const float* W, ushort_t* Wt, int K, int N, int KP, int NP) {
        convT<<<dim3((KP + 31) / 32, (NP + 31) / 32), blk, 0, stream>>>(W, Wt, K, N, KP, NP);
    };
    cvt(emb_W, embT, TT, DD, KPAD, DD);
    for (int l = 0; l < 3; l++) {
        cvt(Wq + (size_t)l * DD * DD, qT + (size_t)l * 262144, DD, DD, DD, DD);
        cvt(Wk + (size_t)l * DD * DD, kT + (size_t)l * 262144, DD, DD, DD, DD);
        cvt(Wv + (size_t)l * DD * DD, vT + (size_t)l * 262144, DD, DD, DD, DD);
        cvt(Wo + (size_t)l * DD * DD, oT + (size_t)l * 262144, DD, DD, DD, DD);
        cvt(ff1_W + (size_t)l * DD * FFD, f1T + (size_t)l * 1048576, DD, FFD, DD, FFD);
        cvt(ff2_W + (size_t)l * FFD * DD, f2T + (size_t)l * 1048576, FFD, DD, FFD, DD);
    }
    cvt(proj_W, pT, DD, TT, DD, NPADP);

    // ---- RevIN + tokens + embedding ----
    revin_stats<<<dim3((CC + 63) / 64, BB), blk, 0, stream>>>(x_enc, mean, stdev);
    build_tok<<<dim3((LTOK + 31) / 32, (KPAD + 31) / 32, BB), blk, 0, stream>>>(
        x_enc, x_mark, mean, stdev, revin_w, revin_b, tokb);
    const int MT = (NTOK + 127) / 128;   // 217
    bgemm<0, true, true><<<dim3(DD / 128, MT), blk, 0, stream>>>(
        tokb, embT, emb_b, x, xb, NTOK, KPAD, DD);

    int ltiles = (LTOK + 63) / 64;
    for (int l = 0; l < 3; l++) {
        bgemm<2, false, true><<<dim3(DD / 128, MT), blk, 0, stream>>>(
            xb, qT + (size_t)l * 262144, bq + l * DD, nullptr, qb, NTOK, DD, DD);
        bgemm<2, false, true><<<dim3(DD / 128, MT), blk, 0, stream>>>(
            xb, kT + (size_t)l * 262144, bk + l * DD, nullptr, kb, NTOK, DD, DD);
        bgemm<0, false, true><<<dim3(DD / 128, MT), blk, 0, stream>>>(
            xb, vT + (size_t)l * 262144, bv + l * DD, nullptr, vb, NTOK, DD, DD);
        attn_sums<false><<<dim3(NBH, LSPLIT), blk, 0, stream>>>(
            qb, kb, nullptr, nullptr, qsumP, ksumP);
        attn_dots<0><<<dim3(NBH, ltiles), blk, 0, stream>>>(qb, kb, ksumP, qsumP, nr, nc);
        attn_sums<true><<<dim3(NBH, LSPLIT), blk, 0, stream>>>(
            qb, kb, nr, nc, qnsumP, knsumP);
        attn_dots<1><<<dim3(NBH, ltiles), blk, 0, stream>>>(qb, kb, knsumP, qnsumP, nrref, ncref);
        attn_softmax<<<NBH, blk, 0, stream>>>(ncref);
        attn_kv_part<<<dim3(NBH, KVSPLIT), blk, 0, stream>>>(kb, vb, ncref, kvpart);
        kv_reduce<<<dim3((NBH * 4096) / 256), blk, 0, stream>>>(kvpart, kvtb);
        attn_out_mfma<<<dim3(NBH, 4), blk, 0, stream>>>(qb, kvtb, nr, nrref, vb);
        // Wo: A = attention output (vb), out -> tmpb (qb, dead)
        bgemm<0, false, true><<<dim3(DD / 128, MT), blk, 0, stream>>>(
            vb, oT + (size_t)l * 262144, bo + l * DD, nullptr, tmpb, NTOK, DD, DD);
        ln_kernel<<<NTOK, blk, 0, stream>>>(x, tmpb, ln1_w + l * DD, ln1_b + l * DD, xb);
        // FF chunked over rows (ff activation fits in U)
        for (int t0 = 0; t0 < NTOK / 64; t0 += 108) {
            int nt = NTOK / 64 - t0; if (nt > 108) nt = 108;
            int rs = t0 * 64, mc = nt * 64;
            bgemm<1, false, true><<<dim3(FFD / 128, (mc + 127) / 128), blk, 0, stream>>>(
                xb + (size_t)rs * DD, f1T + (size_t)l * 1048576, ff1_b + l * FFD,
                nullptr, ffb, mc, DD, FFD);
            bgemm<0, false, true><<<dim3(DD / 128, (mc + 127) / 128), blk, 0, stream>>>(
                ffb, f2T + (size_t)l * 1048576, ff2_b + l * DD,
                nullptr, tmpb + (size_t)rs * DD, mc, FFD, DD);
        }
        ln_kernel<<<NTOK, blk, 0, stream>>>(x, tmpb, ln2_w + l * DD, ln2_b + l * DD, xb);
    }
    ln_kernel<<<NTOK, blk, 0, stream>>>(x, nullptr, lnf_w, lnf_b, xb);
    // projection: [NTOK,512] @ [512,768(pad)] -> projb [NTOK,720] bf16
    bgemm<0, false, true><<<dim3(NPADP / 128, MT), blk, 0, stream>>>(
        xb, pT, proj_b, nullptr, projb, NTOK, DD, TT);
    final_out<<<dim3((CC + 31) / 32, (TT + 31) / 32, BB), blk, 0, stream>>>(
        projb, mean, stdev, revin_w, revin_b, out);
}

// Round 3
// 3279.660 us; speedup vs baseline: 1.2919x; 1.0692x over previous
//
#include <hip/hip_runtime.h>
#include <math.h>

// ---- problem constants ----
#define BB 32
#define TT 720
#define CC 862
#define MM 4
#define LTOK 866          // C + M tokens
#define DD 512
#define HH 8
#define EE 64
#define FFD 2048
#define NTOK (BB * LTOK)  // 27712 = 433*64
#define NBH (BB * HH)     // 256
#define KPAD 736          // 720 padded to mult of 32 (embedding K)
#define NPADP 768         // 720 padded to mult of 128 (proj N tiles)
#define LSPLIT 4          // attn_sums l-split
#define LCHUNK 224        // ceil(866/4) rounded to mult of 32
#define KVSPLIT 8         // attn_kv s-split
#define KVCHUNK 112       // ceil(866/8) rounded to mult of 16
#define QS 1536           // fused QKV row stride
#define TSPL 8            // revin t-split
#define TCH 90            // 720 / TSPL

typedef unsigned short ushort_t;
typedef short s8v __attribute__((ext_vector_type(8)));
typedef float f4v __attribute__((ext_vector_type(4)));

__device__ __forceinline__ float wave_sum(float v) {
    #pragma unroll
    for (int off = 32; off; off >>= 1) v += __shfl_xor(v, off, 64);
    return v;
}
__device__ __forceinline__ float b2f(ushort_t u) {
    return __uint_as_float(((unsigned int)u) << 16);
}
__device__ __forceinline__ ushort_t f2b(float f) {
    unsigned int u = __float_as_uint(f);
    u = (u + 0x7FFFu + ((u >> 16) & 1u)) >> 16;
    return (ushort_t)u;
}

// ============ RevIN stats stage 1: partial sums over t-chunk ============
__global__ __launch_bounds__(256) void revin_part(const float* __restrict__ x_enc,
                                                  float* __restrict__ pS,
                                                  float* __restrict__ pS2) {
    int b = blockIdx.y, tz = blockIdx.z;
    int c = blockIdx.x * 64 + (threadIdx.x & 63);
    int g = threadIdx.x >> 6;
    float s = 0.f, s2 = 0.f;
    if (c < CC) {
        int t0 = tz * TCH;
        for (int t = t0 + g; t < t0 + TCH; t += 4) {
            float v = x_enc[((size_t)b * TT + t) * CC + c];
            s += v; s2 += v * v;
        }
    }
    __shared__ float ls[4][64], ls2[4][64];
    ls[g][threadIdx.x & 63] = s; ls2[g][threadIdx.x & 63] = s2;
    __syncthreads();
    if (g == 0 && c < CC) {
        int cx = threadIdx.x & 63;
        s = ls[0][cx] + ls[1][cx] + ls[2][cx] + ls[3][cx];
        s2 = ls2[0][cx] + ls2[1][cx] + ls2[2][cx] + ls2[3][cx];
        pS[((size_t)tz * BB + b) * CC + c] = s;
        pS2[((size_t)tz * BB + b) * CC + c] = s2;
    }
}

// ============ RevIN stats stage 2: finalize mean/stdev ============
__global__ __launch_bounds__(256) void revin_fin(const float* __restrict__ pS,
                                                 const float* __restrict__ pS2,
                                                 float* __restrict__ mean,
                                                 float* __restrict__ stdev) {
    int idx = blockIdx.x * 256 + threadIdx.x;
    if (idx >= BB * CC) return;
    float s = 0.f, s2 = 0.f;
    #pragma unroll
    for (int tz = 0; tz < TSPL; tz++) {
        s += pS[(size_t)tz * BB * CC + idx];
        s2 += pS2[(size_t)tz * BB * CC + idx];
    }
    float mu = s / (float)TT;
    float var = s2 / (float)TT - mu * mu;
    mean[idx] = mu;
    stdev[idx] = sqrtf(var + 1e-5f);
}

// ============ build tokb[B,866,736] bf16: normalized channels + marks, K-padded ============
__global__ __launch_bounds__(256) void build_tok(const float* __restrict__ x_enc,
                                                 const float* __restrict__ x_mark,
                                                 const float* __restrict__ mean,
                                                 const float* __restrict__ stdev,
                                                 const float* __restrict__ rw,
                                                 const float* __restrict__ rb,
                                                 ushort_t* __restrict__ tok) {
    int b = blockIdx.z;
    int r0 = blockIdx.x * 32, t0 = blockIdx.y * 32;
    __shared__ float tile[32][33];
    int tx = threadIdx.x & 31, ty = threadIdx.x >> 5;
    #pragma unroll
    for (int kk = 0; kk < 4; kk++) {
        int t = t0 + ty + kk * 8, r = r0 + tx;
        float v = 0.f;
        if (t < TT && r < LTOK) {
            if (r < CC) {
                float xv = x_enc[((size_t)b * TT + t) * CC + r];
                v = (xv - mean[b * CC + r]) / stdev[b * CC + r] * rw[r] + rb[r];
            } else {
                v = x_mark[((size_t)b * TT + t) * MM + (r - CC)];
            }
        }
        tile[ty + kk * 8][tx] = v;
    }
    __syncthreads();
    #pragma unroll
    for (int kk = 0; kk < 4; kk++) {
        int r = r0 + ty + kk * 8, t = t0 + tx;
        if (r < LTOK && t < KPAD)
            tok[((size_t)b * LTOK + r) * KPAD + t] = f2b(tile[tx][ty + kk * 8]);
    }
}

// ============ weight convert+transpose: W[K,N] f32 -> Wt[NP,KP] bf16 (zero-padded) ============
__global__ __launch_bounds__(256) void convT(const float* __restrict__ W,
                                             ushort_t* __restrict__ Wt,
                                             int K, int N, int KP, int NP) {
    __shared__ float tile[32][33];
    int k0 = blockIdx.x * 32, n0 = blockIdx.y * 32;
    int tx = threadIdx.x & 31, ty = threadIdx.x >> 5;
    #pragma unroll
    for (int r = 0; r < 4; r++) {
        int k = k0 + ty + r * 8, n = n0 + tx;
        tile[ty + r * 8][tx] = (k < K && n < N) ? W[(size_t)k * N + n] : 0.f;
    }
    __syncthreads();
    #pragma unroll
    for (int r = 0; r < 4; r++) {
        int n = n0 + ty + r * 8, k = k0 + tx;
        if (n < NP && k < KP)
            Wt[(size_t)n * KP + k] = f2b(tile[tx][ty + r * 8]);
    }
}

// ============ bf16 MFMA GEMM: C = act(A[M,K] @ Bt[N,K]^T + bias) ============
// 128x128 tile, BK=32, 4 waves (2x2 of 64x64), mfma_f32_16x16x32_bf16.
// ACT: 0 none, 1 gelu(exact), 2 sigmoid. OF: write f32 Cf. OB: write bf16 Cb.
#define GLL(g, l) __builtin_amdgcn_global_load_lds( \
    (const __attribute__((address_space(1))) void*)(g), \
    (__attribute__((address_space(3))) void*)(l), 16, 0, 0)

template <int ACT, bool OF, bool OB>
__global__ __launch_bounds__(256) void bgemm(const ushort_t* __restrict__ A,
                                             const ushort_t* __restrict__ Bt,
                                             const float* __restrict__ bias,
                                             float* __restrict__ Cf,
                                             ushort_t* __restrict__ Cb,
                                             int Mdim, int Kdim, int Nout) {
    __shared__ ushort_t As[128 * 32];
    __shared__ ushort_t Bs[128 * 32];
    const int tid = threadIdx.x;
    const int lane = tid & 63;
    const int wid = tid >> 6;
    const int m0 = blockIdx.y * 128;
    const int n0 = blockIdx.x * 128;
    const int wm = wid & 1, wn = wid >> 1;

    f4v acc[4][4];
    #pragma unroll
    for (int i = 0; i < 4; i++)
        #pragma unroll
        for (int j = 0; j < 4; j++)
            acc[i][j] = (f4v){0.f, 0.f, 0.f, 0.f};

    const int srow = wid * 16 + (lane >> 2);
    const int skq = (lane & 3) * 8;
    int ar0 = m0 + srow;       if (ar0 > Mdim - 1) ar0 = Mdim - 1;
    int ar1 = m0 + 64 + srow;  if (ar1 > Mdim - 1) ar1 = Mdim - 1;
    const ushort_t* gA0 = A + (size_t)ar0 * Kdim + skq;
    const ushort_t* gA1 = A + (size_t)ar1 * Kdim + skq;
    const ushort_t* gB0 = Bt + (size_t)(n0 + srow) * Kdim + skq;
    const ushort_t* gB1 = Bt + (size_t)(n0 + 64 + srow) * Kdim + skq;
    ushort_t* lA0 = &As[(wid * 16) * 32];
    ushort_t* lA1 = &As[(64 + wid * 16) * 32];
    ushort_t* lB0 = &Bs[(wid * 16) * 32];
    ushort_t* lB1 = &Bs[(64 + wid * 16) * 32];

    const int lr = lane & 15;
    const int kc = (lane >> 4) * 8;

    for (int k0 = 0; k0 < Kdim; k0 += 32) {
        GLL(gA0 + k0, lA0);
        GLL(gA1 + k0, lA1);
        GLL(gB0 + k0, lB0);
        GLL(gB1 + k0, lB1);
        __syncthreads();
        s8v af[4], bf[4];
        #pragma unroll
        for (int i = 0; i < 4; i++)
            af[i] = *(const s8v*)&As[(wm * 64 + i * 16 + lr) * 32 + kc];
        #pragma unroll
        for (int j = 0; j < 4; j++)
            bf[j] = *(const s8v*)&Bs[(wn * 64 + j * 16 + lr) * 32 + kc];
        #pragma unroll
        for (int i = 0; i < 4; i++)
            #pragma unroll
            for (int j = 0; j < 4; j++)
                acc[i][j] = __builtin_amdgcn_mfma_f32_16x16x32_bf16(af[i], bf[j], acc[i][j], 0, 0, 0);
        __syncthreads();
    }

    const int orow = (lane >> 4) * 4;
    #pragma unroll
    for (int j = 0; j < 4; j++) {
        int col = n0 + wn * 64 + j * 16 + lr;
        bool cok = col < Nout;
        float bb = cok ? bias[col] : 0.f;
        #pragma unroll
        for (int i = 0; i < 4; i++) {
            #pragma unroll
            for (int r = 0; r < 4; r++) {
                int row = m0 + wm * 64 + i * 16 + orow + r;
                if (cok && row < Mdim) {
                    float v = acc[i][j][r] + bb;
                    if (ACT == 1) v = 0.5f * v * (1.0f + erff(v * 0.70710678118654752f));
                    if (ACT == 2) v = 1.0f / (1.0f + expf(-v));
                    size_t idx = (size_t)row * Nout + col;
                    if (OF) Cf[idx] = v;
                    if (OB) Cb[idx] = f2b(v);
                }
            }
        }
    }
}

// ============ fused QKV GEMM: [NTOK,512] @ [1536,512]^T -> qkvb [NTOK,1536] bf16 ============
// sections: col<512 Q (sigmoid), <1024 K (sigmoid), else V (none). K=512, N=1536 exact.
__global__ __launch_bounds__(256) void bgemm_qkv(const ushort_t* __restrict__ A,
                                                 const ushort_t* __restrict__ Bt,
                                                 const float* __restrict__ bq_,
                                                 const float* __restrict__ bk_,
                                                 const float* __restrict__ bv_,
                                                 ushort_t* __restrict__ Cb,
                                                 int Mdim) {
    __shared__ ushort_t As[128 * 32];
    __shared__ ushort_t Bs[128 * 32];
    const int tid = threadIdx.x;
    const int lane = tid & 63;
    const int wid = tid >> 6;
    const int m0 = blockIdx.y * 128;
    const int n0 = blockIdx.x * 128;
    const int wm = wid & 1, wn = wid >> 1;

    f4v acc[4][4];
    #pragma unroll
    for (int i = 0; i < 4; i++)
        #pragma unroll
        for (int j = 0; j < 4; j++)
            acc[i][j] = (f4v){0.f, 0.f, 0.f, 0.f};

    const int srow = wid * 16 + (lane >> 2);
    const int skq = (lane & 3) * 8;
    int ar0 = m0 + srow;       if (ar0 > Mdim - 1) ar0 = Mdim - 1;
    int ar1 = m0 + 64 + srow;  if (ar1 > Mdim - 1) ar1 = Mdim - 1;
    const ushort_t* gA0 = A + (size_t)ar0 * DD + skq;
    const ushort_t* gA1 = A + (size_t)ar1 * DD + skq;
    const ushort_t* gB0 = Bt + (size_t)(n0 + srow) * DD + skq;
    const ushort_t* gB1 = Bt + (size_t)(n0 + 64 + srow) * DD + skq;
    ushort_t* lA0 = &As[(wid * 16) * 32];
    ushort_t* lA1 = &As[(64 + wid * 16) * 32];
    ushort_t* lB0 = &Bs[(wid * 16) * 32];
    ushort_t* lB1 = &Bs[(64 + wid * 16) * 32];

    const int lr = lane & 15;
    const int kc = (lane >> 4) * 8;

    for (int k0 = 0; k0 < DD; k0 += 32) {
        GLL(gA0 + k0, lA0);
        GLL(gA1 + k0, lA1);
        GLL(gB0 + k0, lB0);
        GLL(gB1 + k0, lB1);
        __syncthreads();
        s8v af[4], bf[4];
        #pragma unroll
        for (int i = 0; i < 4; i++)
            af[i] = *(const s8v*)&As[(wm * 64 + i * 16 + lr) * 32 + kc];
        #pragma unroll
        for (int j = 0; j < 4; j++)
            bf[j] = *(const s8v*)&Bs[(wn * 64 + j * 16 + lr) * 32 + kc];
        #pragma unroll
        for (int i = 0; i < 4; i++)
            #pragma unroll
            for (int j = 0; j < 4; j++)
                acc[i][j] = __builtin_amdgcn_mfma_f32_16x16x32_bf16(af[i], bf[j], acc[i][j], 0, 0, 0);
        __syncthreads();
    }

    const int orow = (lane >> 4) * 4;
    #pragma unroll
    for (int j = 0; j < 4; j++) {
        int col = n0 + wn * 64 + j * 16 + lr;
        int sec = col >> 9;
        const float* bsel = (sec == 0) ? bq_ : ((sec == 1) ? bk_ : bv_);
        float bb = bsel[col & 511];
        #pragma unroll
        for (int i = 0; i < 4; i++) {
            #pragma unroll
            for (int r = 0; r < 4; r++) {
                int row = m0 + wm * 64 + i * 16 + orow + r;
                if (row < Mdim) {
                    float v = acc[i][j][r] + bb;
                    if (sec < 2) v = 1.0f / (1.0f + expf(-v));
                    Cb[(size_t)row * QS + col] = f2b(v);
                }
            }
        }
    }
}

// ============ LayerNorm over D=512: x_f32 = LN(x + res_bf16); also write bf16 copy ============
__global__ __launch_bounds__(256) void ln_kernel(float* __restrict__ x,
                                                 const ushort_t* __restrict__ res,
                                                 const float* __restrict__ w,
                                                 const float* __restrict__ bp,
                                                 ushort_t* __restrict__ xb) {
    size_t base = (size_t)blockIdx.x * DD;
    int tid = threadIdx.x;
    float v0 = x[base + tid];
    float v1 = x[base + tid + 256];
    if (res != nullptr) { v0 += b2f(res[base + tid]); v1 += b2f(res[base + tid + 256]); }
    float s = wave_sum(v0 + v1);
    float s2 = wave_sum(v0 * v0 + v1 * v1);
    __shared__ float a1[4], a2[4];
    if ((tid & 63) == 0) { a1[tid >> 6] = s; a2[tid >> 6] = s2; }
    __syncthreads();
    s = a1[0] + a1[1] + a1[2] + a1[3];
    s2 = a2[0] + a2[1] + a2[2] + a2[3];
    float mu = s * (1.0f / DD);
    float var = s2 * (1.0f / DD) - mu * mu;
    float rs = rsqrtf(var + 1e-5f);
    float o0 = (v0 - mu) * rs * w[tid] + bp[tid];
    float o1 = (v1 - mu) * rs * w[tid + 256] + bp[tid + 256];
    x[base + tid] = o0;
    x[base + tid + 256] = o1;
    xb[base + tid] = f2b(o0);
    xb[base + tid + 256] = f2b(o1);
}

// ============ attention: per (b,h) column sums over l (optionally weighted) ============
// Q/Kp point into qkvb (stride QS). l-split LSPLIT-way: grid (NBH, LSPLIT).
template <bool WEIGHTED>
__global__ __launch_bounds__(256) void attn_sums(const ushort_t* __restrict__ Q,
                                                 const ushort_t* __restrict__ Kp,
                                                 const float* __restrict__ wq,
                                                 const float* __restrict__ wk,
                                                 float* __restrict__ qsumP,
                                                 float* __restrict__ ksumP) {
    int bh = blockIdx.x;
    int sp = blockIdx.y;
    int b = bh >> 3, h = bh & 7;
    int lane = threadIdx.x & 63, g = threadIdx.x >> 6;
    int eo = (lane & 7) * 8;
    int lofs = lane >> 3;
    const size_t base = ((size_t)b * LTOK) * QS + h * 64 + eo;
    float aq[8] = {}, ak[8] = {};
    int lend = sp * LCHUNK + LCHUNK; if (lend > LTOK) lend = LTOK;
    for (int l = sp * LCHUNK + g * 8 + lofs; l < lend; l += 32) {
        s8v q8 = *(const s8v*)&Q[base + (size_t)l * QS];
        s8v k8 = *(const s8v*)&Kp[base + (size_t)l * QS];
        float wqv = 1.f, wkv = 1.f;
        if (WEIGHTED) { wqv = wq[bh * LTOK + l]; wkv = wk[bh * LTOK + l]; }
        #pragma unroll
        for (int j = 0; j < 8; j++) {
            aq[j] += b2f((ushort_t)q8[j]) * wqv;
            ak[j] += b2f((ushort_t)k8[j]) * wkv;
        }
    }
    #pragma unroll
    for (int off = 8; off < 64; off <<= 1) {
        #pragma unroll
        for (int j = 0; j < 8; j++) {
            aq[j] += __shfl_xor(aq[j], off, 64);
            ak[j] += __shfl_xor(ak[j], off, 64);
        }
    }
    __shared__ float sqs[4][64], sks[4][64];
    if (lofs == 0) {
        #pragma unroll
        for (int j = 0; j < 8; j++) { sqs[g][eo + j] = aq[j]; sks[g][eo + j] = ak[j]; }
    }
    __syncthreads();
    if (threadIdx.x < 64) {
        int e = threadIdx.x;
        float fq = sqs[0][e] + sqs[1][e] + sqs[2][e] + sqs[3][e];
        float fk = sks[0][e] + sks[1][e] + sks[2][e] + sks[3][e];
        qsumP[((size_t)sp * NBH + bh) * 64 + e] = fq;
        ksumP[((size_t)sp * NBH + bh) * 64 + e] = fk;
    }
}

// ============ attention: per-l dot with summed vector (sums LSPLIT partials) ============
template <int MODE>
__global__ __launch_bounds__(256) void attn_dots(const ushort_t* __restrict__ Q,
                                                 const ushort_t* __restrict__ Kp,
                                                 const float* __restrict__ Sq,
                                                 const float* __restrict__ Sk,
                                                 float* __restrict__ outq,
                                                 float* __restrict__ outk) {
    int bh = blockIdx.x;
    int b = bh >> 3, h = bh & 7;
    int lane = threadIdx.x & 63, w = threadIdx.x >> 6;
    float sq = 0.f, sk = 0.f;
    #pragma unroll
    for (int sp = 0; sp < LSPLIT; sp++) {
        sq += Sq[((size_t)sp * NBH + bh) * 64 + lane];
        sk += Sk[((size_t)sp * NBH + bh) * 64 + lane];
    }
    sq += 1e-6f; sk += 1e-6f;
    const size_t base = ((size_t)b * LTOK) * QS + h * 64 + lane;
    int l0 = blockIdx.y * 64 + w * 16;
    for (int i = 0; i < 16; i++) {
        int l = l0 + i;
        if (l >= LTOK) break;
        float dq = (b2f(Q[base + (size_t)l * QS]) + 1e-6f) * sq;
        float dk = (b2f(Kp[base + (size_t)l * QS]) + 1e-6f) * sk;
        dq = wave_sum(dq);
        dk = wave_sum(dk);
        if (lane == 0) {
            if (MODE == 0) { outq[bh * LTOK + l] = 1.0f / dq; outk[bh * LTOK + l] = 1.0f / dk; }
            else { outq[bh * LTOK + l] = 1.0f / (1.0f + expf(-dq)); outk[bh * LTOK + l] = dk; }
        }
    }
}

// ============ attention: softmax over s (in place), scaled by Ls ============
__global__ __launch_bounds__(256) void attn_softmax(float* __restrict__ buf) {
    float* p = buf + (size_t)blockIdx.x * LTOK;
    int tid = threadIdx.x;
    __shared__ float red[4];
    float mx = -1e30f;
    for (int l = tid; l < LTOK; l += 256) mx = fmaxf(mx, p[l]);
    #pragma unroll
    for (int off = 32; off; off >>= 1) mx = fmaxf(mx, __shfl_xor(mx, off, 64));
    if ((tid & 63) == 0) red[tid >> 6] = mx;
    __syncthreads();
    mx = fmaxf(fmaxf(red[0], red[1]), fmaxf(red[2], red[3]));
    __syncthreads();
    float s = 0.f;
    for (int l = tid; l < LTOK; l += 256) s += expf(p[l] - mx);
    s = wave_sum(s);
    if ((tid & 63) == 0) red[tid >> 6] = s;
    __syncthreads();
    s = red[0] + red[1] + red[2] + red[3];
    float scale = (float)LTOK / s;
    for (int l = tid; l < LTOK; l += 256) p[l] = expf(p[l] - mx) * scale;
}

// ============ attention: kv[e,d] = sum_s k[s,e] * v[s,d] * ncref[s] ============
// Kp/V point into qkvb (stride QS). s-split: grid (NBH, KVSPLIT).
__global__ __launch_bounds__(256) void attn_kv_part(const ushort_t* __restrict__ Kp,
                                                    const ushort_t* __restrict__ V,
                                                    const float* __restrict__ ncref,
                                                    float* __restrict__ kvpart) {
    int bh = blockIdx.x;
    int sp = blockIdx.y;
    int b = bh >> 3, h = bh & 7;
    int d = threadIdx.x & 63, eg = threadIdx.x >> 6;
    __shared__ float ks[16][64], vs[16][64];
    float acc[16] = {};
    const size_t base = ((size_t)b * LTOK) * QS + h * 64;
    const int s_begin = sp * KVCHUNK;
    int s_end = s_begin + KVCHUNK; if (s_end > LTOK) s_end = LTOK;

    const bool isV = threadIdx.x >= 128;       // wave-uniform split
    const int slot = threadIdx.x & 127;        // 16 rows x 8 vec-slots
    const int srow = slot >> 3;
    const int e0 = (slot & 7) * 8;
    const ushort_t* src = isV ? V : Kp;

    for (int s0 = s_begin; s0 < s_end; s0 += 16) {
        __syncthreads();
        int s = s0 + srow;
        float vals[8] = {};
        if (s < s_end) {
            s8v raw = *(const s8v*)&src[base + (size_t)s * QS + e0];
            float mul = isV ? ncref[bh * LTOK + s] : 1.f;
            #pragma unroll
            for (int j = 0; j < 8; j++) vals[j] = b2f((ushort_t)raw[j]) * mul;
        }
        float (*dst)[64] = isV ? vs : ks;
        #pragma unroll
        for (int j = 0; j < 8; j++) dst[srow][e0 + j] = vals[j];
        __syncthreads();
        int nsi = s_end - s0; if (nsi > 16) nsi = 16;
        for (int si = 0; si < nsi; si++) {
            float vv = vs[si][d];
            #pragma unroll
            for (int i = 0; i < 16; i++) acc[i] += ks[si][eg * 16 + i] * vv;
        }
    }
    #pragma unroll
    for (int i = 0; i < 16; i++)
        kvpart[((size_t)sp * NBH + bh) * 4096 + (eg * 16 + i) * 64 + d] = acc[i];
}

// ============ reduce kv partials -> kvT bf16: kvtb[bh][d][e] = sum_sp part[sp][bh][e*64+d] ============
__global__ __launch_bounds__(256) void kv_reduce(const float* __restrict__ part,
                                                 ushort_t* __restrict__ kvtb) {
    size_t idx = (size_t)blockIdx.x * 256 + threadIdx.x;   // NBH*4096 total, idx = bh*4096 + e*64 + d
    float s = 0.f;
    #pragma unroll
    for (int sp = 0; sp < KVSPLIT; sp++)
        s += part[(size_t)sp * ((size_t)NBH * 4096) + idx];
    size_t bhbase = idx & ~(size_t)4095;
    int e = (int)((idx >> 6) & 63), d = (int)(idx & 63);
    kvtb[bhbase + (size_t)d * 64 + e] = f2b(s);
}

// ============ attention out via MFMA: out[l,d] = (Q[l,:] @ kv[:,d]) * nr[l]*nrref[l] ============
// Q from qkvb (stride QS); out (stride DD) bf16. grid (NBH, 4); 4 waves x 64 rows.
__global__ __launch_bounds__(256) void attn_out_mfma(const ushort_t* __restrict__ Q,
                                                     const ushort_t* __restrict__ kvtb,
                                                     const float* __restrict__ nr,
                                                     const float* __restrict__ nrref,
                                                     ushort_t* __restrict__ out) {
    int bh = blockIdx.x;
    int b = bh >> 3, h = bh & 7;
    const int lane = threadIdx.x & 63;
    const int wid = threadIdx.x >> 6;
    const int m0 = blockIdx.y * 256 + wid * 64;
    const int lr = lane & 15;
    const int kq = (lane >> 4) * 8;
    const size_t qbase = ((size_t)b * LTOK) * QS + h * 64;
    const size_t obase = ((size_t)b * LTOK) * DD + h * 64;

    s8v bf[2][4];
    #pragma unroll
    for (int ks = 0; ks < 2; ks++)
        #pragma unroll
        for (int j = 0; j < 4; j++)
            bf[ks][j] = *(const s8v*)&kvtb[(size_t)bh * 4096 + (size_t)(j * 16 + lr) * 64 + ks * 32 + kq];

    f4v acc[4][4];
    #pragma unroll
    for (int i = 0; i < 4; i++)
        #pragma unroll
        for (int j = 0; j < 4; j++)
            acc[i][j] = (f4v){0.f, 0.f, 0.f, 0.f};

    #pragma unroll
    for (int ks = 0; ks < 2; ks++) {
        #pragma unroll
        for (int i = 0; i < 4; i++) {
            int row = m0 + i * 16 + lr;
            if (row > LTOK - 1) row = LTOK - 1;   // clamp; those rows never written
            s8v af = *(const s8v*)&Q[qbase + (size_t)row * QS + ks * 32 + kq];
            #pragma unroll
            for (int j = 0; j < 4; j++)
                acc[i][j] = __builtin_amdgcn_mfma_f32_16x16x32_bf16(af, bf[ks][j], acc[i][j], 0, 0, 0);
        }
    }

    const int orow = (lane >> 4) * 4;
    #pragma unroll
    for (int i = 0; i < 4; i++) {
        #pragma unroll
        for (int r = 0; r < 4; r++) {
            int l = m0 + i * 16 + orow + r;
            if (l >= LTOK) continue;
            float sc = nr[bh * LTOK + l] * nrref[bh * LTOK + l];
            #pragma unroll
            for (int j = 0; j < 4; j++) {
                int d = j * 16 + lr;
                out[obase + (size_t)l * DD + d] = f2b(acc[i][j][r] * sc);
            }
        }
    }
}

// ============ final: transpose from projb[NTOK,720] bf16, RevIN denorm ============
__global__ __launch_bounds__(256) void final_out(const ushort_t* __restrict__ p,
                                                 const float* __restrict__ mean,
                                                 const float* __restrict__ stdev,
                                                 const float* __restrict__ rw,
                                                 const float* __restrict__ rb,
                                                 float* __restrict__ out) {
    int b = blockIdx.z;
    int c0 = blockIdx.x * 32, t0 = blockIdx.y * 32;
    __shared__ float tile[32][33];
    int tx = threadIdx.x & 31, ty = threadIdx.x >> 5;
    #pragma unroll
    for (int kk = 0; kk < 4; kk++) {
        int c = c0 + ty + kk * 8, t = t0 + tx;
        float v = 0.f;
        if (c < CC && t < TT) v = b2f(p[((size_t)b * LTOK + c) * TT + t]);
        tile[ty + kk * 8][tx] = v;
    }
    __syncthreads();
    #pragma unroll
    for (int kk = 0; kk < 4; kk++) {
        int t = t0 + ty + kk * 8, c = c0 + tx;
        if (c < CC && t < TT) {
            float v = tile[tx][ty + kk * 8];
            v = (v - rb[c]) / (rw[c] + 1e-10f);
            v = v * stdev[b * CC + c] + mean[b * CC + c];
            out[((size_t)b * TT + t) * CC + c] = v;
        }
    }
}

extern "C" void kernel_launch(void* const* d_in, const int* in_sizes, int n_in,
                              void* d_out, int out_size, void* d_ws, size_t ws_size,
                              hipStream_t stream) {
    (void)in_sizes; (void)n_in; (void)out_size; (void)ws_size;
    const float* x_enc   = (const float*)d_in[0];
    const float* x_mark  = (const float*)d_in[1];
    const float* revin_w = (const float*)d_in[4];
    const float* revin_b = (const float*)d_in[5];
    const float* emb_W   = (const float*)d_in[6];
    const float* emb_b   = (const float*)d_in[7];
    const float* Wq = (const float*)d_in[8];
    const float* bq = (const float*)d_in[9];
    const float* Wk = (const float*)d_in[10];
    const float* bk = (const float*)d_in[11];
    const float* Wv = (const float*)d_in[12];
    const float* bv = (const float*)d_in[13];
    const float* Wo = (const float*)d_in[14];
    const float* bo = (const float*)d_in[15];
    const float* ff1_W = (const float*)d_in[16];
    const float* ff1_b = (const float*)d_in[17];
    const float* ff2_W = (const float*)d_in[18];
    const float* ff2_b = (const float*)d_in[19];
    const float* ln1_w = (const float*)d_in[20];
    const float* ln1_b = (const float*)d_in[21];
    const float* ln2_w = (const float*)d_in[22];
    const float* ln2_b = (const float*)d_in[23];
    const float* lnf_w = (const float*)d_in[24];
    const float* lnf_b = (const float*)d_in[25];
    const float* proj_W = (const float*)d_in[26];
    const float* proj_b = (const float*)d_in[27];
    float* out = (float*)d_out;

    // ---- workspace layout (~240 MB) ----
    char* wsb = (char*)d_ws;
    size_t off = 0;
    auto alloc = [&](size_t bytes) {
        off = (off + 63) & ~(size_t)63;
        void* p = wsb + off; off += bytes; return p;
    };
    float* mean  = (float*)alloc((size_t)BB * CC * 4);
    float* stdev = (float*)alloc((size_t)BB * CC * 4);
    float* pS    = (float*)alloc((size_t)TSPL * BB * CC * 4);
    float* pS2   = (float*)alloc((size_t)TSPL * BB * CC * 4);
    float* qsumP  = (float*)alloc((size_t)LSPLIT * NBH * 64 * 4);
    float* ksumP  = (float*)alloc((size_t)LSPLIT * NBH * 64 * 4);
    float* qnsumP = (float*)alloc((size_t)LSPLIT * NBH * 64 * 4);
    float* knsumP = (float*)alloc((size_t)LSPLIT * NBH * 64 * 4);
    float* nr    = (float*)alloc((size_t)NBH * LTOK * 4);
    float* nc    = (float*)alloc((size_t)NBH * LTOK * 4);
    float* nrref = (float*)alloc((size_t)NBH * LTOK * 4);
    float* ncref = (float*)alloc((size_t)NBH * LTOK * 4);
    ushort_t* kvtb = (ushort_t*)alloc((size_t)NBH * 4096 * 2); // reduced kv, transposed [d][e], bf16
    float* x     = (float*)alloc((size_t)NTOK * DD * 4);          // fp32 residual spine
    ushort_t* xb = (ushort_t*)alloc((size_t)NTOK * DD * 2);       // bf16 copy of x
    ushort_t* qkvb = (ushort_t*)alloc((size_t)NTOK * QS * 2);     // fused QKV [NTOK,1536]
    ushort_t* wbuf = (ushort_t*)alloc((size_t)10207232 * 2);      // all bf16 transposed weights
    ushort_t* U  = (ushort_t*)alloc((size_t)NTOK * KPAD * 2);     // union: tokb/ff-chunk/projb/kvpart/ab

    // weight sub-buffers
    ushort_t* embT = wbuf;                          // [512,736]
    ushort_t* qkvT = embT + (size_t)512 * KPAD;     // 3 layers x [1536,512] (q,k,v stacked)
    ushort_t* oT   = qkvT + (size_t)3 * 786432;     // 3 x [512,512]
    ushort_t* f1T  = oT + 3 * 262144;               // 3 x [2048,512]
    ushort_t* f2T  = f1T + (size_t)3 * 1048576;     // 3 x [512,2048]
    ushort_t* pT   = f2T + (size_t)3 * 1048576;     // [768,512]
    ushort_t* tokb  = U;                             // [NTOK, 736]
    ushort_t* ffb   = U;                             // chunk [6912, 2048]
    ushort_t* projb = U;                             // [NTOK, 720]
    float* kvpart   = (float*)U;                     // [KVSPLIT, NBH, 4096] = 33.5MB
    ushort_t* ab    = U;                             // attn output [NTOK,512] (after kvpart dead)
    ushort_t* tmpb  = qkvb;                          // Wo/FF2 output (qkv dead by then)

    dim3 blk(256);
    // ---- weight conversion (transpose to [N,K] bf16) ----
    auto cvt = [&](const float* W, ushort_t* Wt, int K, int N, int KP, int NP) {
        convT<<<dim3((KP + 31) / 32, (NP + 31) / 32), blk, 0, stream>>>(W, Wt, K, N, KP, NP);
    };
    cvt(emb_W, embT, TT, DD, KPAD, DD);
    for (int l = 0; l < 3; l++) {
        ushort_t* lb = qkvT + (size_t)l * 786432;
        cvt(Wq + (size_t)l * DD * DD, lb,          DD, DD, DD, DD);
        cvt(Wk + (size_t)l * DD * DD, lb + 262144, DD, DD, DD, DD);
        cvt(Wv + (size_t)l * DD * DD, lb + 524288, DD, DD, DD, DD);
        cvt(Wo + (size_t)l * DD * DD, oT + (size_t)l * 262144, DD, DD, DD, DD);
        cvt(ff1_W + (size_t)l * DD * FFD, f1T + (size_t)l * 1048576, DD, FFD, DD, FFD);
        cvt(ff2_W + (size_t)l * FFD * DD, f2T + (size_t)l * 1048576, FFD, DD, FFD, DD);
    }
    cvt(proj_W, pT, DD, TT, DD, NPADP);

    // ---- RevIN (t-split) + tokens + embedding ----
    revin_part<<<dim3((CC + 63) / 64, BB, TSPL), blk, 0, stream>>>(x_enc, pS, pS2);
    revin_fin<<<dim3((BB * CC + 255) / 256), blk, 0, stream>>>(pS, pS2, mean, stdev);
    build_tok<<<dim3((LTOK + 31) / 32, (KPAD + 31) / 32, BB), blk, 0, stream>>>(
        x_enc, x_mark, mean, stdev, revin_w, revin_b, tokb);
    const int MT = (NTOK + 127) / 128;   // 217
    bgemm<0, true, true><<<dim3(DD / 128, MT), blk, 0, stream>>>(
        tokb, embT, emb_b, x, xb, NTOK, KPAD, DD);

    int ltiles = (LTOK + 63) / 64;
    for (int l = 0; l < 3; l++) {
        bgemm_qkv<<<dim3(QS / 128, MT), blk, 0, stream>>>(
            xb, qkvT + (size_t)l * 786432, bq + l * DD, bk + l * DD, bv + l * DD,
            qkvb, NTOK);
        attn_sums<false><<<dim3(NBH, LSPLIT), blk, 0, stream>>>(
            qkvb, qkvb + 512, nullptr, nullptr, qsumP, ksumP);
        attn_dots<0><<<dim3(NBH, ltiles), blk, 0, stream>>>(
            qkvb, qkvb + 512, ksumP, qsumP, nr, nc);
        attn_sums<true><<<dim3(NBH, LSPLIT), blk, 0, stream>>>(
            qkvb, qkvb + 512, nr, nc, qnsumP, knsumP);
        attn_dots<1><<<dim3(NBH, ltiles), blk, 0, stream>>>(
            qkvb, qkvb + 512, knsumP, qnsumP, nrref, ncref);
        attn_softmax<<<NBH, blk, 0, stream>>>(ncref);
        attn_kv_part<<<dim3(NBH, KVSPLIT), blk, 0, stream>>>(
            qkvb + 512, qkvb + 1024, ncref, kvpart);
        kv_reduce<<<dim3((NBH * 4096) / 256), blk, 0, stream>>>(kvpart, kvtb);
        attn_out_mfma<<<dim3(NBH, 4), blk, 0, stream>>>(qkvb, kvtb, nr, nrref, ab);
        // Wo: A = attention output (ab), out -> tmpb (qkvb region, dead)
        bgemm<0, false, true><<<dim3(DD / 128, MT), blk, 0, stream>>>(
            ab, oT + (size_t)l * 262144, bo + l * DD, nullptr, tmpb, NTOK, DD, DD);
        ln_kernel<<<NTOK, blk, 0, stream>>>(x, tmpb, ln1_w + l * DD, ln1_b + l * DD, xb);
        // FF chunked over rows (ff activation fits in U)
        for (int t0 = 0; t0 < NTOK / 64; t0 += 108) {
            int nt = NTOK / 64 - t0; if (nt > 108) nt = 108;
            int rs = t0 * 64, mc = nt * 64;
            bgemm<1, false, true><<<dim3(FFD / 128, (mc + 127) / 128), blk, 0, stream>>>(
                xb + (size_t)rs * DD, f1T + (size_t)l * 1048576, ff1_b + l * FFD,
                nullptr, ffb, mc, DD, FFD);
            bgemm<0, false, true><<<dim3(DD / 128, (mc + 127) / 128), blk, 0, stream>>>(
                ffb, f2T + (size_t)l * 1048576, ff2_b + l * DD,
                nullptr, tmpb + (size_t)rs * DD, mc, FFD, DD);
        }
        ln_kernel<<<NTOK, blk, 0, stream>>>(x, tmpb, ln2_w + l * DD, ln2_b + l * DD, xb);
    }
    ln_kernel<<<NTOK, blk, 0, stream>>>(x, nullptr, lnf_w, lnf_b, xb);
    // projection: [NTOK,512] @ [512,768(pad)] -> projb [NTOK,720] bf16
    bgemm<0, false, true><<<dim3(NPADP / 128, MT), blk, 0, stream>>>(
        xb, pT, proj_b, nullptr, projb, NTOK, DD, TT);
    final_out<<<dim3((CC + 31) / 32, (TT + 31) / 32, BB), blk, 0, stream>>>(
        projb, mean, stdev, revin_w, revin_b, out);
}

// Round 5
// 2807.353 us; speedup vs baseline: 1.5093x; 1.1682x over previous
//
#include <hip/hip_runtime.h>
#include <math.h>

// ---- problem constants ----
#define BB 32
#define TT 720
#define CC 862
#define MM 4
#define LTOK 866          // C + M tokens
#define DD 512
#define HH 8
#define EE 64
#define FFD 2048
#define NTOK (BB * LTOK)  // 27712 = 433*64
#define NBH (BB * HH)     // 256
#define KPAD 736          // 720 padded to mult of 32 (embedding K)
#define NPADP 768         // 720 padded to mult of 128 (proj N tiles)
#define LSPLIT 4          // attn_sums l-split
#define LCHUNK 224        // ceil(866/4) rounded to mult of 32
#define KVSPLIT 8         // attn_kv s-split
#define KVCHUNK 112       // ceil(866/8) rounded to mult of 16
#define QS 1536           // fused QKV row stride
#define TSPL 8            // revin t-split
#define TCH 90            // 720 / TSPL
#define CSLD 136          // C-tile LDS row stride (ushorts); 272B = 17x16B aligned

typedef unsigned short ushort_t;
typedef short s8v __attribute__((ext_vector_type(8)));
typedef float f4v __attribute__((ext_vector_type(4)));

__device__ __forceinline__ float wave_sum(float v) {
    #pragma unroll
    for (int off = 32; off; off >>= 1) v += __shfl_xor(v, off, 64);
    return v;
}
__device__ __forceinline__ float b2f(ushort_t u) {
    return __uint_as_float(((unsigned int)u) << 16);
}
__device__ __forceinline__ ushort_t f2b(float f) {
    unsigned int u = __float_as_uint(f);
    u = (u + 0x7FFFu + ((u >> 16) & 1u)) >> 16;
    return (ushort_t)u;
}

// ============ RevIN stats stage 1: partial sums over t-chunk ============
__global__ __launch_bounds__(256) void revin_part(const float* __restrict__ x_enc,
                                                  float* __restrict__ pS,
                                                  float* __restrict__ pS2) {
    int b = blockIdx.y, tz = blockIdx.z;
    int c = blockIdx.x * 64 + (threadIdx.x & 63);
    int g = threadIdx.x >> 6;
    float s = 0.f, s2 = 0.f;
    if (c < CC) {
        int t0 = tz * TCH;
        for (int t = t0 + g; t < t0 + TCH; t += 4) {
            float v = x_enc[((size_t)b * TT + t) * CC + c];
            s += v; s2 += v * v;
        }
    }
    __shared__ float ls[4][64], ls2[4][64];
    ls[g][threadIdx.x & 63] = s; ls2[g][threadIdx.x & 63] = s2;
    __syncthreads();
    if (g == 0 && c < CC) {
        int cx = threadIdx.x & 63;
        s = ls[0][cx] + ls[1][cx] + ls[2][cx] + ls[3][cx];
        s2 = ls2[0][cx] + ls2[1][cx] + ls2[2][cx] + ls2[3][cx];
        pS[((size_t)tz * BB + b) * CC + c] = s;
        pS2[((size_t)tz * BB + b) * CC + c] = s2;
    }
}

// ============ RevIN stats stage 2: finalize mean/stdev ============
__global__ __launch_bounds__(256) void revin_fin(const float* __restrict__ pS,
                                                 const float* __restrict__ pS2,
                                                 float* __restrict__ mean,
                                                 float* __restrict__ stdev) {
    int idx = blockIdx.x * 256 + threadIdx.x;
    if (idx >= BB * CC) return;
    float s = 0.f, s2 = 0.f;
    #pragma unroll
    for (int tz = 0; tz < TSPL; tz++) {
        s += pS[(size_t)tz * BB * CC + idx];
        s2 += pS2[(size_t)tz * BB * CC + idx];
    }
    float mu = s / (float)TT;
    float var = s2 / (float)TT - mu * mu;
    mean[idx] = mu;
    stdev[idx] = sqrtf(var + 1e-5f);
}

// ============ build tokb[B,866,736] bf16: normalized channels + marks, K-padded ============
__global__ __launch_bounds__(256) void build_tok(const float* __restrict__ x_enc,
                                                 const float* __restrict__ x_mark,
                                                 const float* __restrict__ mean,
                                                 const float* __restrict__ stdev,
                                                 const float* __restrict__ rw,
                                                 const float* __restrict__ rb,
                                                 ushort_t* __restrict__ tok) {
    int b = blockIdx.z;
    int r0 = blockIdx.x * 32, t0 = blockIdx.y * 32;
    __shared__ float tile[32][33];
    int tx = threadIdx.x & 31, ty = threadIdx.x >> 5;
    #pragma unroll
    for (int kk = 0; kk < 4; kk++) {
        int t = t0 + ty + kk * 8, r = r0 + tx;
        float v = 0.f;
        if (t < TT && r < LTOK) {
            if (r < CC) {
                float xv = x_enc[((size_t)b * TT + t) * CC + r];
                v = (xv - mean[b * CC + r]) / stdev[b * CC + r] * rw[r] + rb[r];
            } else {
                v = x_mark[((size_t)b * TT + t) * MM + (r - CC)];
            }
        }
        tile[ty + kk * 8][tx] = v;
    }
    __syncthreads();
    #pragma unroll
    for (int kk = 0; kk < 4; kk++) {
        int r = r0 + ty + kk * 8, t = t0 + tx;
        if (r < LTOK && t < KPAD)
            tok[((size_t)b * LTOK + r) * KPAD + t] = f2b(tile[tx][ty + kk * 8]);
    }
}

// ============ weight convert+transpose: W[K,N] f32 -> Wt[NP,KP] bf16 (zero-padded) ============
__global__ __launch_bounds__(256) void convT(const float* __restrict__ W,
                                             ushort_t* __restrict__ Wt,
                                             int K, int N, int KP, int NP) {
    __shared__ float tile[32][33];
    int k0 = blockIdx.x * 32, n0 = blockIdx.y * 32;
    int tx = threadIdx.x & 31, ty = threadIdx.x >> 5;
    #pragma unroll
    for (int r = 0; r < 4; r++) {
        int k = k0 + ty + r * 8, n = n0 + tx;
        tile[ty + r * 8][tx] = (k < K && n < N) ? W[(size_t)k * N + n] : 0.f;
    }
    __syncthreads();
    #pragma unroll
    for (int r = 0; r < 4; r++) {
        int n = n0 + ty + r * 8, k = k0 + tx;
        if (n < NP && k < KP)
            Wt[(size_t)n * KP + k] = f2b(tile[tx][ty + r * 8]);
    }
}

// ============ bf16 MFMA GEMM: C = act(A[M,K] @ Bt[N,K]^T + bias) ============
// 128x128 tile, BK=32, 4 waves (2x2 of 64x64), mfma_f32_16x16x32_bf16.
// LDS chunk-XOR swizzle (both-sides: pre-swizzled global src + swizzled read)
// kills the 8-way ds_read_b128 bank conflict. bf16 epilogue staged through LDS
// for full-row coalesced stores (fixes 2x HBM write amplification + RMW fetch).
// ACT: 0 none, 1 gelu(exact), 2 sigmoid. OF: write f32 Cf. OB: write bf16 Cb.
#define GLL(g, l) __builtin_amdgcn_global_load_lds( \
    (const __attribute__((address_space(1))) void*)(g), \
    (__attribute__((address_space(3))) void*)(l), 16, 0, 0)

template <int ACT, bool OF, bool OB>
__global__ __launch_bounds__(256) void bgemm(const ushort_t* __restrict__ A,
                                             const ushort_t* __restrict__ Bt,
                                             const float* __restrict__ bias,
                                             float* __restrict__ Cf,
                                             ushort_t* __restrict__ Cb,
                                             int Mdim, int Kdim, int Nout) {
    __shared__ ushort_t smem[17408];       // As[4096] | Bs[4096]; epilogue: C-tile [128][CSLD]
    ushort_t* As = smem;
    ushort_t* Bs = smem + 4096;
    const int tid = threadIdx.x;
    const int lane = tid & 63;
    const int wid = tid >> 6;
    const int m0 = blockIdx.y * 128;
    const int n0 = blockIdx.x * 128;
    const int wm = wid & 1, wn = wid >> 1;

    f4v acc[4][4];
    #pragma unroll
    for (int i = 0; i < 4; i++)
        #pragma unroll
        for (int j = 0; j < 4; j++)
            acc[i][j] = (f4v){0.f, 0.f, 0.f, 0.f};

    // staging: per wave, 2 instructions for A (16 rows x 32k each) + 2 for B.
    // global k-chunk pre-swizzled so linear LDS holds slot = chunk ^ ((row>>1)&3).
    const int srow = wid * 16 + (lane >> 2);
    const int skq = ((lane & 3) ^ ((lane >> 3) & 3)) * 8;
    int ar0 = m0 + srow;       if (ar0 > Mdim - 1) ar0 = Mdim - 1;
    int ar1 = m0 + 64 + srow;  if (ar1 > Mdim - 1) ar1 = Mdim - 1;
    const ushort_t* gA0 = A + (size_t)ar0 * Kdim + skq;
    const ushort_t* gA1 = A + (size_t)ar1 * Kdim + skq;
    const ushort_t* gB0 = Bt + (size_t)(n0 + srow) * Kdim + skq;
    const ushort_t* gB1 = Bt + (size_t)(n0 + 64 + srow) * Kdim + skq;
    ushort_t* lA0 = As + (wid * 16) * 32;
    ushort_t* lA1 = As + (64 + wid * 16) * 32;
    ushort_t* lB0 = Bs + (wid * 16) * 32;
    ushort_t* lB1 = Bs + (64 + wid * 16) * 32;

    const int lr = lane & 15;
    const int kc = (((lane >> 4) ^ ((lane >> 1) & 3))) * 8;  // swizzled read slot

    for (int k0 = 0; k0 < Kdim; k0 += 32) {
        GLL(gA0 + k0, lA0);
        GLL(gA1 + k0, lA1);
        GLL(gB0 + k0, lB0);
        GLL(gB1 + k0, lB1);
        __syncthreads();
        s8v af[4], bf[4];
        #pragma unroll
        for (int i = 0; i < 4; i++)
            af[i] = *(const s8v*)&As[(wm * 64 + i * 16 + lr) * 32 + kc];
        #pragma unroll
        for (int j = 0; j < 4; j++)
            bf[j] = *(const s8v*)&Bs[(wn * 64 + j * 16 + lr) * 32 + kc];
        #pragma unroll
        for (int i = 0; i < 4; i++)
            #pragma unroll
            for (int j = 0; j < 4; j++)
                acc[i][j] = __builtin_amdgcn_mfma_f32_16x16x32_bf16(af[i], bf[j], acc[i][j], 0, 0, 0);
        __syncthreads();
    }

    // epilogue: C/D layout col=lane&15, row=(lane>>4)*4+reg
    const int orow = (lane >> 4) * 4;
    if (OF) {
        #pragma unroll
        for (int j = 0; j < 4; j++) {
            int col = n0 + wn * 64 + j * 16 + lr;
            bool cok = col < Nout;
            float bb = cok ? bias[col] : 0.f;
            #pragma unroll
            for (int i = 0; i < 4; i++) {
                #pragma unroll
                for (int r = 0; r < 4; r++) {
                    int row = m0 + wm * 64 + i * 16 + orow + r;
                    if (cok && row < Mdim) {
                        float v = acc[i][j][r] + bb;
                        if (ACT == 1) v = 0.5f * v * (1.0f + erff(v * 0.70710678118654752f));
                        if (ACT == 2) v = 1.0f / (1.0f + expf(-v));
                        Cf[(size_t)row * Nout + col] = v;
                    }
                }
            }
        }
    }
    if (OB) {
        // stage bf16 tile in LDS (quadrants disjoint; K-loop's final barrier protects As/Bs)
        #pragma unroll
        for (int j = 0; j < 4; j++) {
            int cl = wn * 64 + j * 16 + lr;
            int gcol = n0 + cl;
            float bb = (gcol < Nout) ? bias[gcol] : 0.f;
            #pragma unroll
            for (int i = 0; i < 4; i++) {
                #pragma unroll
                for (int r = 0; r < 4; r++) {
                    float v = acc[i][j][r] + bb;
                    if (ACT == 1) v = 0.5f * v * (1.0f + erff(v * 0.70710678118654752f));
                    if (ACT == 2) v = 1.0f / (1.0f + expf(-v));
                    smem[(wm * 64 + i * 16 + orow + r) * CSLD + cl] = f2b(v);
                }
            }
        }
        __syncthreads();
        // coalesced copy-out: 16B per lane, 256B contiguous per row
        #pragma unroll
        for (int c = 0; c < 8; c++) {
            int idx = c * 256 + tid;
            int row = idx >> 4, cs = idx & 15;
            int grow = m0 + row, gcol = n0 + cs * 8;
            if (grow < Mdim) {
                if (gcol + 8 <= Nout) {
                    *(s8v*)&Cb[(size_t)grow * Nout + gcol] = *(const s8v*)&smem[row * CSLD + cs * 8];
                } else if (gcol < Nout) {
                    for (int q = 0; q < Nout - gcol; q++)
                        Cb[(size_t)grow * Nout + gcol + q] = smem[row * CSLD + cs * 8 + q];
                }
            }
        }
    }
}

// ============ fused QKV GEMM: [NTOK,512] @ [1536,512]^T -> qkvb [NTOK,1536] bf16 ============
// sections: col<512 Q (sigmoid), <1024 K (sigmoid), else V (none). K=512, N=1536 exact.
__global__ __launch_bounds__(256) void bgemm_qkv(const ushort_t* __restrict__ A,
                                                 const ushort_t* __restrict__ Bt,
                                                 const float* __restrict__ bq_,
                                                 const float* __restrict__ bk_,
                                                 const float* __restrict__ bv_,
                                                 ushort_t* __restrict__ Cb,
                                                 int Mdim) {
    __shared__ ushort_t smem[17408];
    ushort_t* As = smem;
    ushort_t* Bs = smem + 4096;
    const int tid = threadIdx.x;
    const int lane = tid & 63;
    const int wid = tid >> 6;
    const int m0 = blockIdx.y * 128;
    const int n0 = blockIdx.x * 128;
    const int wm = wid & 1, wn = wid >> 1;

    f4v acc[4][4];
    #pragma unroll
    for (int i = 0; i < 4; i++)
        #pragma unroll
        for (int j = 0; j < 4; j++)
            acc[i][j] = (f4v){0.f, 0.f, 0.f, 0.f};

    const int srow = wid * 16 + (lane >> 2);
    const int skq = ((lane & 3) ^ ((lane >> 3) & 3)) * 8;
    int ar0 = m0 + srow;       if (ar0 > Mdim - 1) ar0 = Mdim - 1;
    int ar1 = m0 + 64 + srow;  if (ar1 > Mdim - 1) ar1 = Mdim - 1;
    const ushort_t* gA0 = A + (size_t)ar0 * DD + skq;
    const ushort_t* gA1 = A + (size_t)ar1 * DD + skq;
    const ushort_t* gB0 = Bt + (size_t)(n0 + srow) * DD + skq;
    const ushort_t* gB1 = Bt + (size_t)(n0 + 64 + srow) * DD + skq;
    ushort_t* lA0 = As + (wid * 16) * 32;
    ushort_t* lA1 = As + (64 + wid * 16) * 32;
    ushort_t* lB0 = Bs + (wid * 16) * 32;
    ushort_t* lB1 = Bs + (64 + wid * 16) * 32;

    const int lr = lane & 15;
    const int kc = (((lane >> 4) ^ ((lane >> 1) & 3))) * 8;

    for (int k0 = 0; k0 < DD; k0 += 32) {
        GLL(gA0 + k0, lA0);
        GLL(gA1 + k0, lA1);
        GLL(gB0 + k0, lB0);
        GLL(gB1 + k0, lB1);
        __syncthreads();
        s8v af[4], bf[4];
        #pragma unroll
        for (int i = 0; i < 4; i++)
            af[i] = *(const s8v*)&As[(wm * 64 + i * 16 + lr) * 32 + kc];
        #pragma unroll
        for (int j = 0; j < 4; j++)
            bf[j] = *(const s8v*)&Bs[(wn * 64 + j * 16 + lr) * 32 + kc];
        #pragma unroll
        for (int i = 0; i < 4; i++)
            #pragma unroll
            for (int j = 0; j < 4; j++)
                acc[i][j] = __builtin_amdgcn_mfma_f32_16x16x32_bf16(af[i], bf[j], acc[i][j], 0, 0, 0);
        __syncthreads();
    }

    const int orow = (lane >> 4) * 4;
    #pragma unroll
    for (int j = 0; j < 4; j++) {
        int cl = wn * 64 + j * 16 + lr;
        int col = n0 + cl;
        int sec = col >> 9;
        const float* bsel = (sec == 0) ? bq_ : ((sec == 1) ? bk_ : bv_);
        float bb = bsel[col & 511];
        #pragma unroll
        for (int i = 0; i < 4; i++) {
            #pragma unroll
            for (int r = 0; r < 4; r++) {
                float v = acc[i][j][r] + bb;
                if (sec < 2) v = 1.0f / (1.0f + expf(-v));
                smem[(wm * 64 + i * 16 + orow + r) * CSLD + cl] = f2b(v);
            }
        }
    }
    __syncthreads();
    #pragma unroll
    for (int c = 0; c < 8; c++) {
        int idx = c * 256 + tid;
        int row = idx >> 4, cs = idx & 15;
        int grow = m0 + row;
        if (grow < Mdim)
            *(s8v*)&Cb[(size_t)grow * QS + n0 + cs * 8] = *(const s8v*)&smem[row * CSLD + cs * 8];
    }
}

// ============ LayerNorm over D=512: x_f32 = LN(x + res_bf16); also write bf16 copy ============
__global__ __launch_bounds__(256) void ln_kernel(float* __restrict__ x,
                                                 const ushort_t* __restrict__ res,
                                                 const float* __restrict__ w,
                                                 const float* __restrict__ bp,
                                                 ushort_t* __restrict__ xb) {
    size_t base = (size_t)blockIdx.x * DD;
    int tid = threadIdx.x;
    float v0 = x[base + tid];
    float v1 = x[base + tid + 256];
    if (res != nullptr) { v0 += b2f(res[base + tid]); v1 += b2f(res[base + tid + 256]); }
    float s = wave_sum(v0 + v1);
    float s2 = wave_sum(v0 * v0 + v1 * v1);
    __shared__ float a1[4], a2[4];
    if ((tid & 63) == 0) { a1[tid >> 6] = s; a2[tid >> 6] = s2; }
    __syncthreads();
    s = a1[0] + a1[1] + a1[2] + a1[3];
    s2 = a2[0] + a2[1] + a2[2] + a2[3];
    float mu = s * (1.0f / DD);
    float var = s2 * (1.0f / DD) - mu * mu;
    float rs = rsqrtf(var + 1e-5f);
    float o0 = (v0 - mu) * rs * w[tid] + bp[tid];
    float o1 = (v1 - mu) * rs * w[tid + 256] + bp[tid + 256];
    x[base + tid] = o0;
    x[base + tid + 256] = o1;
    xb[base + tid] = f2b(o0);
    xb[base + tid + 256] = f2b(o1);
}

// ============ attention: per (b,h) column sums over l (optionally weighted) ============
// Q/Kp point into qkvb (stride QS). l-split LSPLIT-way: grid (NBH, LSPLIT).
template <bool WEIGHTED>
__global__ __launch_bounds__(256) void attn_sums(const ushort_t* __restrict__ Q,
                                                 const ushort_t* __restrict__ Kp,
                                                 const float* __restrict__ wq,
                                                 const float* __restrict__ wk,
                                                 float* __restrict__ qsumP,
                                                 float* __restrict__ ksumP) {
    int bh = blockIdx.x;
    int sp = blockIdx.y;
    int b = bh >> 3, h = bh & 7;
    int lane = threadIdx.x & 63, g = threadIdx.x >> 6;
    int eo = (lane & 7) * 8;
    int lofs = lane >> 3;
    const size_t base = ((size_t)b * LTOK) * QS + h * 64 + eo;
    float aq[8] = {}, ak[8] = {};
    int lend = sp * LCHUNK + LCHUNK; if (lend > LTOK) lend = LTOK;
    for (int l = sp * LCHUNK + g * 8 + lofs; l < lend; l += 32) {
        s8v q8 = *(const s8v*)&Q[base + (size_t)l * QS];
        s8v k8 = *(const s8v*)&Kp[base + (size_t)l * QS];
        float wqv = 1.f, wkv = 1.f;
        if (WEIGHTED) { wqv = wq[bh * LTOK + l]; wkv = wk[bh * LTOK + l]; }
        #pragma unroll
        for (int j = 0; j < 8; j++) {
            aq[j] += b2f((ushort_t)q8[j]) * wqv;
            ak[j] += b2f((ushort_t)k8[j]) * wkv;
        }
    }
    #pragma unroll
    for (int off = 8; off < 64; off <<= 1) {
        #pragma unroll
        for (int j = 0; j < 8; j++) {
            aq[j] += __shfl_xor(aq[j], off, 64);
            ak[j] += __shfl_xor(ak[j], off, 64);
        }
    }
    __shared__ float sqs[4][64], sks[4][64];
    if (lofs == 0) {
        #pragma unroll
        for (int j = 0; j < 8; j++) { sqs[g][eo + j] = aq[j]; sks[g][eo + j] = ak[j]; }
    }
    __syncthreads();
    if (threadIdx.x < 64) {
        int e = threadIdx.x;
        float fq = sqs[0][e] + sqs[1][e] + sqs[2][e] + sqs[3][e];
        float fk = sks[0][e] + sks[1][e] + sks[2][e] + sks[3][e];
        qsumP[((size_t)sp * NBH + bh) * 64 + e] = fq;
        ksumP[((size_t)sp * NBH + bh) * 64 + e] = fk;
    }
}

// ============ attention: per-l dot with summed vector (sums LSPLIT partials) ============
template <int MODE>
__global__ __launch_bounds__(256) void attn_dots(const ushort_t* __restrict__ Q,
                                                 const ushort_t* __restrict__ Kp,
                                                 const float* __restrict__ Sq,
                                                 const float* __restrict__ Sk,
                                                 float* __restrict__ outq,
                                                 float* __restrict__ outk) {
    int bh = blockIdx.x;
    int b = bh >> 3, h = bh & 7;
    int lane = threadIdx.x & 63, w = threadIdx.x >> 6;
    float sq = 0.f, sk = 0.f;
    #pragma unroll
    for (int sp = 0; sp < LSPLIT; sp++) {
        sq += Sq[((size_t)sp * NBH + bh) * 64 + lane];
        sk += Sk[((size_t)sp * NBH + bh) * 64 + lane];
    }
    sq += 1e-6f; sk += 1e-6f;
    const size_t base = ((size_t)b * LTOK) * QS + h * 64 + lane;
    int l0 = blockIdx.y * 64 + w * 16;
    for (int i = 0; i < 16; i++) {
        int l = l0 + i;
        if (l >= LTOK) break;
        float dq = (b2f(Q[base + (size_t)l * QS]) + 1e-6f) * sq;
        float dk = (b2f(Kp[base + (size_t)l * QS]) + 1e-6f) * sk;
        dq = wave_sum(dq);
        dk = wave_sum(dk);
        if (lane == 0) {
            if (MODE == 0) { outq[bh * LTOK + l] = 1.0f / dq; outk[bh * LTOK + l] = 1.0f / dk; }
            else { outq[bh * LTOK + l] = 1.0f / (1.0f + expf(-dq)); outk[bh * LTOK + l] = dk; }
        }
    }
}

// ============ attention: softmax over s (in place), scaled by Ls ============
__global__ __launch_bounds__(256) void attn_softmax(float* __restrict__ buf) {
    float* p = buf + (size_t)blockIdx.x * LTOK;
    int tid = threadIdx.x;
    __shared__ float red[4];
    float mx = -1e30f;
    for (int l = tid; l < LTOK; l += 256) mx = fmaxf(mx, p[l]);
    #pragma unroll
    for (int off = 32; off; off >>= 1) mx = fmaxf(mx, __shfl_xor(mx, off, 64));
    if ((tid & 63) == 0) red[tid >> 6] = mx;
    __syncthreads();
    mx = fmaxf(fmaxf(red[0], red[1]), fmaxf(red[2], red[3]));
    __syncthreads();
    float s = 0.f;
    for (int l = tid; l < LTOK; l += 256) s += expf(p[l] - mx);
    s = wave_sum(s);
    if ((tid & 63) == 0) red[tid >> 6] = s;
    __syncthreads();
    s = red[0] + red[1] + red[2] + red[3];
    float scale = (float)LTOK / s;
    for (int l = tid; l < LTOK; l += 256) p[l] = expf(p[l] - mx) * scale;
}

// ============ attention: kv[e,d] = sum_s k[s,e] * v[s,d] * ncref[s] ============
// Kp/V point into qkvb (stride QS). s-split: grid (NBH, KVSPLIT).
__global__ __launch_bounds__(256) void attn_kv_part(const ushort_t* __restrict__ Kp,
                                                    const ushort_t* __restrict__ V,
                                                    const float* __restrict__ ncref,
                                                    float* __restrict__ kvpart) {
    int bh = blockIdx.x;
    int sp = blockIdx.y;
    int b = bh >> 3, h = bh & 7;
    int d = threadIdx.x & 63, eg = threadIdx.x >> 6;
    __shared__ float ks[16][64], vs[16][64];
    float acc[16] = {};
    const size_t base = ((size_t)b * LTOK) * QS + h * 64;
    const int s_begin = sp * KVCHUNK;
    int s_end = s_begin + KVCHUNK; if (s_end > LTOK) s_end = LTOK;

    const bool isV = threadIdx.x >= 128;       // wave-uniform split
    const int slot = threadIdx.x & 127;        // 16 rows x 8 vec-slots
    const int srow = slot >> 3;
    const int e0 = (slot & 7) * 8;
    const ushort_t* src = isV ? V : Kp;

    for (int s0 = s_begin; s0 < s_end; s0 += 16) {
        __syncthreads();
        int s = s0 + srow;
        float vals[8] = {};
        if (s < s_end) {
            s8v raw = *(const s8v*)&src[base + (size_t)s * QS + e0];
            float mul = isV ? ncref[bh * LTOK + s] : 1.f;
            #pragma unroll
            for (int j = 0; j < 8; j++) vals[j] = b2f((ushort_t)raw[j]) * mul;
        }
        float (*dst)[64] = isV ? vs : ks;
        #pragma unroll
        for (int j = 0; j < 8; j++) dst[srow][e0 + j] = vals[j];
        __syncthreads();
        int nsi = s_end - s0; if (nsi > 16) nsi = 16;
        for (int si = 0; si < nsi; si++) {
            float vv = vs[si][d];
            #pragma unroll
            for (int i = 0; i < 16; i++) acc[i] += ks[si][eg * 16 + i] * vv;
        }
    }
    #pragma unroll
    for (int i = 0; i < 16; i++)
        kvpart[((size_t)sp * NBH + bh) * 4096 + (eg * 16 + i) * 64 + d] = acc[i];
}

// ============ reduce kv partials -> kvT bf16: kvtb[bh][d][e] = sum_sp part[sp][bh][e*64+d] ============
__global__ __launch_bounds__(256) void kv_reduce(const float* __restrict__ part,
                                                 ushort_t* __restrict__ kvtb) {
    size_t idx = (size_t)blockIdx.x * 256 + threadIdx.x;   // NBH*4096 total, idx = bh*4096 + e*64 + d
    float s = 0.f;
    #pragma unroll
    for (int sp = 0; sp < KVSPLIT; sp++)
        s += part[(size_t)sp * ((size_t)NBH * 4096) + idx];
    size_t bhbase = idx & ~(size_t)4095;
    int e = (int)((idx >> 6) & 63), d = (int)(idx & 63);
    kvtb[bhbase + (size_t)d * 64 + e] = f2b(s);
}

// ============ attention out via MFMA: out[l,d] = (Q[l,:] @ kv[:,d]) * nr[l]*nrref[l] ============
// Q from qkvb (stride QS); out (stride DD) bf16. grid (NBH, 4); 4 waves x 64 rows.
__global__ __launch_bounds__(256) void attn_out_mfma(const ushort_t* __restrict__ Q,
                                                     const ushort_t* __restrict__ kvtb,
                                                     const float* __restrict__ nr,
                                                     const float* __restrict__ nrref,
                                                     ushort_t* __restrict__ out) {
    int bh = blockIdx.x;
    int b = bh >> 3, h = bh & 7;
    const int lane = threadIdx.x & 63;
    const int wid = threadIdx.x >> 6;
    const int m0 = blockIdx.y * 256 + wid * 64;
    const int lr = lane & 15;
    const int kq = (lane >> 4) * 8;
    const size_t qbase = ((size_t)b * LTOK) * QS + h * 64;
    const size_t obase = ((size_t)b * LTOK) * DD + h * 64;

    s8v bf[2][4];
    #pragma unroll
    for (int ks = 0; ks < 2; ks++)
        #pragma unroll
        for (int j = 0; j < 4; j++)
            bf[ks][j] = *(const s8v*)&kvtb[(size_t)bh * 4096 + (size_t)(j * 16 + lr) * 64 + ks * 32 + kq];

    f4v acc[4][4];
    #pragma unroll
    for (int i = 0; i < 4; i++)
        #pragma unroll
        for (int j = 0; j < 4; j++)
            acc[i][j] = (f4v){0.f, 0.f, 0.f, 0.f};

    #pragma unroll
    for (int ks = 0; ks < 2; ks++) {
        #pragma unroll
        for (int i = 0; i < 4; i++) {
            int row = m0 + i * 16 + lr;
            if (row > LTOK - 1) row = LTOK - 1;   // clamp; those rows never written
            s8v af = *(const s8v*)&Q[qbase + (size_t)row * QS + ks * 32 + kq];
            #pragma unroll
            for (int j = 0; j < 4; j++)
                acc[i][j] = __builtin_amdgcn_mfma_f32_16x16x32_bf16(af, bf[ks][j], acc[i][j], 0, 0, 0);
        }
    }

    const int orow = (lane >> 4) * 4;
    #pragma unroll
    for (int i = 0; i < 4; i++) {
        #pragma unroll
        for (int r = 0; r < 4; r++) {
            int l = m0 + i * 16 + orow + r;
            if (l >= LTOK) continue;
            float sc = nr[bh * LTOK + l] * nrref[bh * LTOK + l];
            #pragma unroll
            for (int j = 0; j < 4; j++) {
                int d = j * 16 + lr;
                out[obase + (size_t)l * DD + d] = f2b(acc[i][j][r] * sc);
            }
        }
    }
}

// ============ final: transpose from projb[NTOK,720] bf16, RevIN denorm ============
__global__ __launch_bounds__(256) void final_out(const ushort_t* __restrict__ p,
                                                 const float* __restrict__ mean,
                                                 const float* __restrict__ stdev,
                                                 const float* __restrict__ rw,
                                                 const float* __restrict__ rb,
                                                 float* __restrict__ out) {
    int b = blockIdx.z;
    int c0 = blockIdx.x * 32, t0 = blockIdx.y * 32;
    __shared__ float tile[32][33];
    int tx = threadIdx.x & 31, ty = threadIdx.x >> 5;
    #pragma unroll
    for (int kk = 0; kk < 4; kk++) {
        int c = c0 + ty + kk * 8, t = t0 + tx;
        float v = 0.f;
        if (c < CC && t < TT) v = b2f(p[((size_t)b * LTOK + c) * TT + t]);
        tile[ty + kk * 8][tx] = v;
    }
    __syncthreads();
    #pragma unroll
    for (int kk = 0; kk < 4; kk++) {
        int t = t0 + ty + kk * 8, c = c0 + tx;
        if (c < CC && t < TT) {
            float v = tile[tx][ty + kk * 8];
            v = (v - rb[c]) / (rw[c] + 1e-10f);
            v = v * stdev[b * CC + c] + mean[b * CC + c];
            out[((size_t)b * TT + t) * CC + c] = v;
        }
    }
}

extern "C" void kernel_launch(void* const* d_in, const int* in_sizes, int n_in,
                              void* d_out, int out_size, void* d_ws, size_t ws_size,
                              hipStream_t stream) {
    (void)in_sizes; (void)n_in; (void)out_size; (void)ws_size;
    const float* x_enc   = (const float*)d_in[0];
    const float* x_mark  = (const float*)d_in[1];
    const float* revin_w = (const float*)d_in[4];
    const float* revin_b = (const float*)d_in[5];
    const float* emb_W   = (const float*)d_in[6];
    const float* emb_b   = (const float*)d_in[7];
    const float* Wq = (const float*)d_in[8];
    const float* bq = (const float*)d_in[9];
    const float* Wk = (const float*)d_in[10];
    const float* bk = (const float*)d_in[11];
    const float* Wv = (const float*)d_in[12];
    const float* bv = (const float*)d_in[13];
    const float* Wo = (const float*)d_in[14];
    const float* bo = (const float*)d_in[15];
    const float* ff1_W = (const float*)d_in[16];
    const float* ff1_b = (const float*)d_in[17];
    const float* ff2_W = (const float*)d_in[18];
    const float* ff2_b = (const float*)d_in[19];
    const float* ln1_w = (const float*)d_in[20];
    const float* ln1_b = (const float*)d_in[21];
    const float* ln2_w = (const float*)d_in[22];
    const float* ln2_b = (const float*)d_in[23];
    const float* lnf_w = (const float*)d_in[24];
    const float* lnf_b = (const float*)d_in[25];
    const float* proj_W = (const float*)d_in[26];
    const float* proj_b = (const float*)d_in[27];
    float* out = (float*)d_out;

    // ---- workspace layout (~240 MB) ----
    char* wsb = (char*)d_ws;
    size_t off = 0;
    auto alloc = [&](size_t bytes) {
        off = (off + 63) & ~(size_t)63;
        void* p = wsb + off; off += bytes; return p;
    };
    float* mean  = (float*)alloc((size_t)BB * CC * 4);
    float* stdev = (float*)alloc((size_t)BB * CC * 4);
    float* pS    = (float*)alloc((size_t)TSPL * BB * CC * 4);
    float* pS2   = (float*)alloc((size_t)TSPL * BB * CC * 4);
    float* qsumP  = (float*)alloc((size_t)LSPLIT * NBH * 64 * 4);
    float* ksumP  = (float*)alloc((size_t)LSPLIT * NBH * 64 * 4);
    float* qnsumP = (float*)alloc((size_t)LSPLIT * NBH * 64 * 4);
    float* knsumP = (float*)alloc((size_t)LSPLIT * NBH * 64 * 4);
    float* nr    = (float*)alloc((size_t)NBH * LTOK * 4);
    float* nc    = (float*)alloc((size_t)NBH * LTOK * 4);
    float* nrref = (float*)alloc((size_t)NBH * LTOK * 4);
    float* ncref = (float*)alloc((size_t)NBH * LTOK * 4);
    ushort_t* kvtb = (ushort_t*)alloc((size_t)NBH * 4096 * 2); // reduced kv, transposed [d][e], bf16
    float* x     = (float*)alloc((size_t)NTOK * DD * 4);          // fp32 residual spine
    ushort_t* xb = (ushort_t*)alloc((size_t)NTOK * DD * 2);       // bf16 copy of x
    ushort_t* qkvb = (ushort_t*)alloc((size_t)NTOK * QS * 2);     // fused QKV [NTOK,1536]
    ushort_t* wbuf = (ushort_t*)alloc((size_t)10207232 * 2);      // all bf16 transposed weights
    ushort_t* U  = (ushort_t*)alloc((size_t)NTOK * KPAD * 2);     // union: tokb/ff-chunk/projb/kvpart/ab

    // weight sub-buffers
    ushort_t* embT = wbuf;                          // [512,736]
    ushort_t* qkvT = embT + (size_t)512 * KPAD;     // 3 layers x [1536,512] (q,k,v stacked)
    ushort_t* oT   = qkvT + (size_t)3 * 786432;     // 3 x [512,512]
    ushort_t* f1T  = oT + 3 * 262144;               // 3 x [2048,512]
    ushort_t* f2T  = f1T + (size_t)3 * 1048576;     // 3 x [512,2048]
    ushort_t* pT   = f2T + (size_t)3 * 1048576;     // [768,512]
    ushort_t* tokb  = U;                             // [NTOK, 736]
    ushort_t* ffb   = U;                             // chunk [6912, 2048]
    ushort_t* projb = U;                             // [NTOK, 720]
    float* kvpart   = (float*)U;                     // [KVSPLIT, NBH, 4096] = 33.5MB
    ushort_t* ab    = U;                             // attn output [NTOK,512] (after kvpart dead)
    ushort_t* tmpb  = qkvb;                          // Wo/FF2 output (qkv dead by then)

    dim3 blk(256);
    // ---- weight conversion (transpose to [N,K] bf16) ----
    auto cvt = [&](const float* W, ushort_t* Wt, int K, int N, int KP, int NP) {
        convT<<<dim3((KP + 31) / 32, (NP + 31) / 32), blk, 0, stream>>>(W, Wt, K, N, KP, NP);
    };
    cvt(emb_W, embT, TT, DD, KPAD, DD);
    for (int l = 0; l < 3; l++) {
        ushort_t* lb = qkvT + (size_t)l * 786432;
        cvt(Wq + (size_t)l * DD * DD, lb,          DD, DD, DD, DD);
        cvt(Wk + (size_t)l * DD * DD, lb + 262144, DD, DD, DD, DD);
        cvt(Wv + (size_t)l * DD * DD, lb + 524288, DD, DD, DD, DD);
        cvt(Wo + (size_t)l * DD * DD, oT + (size_t)l * 262144, DD, DD, DD, DD);
        cvt(ff1_W + (size_t)l * DD * FFD, f1T + (size_t)l * 1048576, DD, FFD, DD, FFD);
        cvt(ff2_W + (size_t)l * FFD * DD, f2T + (size_t)l * 1048576, FFD, DD, FFD, DD);
    }
    cvt(proj_W, pT, DD, TT, DD, NPADP);

    // ---- RevIN (t-split) + tokens + embedding ----
    revin_part<<<dim3((CC + 63) / 64, BB, TSPL), blk, 0, stream>>>(x_enc, pS, pS2);
    revin_fin<<<dim3((BB * CC + 255) / 256), blk, 0, stream>>>(pS, pS2, mean, stdev);
    build_tok<<<dim3((LTOK + 31) / 32, (KPAD + 31) / 32, BB), blk, 0, stream>>>(
        x_enc, x_mark, mean, stdev, revin_w, revin_b, tokb);
    const int MT = (NTOK + 127) / 128;   // 217
    bgemm<0, true, true><<<dim3(DD / 128, MT), blk, 0, stream>>>(
        tokb, embT, emb_b, x, xb, NTOK, KPAD, DD);

    int ltiles = (LTOK + 63) / 64;
    for (int l = 0; l < 3; l++) {
        bgemm_qkv<<<dim3(QS / 128, MT), blk, 0, stream>>>(
            xb, qkvT + (size_t)l * 786432, bq + l * DD, bk + l * DD, bv + l * DD,
            qkvb, NTOK);
        attn_sums<false><<<dim3(NBH, LSPLIT), blk, 0, stream>>>(
            qkvb, qkvb + 512, nullptr, nullptr, qsumP, ksumP);
        attn_dots<0><<<dim3(NBH, ltiles), blk, 0, stream>>>(
            qkvb, qkvb + 512, ksumP, qsumP, nr, nc);
        attn_sums<true><<<dim3(NBH, LSPLIT), blk, 0, stream>>>(
            qkvb, qkvb + 512, nr, nc, qnsumP, knsumP);
        attn_dots<1><<<dim3(NBH, ltiles), blk, 0, stream>>>(
            qkvb, qkvb + 512, knsumP, qnsumP, nrref, ncref);
        attn_softmax<<<NBH, blk, 0, stream>>>(ncref);
        attn_kv_part<<<dim3(NBH, KVSPLIT), blk, 0, stream>>>(
            qkvb + 512, qkvb + 1024, ncref, kvpart);
        kv_reduce<<<dim3((NBH * 4096) / 256), blk, 0, stream>>>(kvpart, kvtb);
        attn_out_mfma<<<dim3(NBH, 4), blk, 0, stream>>>(qkvb, kvtb, nr, nrref, ab);
        // Wo: A = attention output (ab), out -> tmpb (qkvb region, dead)
        bgemm<0, false, true><<<dim3(DD / 128, MT), blk, 0, stream>>>(
            ab, oT + (size_t)l * 262144, bo + l * DD, nullptr, tmpb, NTOK, DD, DD);
        ln_kernel<<<NTOK, blk, 0, stream>>>(x, tmpb, ln1_w + l * DD, ln1_b + l * DD, xb);
        // FF chunked over rows (ff activation fits in U)
        for (int t0 = 0; t0 < NTOK / 64; t0 += 108) {
            int nt = NTOK / 64 - t0; if (nt > 108) nt = 108;
            int rs = t0 * 64, mc = nt * 64;
            bgemm<1, false, true><<<dim3(FFD / 128, (mc + 127) / 128), blk, 0, stream>>>(
                xb + (size_t)rs * DD, f1T + (size_t)l * 1048576, ff1_b + l * FFD,
                nullptr, ffb, mc, DD, FFD);
            bgemm<0, false, true><<<dim3(DD / 128, (mc + 127) / 128), blk, 0, stream>>>(
                ffb, f2T + (size_t)l * 1048576, ff2_b + l * DD,
                nullptr, tmpb + (size_t)rs * DD, mc, FFD, DD);
        }
        ln_kernel<<<NTOK, blk, 0, stream>>>(x, tmpb, ln2_w + l * DD, ln2_b + l * DD, xb);
    }
    ln_kernel<<<NTOK, blk, 0, stream>>>(x, nullptr, lnf_w, lnf_b, xb);
    // projection: [NTOK,512] @ [512,768(pad)] -> projb [NTOK,720] bf16
    bgemm<0, false, true><<<dim3(NPADP / 128, MT), blk, 0, stream>>>(
        xb, pT, proj_b, nullptr, projb, NTOK, DD, TT);
    final_out<<<dim3((CC + 31) / 32, (TT + 31) / 32, BB), blk, 0, stream>>>(
        projb, mean, stdev, revin_w, revin_b, out);
}

// Round 6
// 2735.869 us; speedup vs baseline: 1.5487x; 1.0261x over previous
//
#include <hip/hip_runtime.h>
#include <math.h>

// ---- problem constants ----
#define BB 32
#define TT 720
#define CC 862
#define MM 4
#define LTOK 866          // C + M tokens
#define DD 512
#define HH 8
#define EE 64
#define FFD 2048
#define NTOK (BB * LTOK)  // 27712 = 433*64
#define NBH (BB * HH)     // 256
#define KPAD 736          // 720 padded to mult of 32 (embedding K)
#define NPADP 768         // 720 padded to mult of 128 (proj N tiles)
#define LSPLIT 4          // attn_sums l-split
#define LCHUNK 224        // ceil(866/4) rounded to mult of 32
#define KVSPLIT 8         // attn_kv s-split
#define KVCHUNK 112       // ceil(866/8) rounded to mult of 16
#define QS 1536           // fused QKV row stride
#define TSPL 8            // revin t-split
#define TCH 90            // 720 / TSPL
#define CSLD 136          // C-tile LDS row stride (ushorts); 272B = 17x16B aligned

typedef unsigned short ushort_t;
typedef short s8v __attribute__((ext_vector_type(8)));
typedef float f4v __attribute__((ext_vector_type(4)));

__device__ __forceinline__ float wave_sum(float v) {
    #pragma unroll
    for (int off = 32; off; off >>= 1) v += __shfl_xor(v, off, 64);
    return v;
}
__device__ __forceinline__ float b2f(ushort_t u) {
    return __uint_as_float(((unsigned int)u) << 16);
}
__device__ __forceinline__ ushort_t f2b(float f) {
    unsigned int u = __float_as_uint(f);
    u = (u + 0x7FFFu + ((u >> 16) & 1u)) >> 16;
    return (ushort_t)u;
}

// XCD-aware bijective block swizzle (m204): same-m blocks land on one XCD's L2.
// HW round-robins linear bid across 8 XCDs; remap so each XCD owns a contiguous
// run of work-ids (n fastest within m). Bijective for any nwg.
__device__ __forceinline__ void xcd_tile(int gx, int* m_t, int* n_t) {
    int nwg = gx * gridDim.y;
    int bid = blockIdx.y * gx + blockIdx.x;
    int xcd = bid & 7;
    int lid = bid >> 3;
    int q = nwg >> 3, r = nwg & 7;
    int wgid = (xcd < r ? xcd * (q + 1) : r * (q + 1) + (xcd - r) * q) + lid;
    *m_t = wgid / gx;
    *n_t = wgid % gx;
}

// ============ RevIN stats stage 1: partial sums over t-chunk ============
__global__ __launch_bounds__(256) void revin_part(const float* __restrict__ x_enc,
                                                  float* __restrict__ pS,
                                                  float* __restrict__ pS2) {
    int b = blockIdx.y, tz = blockIdx.z;
    int c = blockIdx.x * 64 + (threadIdx.x & 63);
    int g = threadIdx.x >> 6;
    float s = 0.f, s2 = 0.f;
    if (c < CC) {
        int t0 = tz * TCH;
        for (int t = t0 + g; t < t0 + TCH; t += 4) {
            float v = x_enc[((size_t)b * TT + t) * CC + c];
            s += v; s2 += v * v;
        }
    }
    __shared__ float ls[4][64], ls2[4][64];
    ls[g][threadIdx.x & 63] = s; ls2[g][threadIdx.x & 63] = s2;
    __syncthreads();
    if (g == 0 && c < CC) {
        int cx = threadIdx.x & 63;
        s = ls[0][cx] + ls[1][cx] + ls[2][cx] + ls[3][cx];
        s2 = ls2[0][cx] + ls2[1][cx] + ls2[2][cx] + ls2[3][cx];
        pS[((size_t)tz * BB + b) * CC + c] = s;
        pS2[((size_t)tz * BB + b) * CC + c] = s2;
    }
}

// ============ RevIN stats stage 2: finalize mean/stdev ============
__global__ __launch_bounds__(256) void revin_fin(const float* __restrict__ pS,
                                                 const float* __restrict__ pS2,
                                                 float* __restrict__ mean,
                                                 float* __restrict__ stdev) {
    int idx = blockIdx.x * 256 + threadIdx.x;
    if (idx >= BB * CC) return;
    float s = 0.f, s2 = 0.f;
    #pragma unroll
    for (int tz = 0; tz < TSPL; tz++) {
        s += pS[(size_t)tz * BB * CC + idx];
        s2 += pS2[(size_t)tz * BB * CC + idx];
    }
    float mu = s / (float)TT;
    float var = s2 / (float)TT - mu * mu;
    mean[idx] = mu;
    stdev[idx] = sqrtf(var + 1e-5f);
}

// ============ build tokb[B,866,736] bf16: normalized channels + marks, K-padded ============
__global__ __launch_bounds__(256) void build_tok(const float* __restrict__ x_enc,
                                                 const float* __restrict__ x_mark,
                                                 const float* __restrict__ mean,
                                                 const float* __restrict__ stdev,
                                                 const float* __restrict__ rw,
                                                 const float* __restrict__ rb,
                                                 ushort_t* __restrict__ tok) {
    int b = blockIdx.z;
    int r0 = blockIdx.x * 32, t0 = blockIdx.y * 32;
    __shared__ float tile[32][33];
    int tx = threadIdx.x & 31, ty = threadIdx.x >> 5;
    #pragma unroll
    for (int kk = 0; kk < 4; kk++) {
        int t = t0 + ty + kk * 8, r = r0 + tx;
        float v = 0.f;
        if (t < TT && r < LTOK) {
            if (r < CC) {
                float xv = x_enc[((size_t)b * TT + t) * CC + r];
                v = (xv - mean[b * CC + r]) / stdev[b * CC + r] * rw[r] + rb[r];
            } else {
                v = x_mark[((size_t)b * TT + t) * MM + (r - CC)];
            }
        }
        tile[ty + kk * 8][tx] = v;
    }
    __syncthreads();
    #pragma unroll
    for (int kk = 0; kk < 4; kk++) {
        int r = r0 + ty + kk * 8, t = t0 + tx;
        if (r < LTOK && t < KPAD)
            tok[((size_t)b * LTOK + r) * KPAD + t] = f2b(tile[tx][ty + kk * 8]);
    }
}

// ============ weight convert+transpose: W[K,N] f32 -> Wt[NP,KP] bf16 (zero-padded) ============
__global__ __launch_bounds__(256) void convT(const float* __restrict__ W,
                                             ushort_t* __restrict__ Wt,
                                             int K, int N, int KP, int NP) {
    __shared__ float tile[32][33];
    int k0 = blockIdx.x * 32, n0 = blockIdx.y * 32;
    int tx = threadIdx.x & 31, ty = threadIdx.x >> 5;
    #pragma unroll
    for (int r = 0; r < 4; r++) {
        int k = k0 + ty + r * 8, n = n0 + tx;
        tile[ty + r * 8][tx] = (k < K && n < N) ? W[(size_t)k * N + n] : 0.f;
    }
    __syncthreads();
    #pragma unroll
    for (int r = 0; r < 4; r++) {
        int n = n0 + ty + r * 8, k = k0 + tx;
        if (n < NP && k < KP)
            Wt[(size_t)n * KP + k] = f2b(tile[tx][ty + r * 8]);
    }
}

// ============ bf16 MFMA GEMM: C = act(A[M,K] @ Bt[N,K]^T + bias) ============
// 128x128 tile, BK=32, 4 waves (2x2 of 64x64), mfma_f32_16x16x32_bf16.
// XCD-aware block swizzle: same-A-row tiles co-resident on one XCD L2.
// LDS chunk-XOR swizzle kills the 8-way ds_read_b128 bank conflict.
// bf16 epilogue staged through LDS for full-row coalesced stores.
// ACT: 0 none, 1 gelu(exact), 2 sigmoid. OF: write f32 Cf. OB: write bf16 Cb.
#define GLL(g, l) __builtin_amdgcn_global_load_lds( \
    (const __attribute__((address_space(1))) void*)(g), \
    (__attribute__((address_space(3))) void*)(l), 16, 0, 0)

template <int ACT, bool OF, bool OB>
__global__ __launch_bounds__(256) void bgemm(const ushort_t* __restrict__ A,
                                             const ushort_t* __restrict__ Bt,
                                             const float* __restrict__ bias,
                                             float* __restrict__ Cf,
                                             ushort_t* __restrict__ Cb,
                                             int Mdim, int Kdim, int Nout) {
    __shared__ ushort_t smem[17408];       // As[4096] | Bs[4096]; epilogue: C-tile [128][CSLD]
    ushort_t* As = smem;
    ushort_t* Bs = smem + 4096;
    const int tid = threadIdx.x;
    const int lane = tid & 63;
    const int wid = tid >> 6;
    int m_t, n_t;
    xcd_tile(gridDim.x, &m_t, &n_t);
    const int m0 = m_t * 128;
    const int n0 = n_t * 128;
    const int wm = wid & 1, wn = wid >> 1;

    f4v acc[4][4];
    #pragma unroll
    for (int i = 0; i < 4; i++)
        #pragma unroll
        for (int j = 0; j < 4; j++)
            acc[i][j] = (f4v){0.f, 0.f, 0.f, 0.f};

    // staging: per wave, 2 instructions for A (16 rows x 32k each) + 2 for B.
    // global k-chunk pre-swizzled so linear LDS holds slot = chunk ^ ((row>>1)&3).
    const int srow = wid * 16 + (lane >> 2);
    const int skq = ((lane & 3) ^ ((lane >> 3) & 3)) * 8;
    int ar0 = m0 + srow;       if (ar0 > Mdim - 1) ar0 = Mdim - 1;
    int ar1 = m0 + 64 + srow;  if (ar1 > Mdim - 1) ar1 = Mdim - 1;
    const ushort_t* gA0 = A + (size_t)ar0 * Kdim + skq;
    const ushort_t* gA1 = A + (size_t)ar1 * Kdim + skq;
    const ushort_t* gB0 = Bt + (size_t)(n0 + srow) * Kdim + skq;
    const ushort_t* gB1 = Bt + (size_t)(n0 + 64 + srow) * Kdim + skq;
    ushort_t* lA0 = As + (wid * 16) * 32;
    ushort_t* lA1 = As + (64 + wid * 16) * 32;
    ushort_t* lB0 = Bs + (wid * 16) * 32;
    ushort_t* lB1 = Bs + (64 + wid * 16) * 32;

    const int lr = lane & 15;
    const int kc = (((lane >> 4) ^ ((lane >> 1) & 3))) * 8;  // swizzled read slot

    for (int k0 = 0; k0 < Kdim; k0 += 32) {
        GLL(gA0 + k0, lA0);
        GLL(gA1 + k0, lA1);
        GLL(gB0 + k0, lB0);
        GLL(gB1 + k0, lB1);
        __syncthreads();
        s8v af[4], bf[4];
        #pragma unroll
        for (int i = 0; i < 4; i++)
            af[i] = *(const s8v*)&As[(wm * 64 + i * 16 + lr) * 32 + kc];
        #pragma unroll
        for (int j = 0; j < 4; j++)
            bf[j] = *(const s8v*)&Bs[(wn * 64 + j * 16 + lr) * 32 + kc];
        #pragma unroll
        for (int i = 0; i < 4; i++)
            #pragma unroll
            for (int j = 0; j < 4; j++)
                acc[i][j] = __builtin_amdgcn_mfma_f32_16x16x32_bf16(af[i], bf[j], acc[i][j], 0, 0, 0);
        __syncthreads();
    }

    // epilogue: C/D layout col=lane&15, row=(lane>>4)*4+reg
    const int orow = (lane >> 4) * 4;
    if (OF) {
        #pragma unroll
        for (int j = 0; j < 4; j++) {
            int col = n0 + wn * 64 + j * 16 + lr;
            bool cok = col < Nout;
            float bb = cok ? bias[col] : 0.f;
            #pragma unroll
            for (int i = 0; i < 4; i++) {
                #pragma unroll
                for (int r = 0; r < 4; r++) {
                    int row = m0 + wm * 64 + i * 16 + orow + r;
                    if (cok && row < Mdim) {
                        float v = acc[i][j][r] + bb;
                        if (ACT == 1) v = 0.5f * v * (1.0f + erff(v * 0.70710678118654752f));
                        if (ACT == 2) v = 1.0f / (1.0f + expf(-v));
                        Cf[(size_t)row * Nout + col] = v;
                    }
                }
            }
        }
    }
    if (OB) {
        // stage bf16 tile in LDS (quadrants disjoint; K-loop's final barrier protects As/Bs)
        #pragma unroll
        for (int j = 0; j < 4; j++) {
            int cl = wn * 64 + j * 16 + lr;
            int gcol = n0 + cl;
            float bb = (gcol < Nout) ? bias[gcol] : 0.f;
            #pragma unroll
            for (int i = 0; i < 4; i++) {
                #pragma unroll
                for (int r = 0; r < 4; r++) {
                    float v = acc[i][j][r] + bb;
                    if (ACT == 1) v = 0.5f * v * (1.0f + erff(v * 0.70710678118654752f));
                    if (ACT == 2) v = 1.0f / (1.0f + expf(-v));
                    smem[(wm * 64 + i * 16 + orow + r) * CSLD + cl] = f2b(v);
                }
            }
        }
        __syncthreads();
        // coalesced copy-out: 16B per lane, 256B contiguous per row
        #pragma unroll
        for (int c = 0; c < 8; c++) {
            int idx = c * 256 + tid;
            int row = idx >> 4, cs = idx & 15;
            int grow = m0 + row, gcol = n0 + cs * 8;
            if (grow < Mdim) {
                if (gcol + 8 <= Nout) {
                    *(s8v*)&Cb[(size_t)grow * Nout + gcol] = *(const s8v*)&smem[row * CSLD + cs * 8];
                } else if (gcol < Nout) {
                    for (int q = 0; q < Nout - gcol; q++)
                        Cb[(size_t)grow * Nout + gcol + q] = smem[row * CSLD + cs * 8 + q];
                }
            }
        }
    }
}

// ============ fused QKV GEMM: [NTOK,512] @ [1536,512]^T -> qkvb [NTOK,1536] bf16 ============
// sections: col<512 Q (sigmoid), <1024 K (sigmoid), else V (none). K=512, N=1536 exact.
__global__ __launch_bounds__(256) void bgemm_qkv(const ushort_t* __restrict__ A,
                                                 const ushort_t* __restrict__ Bt,
                                                 const float* __restrict__ bq_,
                                                 const float* __restrict__ bk_,
                                                 const float* __restrict__ bv_,
                                                 ushort_t* __restrict__ Cb,
                                                 int Mdim) {
    __shared__ ushort_t smem[17408];
    ushort_t* As = smem;
    ushort_t* Bs = smem + 4096;
    const int tid = threadIdx.x;
    const int lane = tid & 63;
    const int wid = tid >> 6;
    int m_t, n_t;
    xcd_tile(gridDim.x, &m_t, &n_t);
    const int m0 = m_t * 128;
    const int n0 = n_t * 128;
    const int wm = wid & 1, wn = wid >> 1;

    f4v acc[4][4];
    #pragma unroll
    for (int i = 0; i < 4; i++)
        #pragma unroll
        for (int j = 0; j < 4; j++)
            acc[i][j] = (f4v){0.f, 0.f, 0.f, 0.f};

    const int srow = wid * 16 + (lane >> 2);
    const int skq = ((lane & 3) ^ ((lane >> 3) & 3)) * 8;
    int ar0 = m0 + srow;       if (ar0 > Mdim - 1) ar0 = Mdim - 1;
    int ar1 = m0 + 64 + srow;  if (ar1 > Mdim - 1) ar1 = Mdim - 1;
    const ushort_t* gA0 = A + (size_t)ar0 * DD + skq;
    const ushort_t* gA1 = A + (size_t)ar1 * DD + skq;
    const ushort_t* gB0 = Bt + (size_t)(n0 + srow) * DD + skq;
    const ushort_t* gB1 = Bt + (size_t)(n0 + 64 + srow) * DD + skq;
    ushort_t* lA0 = As + (wid * 16) * 32;
    ushort_t* lA1 = As + (64 + wid * 16) * 32;
    ushort_t* lB0 = Bs + (wid * 16) * 32;
    ushort_t* lB1 = Bs + (64 + wid * 16) * 32;

    const int lr = lane & 15;
    const int kc = (((lane >> 4) ^ ((lane >> 1) & 3))) * 8;

    for (int k0 = 0; k0 < DD; k0 += 32) {
        GLL(gA0 + k0, lA0);
        GLL(gA1 + k0, lA1);
        GLL(gB0 + k0, lB0);
        GLL(gB1 + k0, lB1);
        __syncthreads();
        s8v af[4], bf[4];
        #pragma unroll
        for (int i = 0; i < 4; i++)
            af[i] = *(const s8v*)&As[(wm * 64 + i * 16 + lr) * 32 + kc];
        #pragma unroll
        for (int j = 0; j < 4; j++)
            bf[j] = *(const s8v*)&Bs[(wn * 64 + j * 16 + lr) * 32 + kc];
        #pragma unroll
        for (int i = 0; i < 4; i++)
            #pragma unroll
            for (int j = 0; j < 4; j++)
                acc[i][j] = __builtin_amdgcn_mfma_f32_16x16x32_bf16(af[i], bf[j], acc[i][j], 0, 0, 0);
        __syncthreads();
    }

    const int orow = (lane >> 4) * 4;
    #pragma unroll
    for (int j = 0; j < 4; j++) {
        int cl = wn * 64 + j * 16 + lr;
        int col = n0 + cl;
        int sec = col >> 9;
        const float* bsel = (sec == 0) ? bq_ : ((sec == 1) ? bk_ : bv_);
        float bb = bsel[col & 511];
        #pragma unroll
        for (int i = 0; i < 4; i++) {
            #pragma unroll
            for (int r = 0; r < 4; r++) {
                float v = acc[i][j][r] + bb;
                if (sec < 2) v = 1.0f / (1.0f + expf(-v));
                smem[(wm * 64 + i * 16 + orow + r) * CSLD + cl] = f2b(v);
            }
        }
    }
    __syncthreads();
    #pragma unroll
    for (int c = 0; c < 8; c++) {
        int idx = c * 256 + tid;
        int row = idx >> 4, cs = idx & 15;
        int grow = m0 + row;
        if (grow < Mdim)
            *(s8v*)&Cb[(size_t)grow * QS + n0 + cs * 8] = *(const s8v*)&smem[row * CSLD + cs * 8];
    }
}

// ============ LayerNorm over D=512: x_f32 = LN(x + res_bf16); also write bf16 copy ============
__global__ __launch_bounds__(256) void ln_kernel(float* __restrict__ x,
                                                 const ushort_t* __restrict__ res,
                                                 const float* __restrict__ w,
                                                 const float* __restrict__ bp,
                                                 ushort_t* __restrict__ xb) {
    size_t base = (size_t)blockIdx.x * DD;
    int tid = threadIdx.x;
    float v0 = x[base + tid];
    float v1 = x[base + tid + 256];
    if (res != nullptr) { v0 += b2f(res[base + tid]); v1 += b2f(res[base + tid + 256]); }
    float s = wave_sum(v0 + v1);
    float s2 = wave_sum(v0 * v0 + v1 * v1);
    __shared__ float a1[4], a2[4];
    if ((tid & 63) == 0) { a1[tid >> 6] = s; a2[tid >> 6] = s2; }
    __syncthreads();
    s = a1[0] + a1[1] + a1[2] + a1[3];
    s2 = a2[0] + a2[1] + a2[2] + a2[3];
    float mu = s * (1.0f / DD);
    float var = s2 * (1.0f / DD) - mu * mu;
    float rs = rsqrtf(var + 1e-5f);
    float o0 = (v0 - mu) * rs * w[tid] + bp[tid];
    float o1 = (v1 - mu) * rs * w[tid + 256] + bp[tid + 256];
    x[base + tid] = o0;
    x[base + tid + 256] = o1;
    xb[base + tid] = f2b(o0);
    xb[base + tid + 256] = f2b(o1);
}

// ============ attention: per (b,h) column sums over l (optionally weighted) ============
// Q/Kp point into qkvb (stride QS). l-split LSPLIT-way: grid (NBH, LSPLIT).
template <bool WEIGHTED>
__global__ __launch_bounds__(256) void attn_sums(const ushort_t* __restrict__ Q,
                                                 const ushort_t* __restrict__ Kp,
                                                 const float* __restrict__ wq,
                                                 const float* __restrict__ wk,
                                                 float* __restrict__ qsumP,
                                                 float* __restrict__ ksumP) {
    int bh = blockIdx.x;
    int sp = blockIdx.y;
    int b = bh >> 3, h = bh & 7;
    int lane = threadIdx.x & 63, g = threadIdx.x >> 6;
    int eo = (lane & 7) * 8;
    int lofs = lane >> 3;
    const size_t base = ((size_t)b * LTOK) * QS + h * 64 + eo;
    float aq[8] = {}, ak[8] = {};
    int lend = sp * LCHUNK + LCHUNK; if (lend > LTOK) lend = LTOK;
    for (int l = sp * LCHUNK + g * 8 + lofs; l < lend; l += 32) {
        s8v q8 = *(const s8v*)&Q[base + (size_t)l * QS];
        s8v k8 = *(const s8v*)&Kp[base + (size_t)l * QS];
        float wqv = 1.f, wkv = 1.f;
        if (WEIGHTED) { wqv = wq[bh * LTOK + l]; wkv = wk[bh * LTOK + l]; }
        #pragma unroll
        for (int j = 0; j < 8; j++) {
            aq[j] += b2f((ushort_t)q8[j]) * wqv;
            ak[j] += b2f((ushort_t)k8[j]) * wkv;
        }
    }
    #pragma unroll
    for (int off = 8; off < 64; off <<= 1) {
        #pragma unroll
        for (int j = 0; j < 8; j++) {
            aq[j] += __shfl_xor(aq[j], off, 64);
            ak[j] += __shfl_xor(ak[j], off, 64);
        }
    }
    __shared__ float sqs[4][64], sks[4][64];
    if (lofs == 0) {
        #pragma unroll
        for (int j = 0; j < 8; j++) { sqs[g][eo + j] = aq[j]; sks[g][eo + j] = ak[j]; }
    }
    __syncthreads();
    if (threadIdx.x < 64) {
        int e = threadIdx.x;
        float fq = sqs[0][e] + sqs[1][e] + sqs[2][e] + sqs[3][e];
        float fk = sks[0][e] + sks[1][e] + sks[2][e] + sks[3][e];
        qsumP[((size_t)sp * NBH + bh) * 64 + e] = fq;
        ksumP[((size_t)sp * NBH + bh) * 64 + e] = fk;
    }
}

// ============ attention: per-l dot with summed vector (sums LSPLIT partials) ============
template <int MODE>
__global__ __launch_bounds__(256) void attn_dots(const ushort_t* __restrict__ Q,
                                                 const ushort_t* __restrict__ Kp,
                                                 const float* __restrict__ Sq,
                                                 const float* __restrict__ Sk,
                                                 float* __restrict__ outq,
                                                 float* __restrict__ outk) {
    int bh = blockIdx.x;
    int b = bh >> 3, h = bh & 7;
    int lane = threadIdx.x & 63, w = threadIdx.x >> 6;
    float sq = 0.f, sk = 0.f;
    #pragma unroll
    for (int sp = 0; sp < LSPLIT; sp++) {
        sq += Sq[((size_t)sp * NBH + bh) * 64 + lane];
        sk += Sk[((size_t)sp * NBH + bh) * 64 + lane];
    }
    sq += 1e-6f; sk += 1e-6f;
    const size_t base = ((size_t)b * LTOK) * QS + h * 64 + lane;
    int l0 = blockIdx.y * 64 + w * 16;
    for (int i = 0; i < 16; i++) {
        int l = l0 + i;
        if (l >= LTOK) break;
        float dq = (b2f(Q[base + (size_t)l * QS]) + 1e-6f) * sq;
        float dk = (b2f(Kp[base + (size_t)l * QS]) + 1e-6f) * sk;
        dq = wave_sum(dq);
        dk = wave_sum(dk);
        if (lane == 0) {
            if (MODE == 0) { outq[bh * LTOK + l] = 1.0f / dq; outk[bh * LTOK + l] = 1.0f / dk; }
            else { outq[bh * LTOK + l] = 1.0f / (1.0f + expf(-dq)); outk[bh * LTOK + l] = dk; }
        }
    }
}

// ============ attention: softmax over s (in place), scaled by Ls ============
__global__ __launch_bounds__(256) void attn_softmax(float* __restrict__ buf) {
    float* p = buf + (size_t)blockIdx.x * LTOK;
    int tid = threadIdx.x;
    __shared__ float red[4];
    float mx = -1e30f;
    for (int l = tid; l < LTOK; l += 256) mx = fmaxf(mx, p[l]);
    #pragma unroll
    for (int off = 32; off; off >>= 1) mx = fmaxf(mx, __shfl_xor(mx, off, 64));
    if ((tid & 63) == 0) red[tid >> 6] = mx;
    __syncthreads();
    mx = fmaxf(fmaxf(red[0], red[1]), fmaxf(red[2], red[3]));
    __syncthreads();
    float s = 0.f;
    for (int l = tid; l < LTOK; l += 256) s += expf(p[l] - mx);
    s = wave_sum(s);
    if ((tid & 63) == 0) red[tid >> 6] = s;
    __syncthreads();
    s = red[0] + red[1] + red[2] + red[3];
    float scale = (float)LTOK / s;
    for (int l = tid; l < LTOK; l += 256) p[l] = expf(p[l] - mx) * scale;
}

// ============ attention: kv[e,d] = sum_s k[s,e] * v[s,d] * ncref[s] ============
// Kp/V point into qkvb (stride QS). s-split: grid (NBH, KVSPLIT).
__global__ __launch_bounds__(256) void attn_kv_part(const ushort_t* __restrict__ Kp,
                                                    const ushort_t* __restrict__ V,
                                                    const float* __restrict__ ncref,
                                                    float* __restrict__ kvpart) {
    int bh = blockIdx.x;
    int sp = blockIdx.y;
    int b = bh >> 3, h = bh & 7;
    int d = threadIdx.x & 63, eg = threadIdx.x >> 6;
    __shared__ float ks[16][64], vs[16][64];
    float acc[16] = {};
    const size_t base = ((size_t)b * LTOK) * QS + h * 64;
    const int s_begin = sp * KVCHUNK;
    int s_end = s_begin + KVCHUNK; if (s_end > LTOK) s_end = LTOK;

    const bool isV = threadIdx.x >= 128;       // wave-uniform split
    const int slot = threadIdx.x & 127;        // 16 rows x 8 vec-slots
    const int srow = slot >> 3;
    const int e0 = (slot & 7) * 8;
    const ushort_t* src = isV ? V : Kp;

    for (int s0 = s_begin; s0 < s_end; s0 += 16) {
        __syncthreads();
        int s = s0 + srow;
        float vals[8] = {};
        if (s < s_end) {
            s8v raw = *(const s8v*)&src[base + (size_t)s * QS + e0];
            float mul = isV ? ncref[bh * LTOK + s] : 1.f;
            #pragma unroll
            for (int j = 0; j < 8; j++) vals[j] = b2f((ushort_t)raw[j]) * mul;
        }
        float (*dst)[64] = isV ? vs : ks;
        #pragma unroll
        for (int j = 0; j < 8; j++) dst[srow][e0 + j] = vals[j];
        __syncthreads();
        int nsi = s_end - s0; if (nsi > 16) nsi = 16;
        for (int si = 0; si < nsi; si++) {
            float vv = vs[si][d];
            #pragma unroll
            for (int i = 0; i < 16; i++) acc[i] += ks[si][eg * 16 + i] * vv;
        }
    }
    #pragma unroll
    for (int i = 0; i < 16; i++)
        kvpart[((size_t)sp * NBH + bh) * 4096 + (eg * 16 + i) * 64 + d] = acc[i];
}

// ============ reduce kv partials -> kvT bf16: kvtb[bh][d][e] = sum_sp part[sp][bh][e*64+d] ============
__global__ __launch_bounds__(256) void kv_reduce(const float* __restrict__ part,
                                                 ushort_t* __restrict__ kvtb) {
    size_t idx = (size_t)blockIdx.x * 256 + threadIdx.x;   // NBH*4096 total, idx = bh*4096 + e*64 + d
    float s = 0.f;
    #pragma unroll
    for (int sp = 0; sp < KVSPLIT; sp++)
        s += part[(size_t)sp * ((size_t)NBH * 4096) + idx];
    size_t bhbase = idx & ~(size_t)4095;
    int e = (int)((idx >> 6) & 63), d = (int)(idx & 63);
    kvtb[bhbase + (size_t)d * 64 + e] = f2b(s);
}

// ============ attention out via MFMA: out[l,d] = (Q[l,:] @ kv[:,d]) * nr[l]*nrref[l] ============
// Q from qkvb (stride QS); out (stride DD) bf16. grid (NBH, 4); 4 waves x 64 rows.
__global__ __launch_bounds__(256) void attn_out_mfma(const ushort_t* __restrict__ Q,
                                                     const ushort_t* __restrict__ kvtb,
                                                     const float* __restrict__ nr,
                                                     const float* __restrict__ nrref,
                                                     ushort_t* __restrict__ out) {
    int bh = blockIdx.x;
    int b = bh >> 3, h = bh & 7;
    const int lane = threadIdx.x & 63;
    const int wid = threadIdx.x >> 6;
    const int m0 = blockIdx.y * 256 + wid * 64;
    const int lr = lane & 15;
    const int kq = (lane >> 4) * 8;
    const size_t qbase = ((size_t)b * LTOK) * QS + h * 64;
    const size_t obase = ((size_t)b * LTOK) * DD + h * 64;

    s8v bf[2][4];
    #pragma unroll
    for (int ks = 0; ks < 2; ks++)
        #pragma unroll
        for (int j = 0; j < 4; j++)
            bf[ks][j] = *(const s8v*)&kvtb[(size_t)bh * 4096 + (size_t)(j * 16 + lr) * 64 + ks * 32 + kq];

    f4v acc[4][4];
    #pragma unroll
    for (int i = 0; i < 4; i++)
        #pragma unroll
        for (int j = 0; j < 4; j++)
            acc[i][j] = (f4v){0.f, 0.f, 0.f, 0.f};

    #pragma unroll
    for (int ks = 0; ks < 2; ks++) {
        #pragma unroll
        for (int i = 0; i < 4; i++) {
            int row = m0 + i * 16 + lr;
            if (row > LTOK - 1) row = LTOK - 1;   // clamp; those rows never written
            s8v af = *(const s8v*)&Q[qbase + (size_t)row * QS + ks * 32 + kq];
            #pragma unroll
            for (int j = 0; j < 4; j++)
                acc[i][j] = __builtin_amdgcn_mfma_f32_16x16x32_bf16(af, bf[ks][j], acc[i][j], 0, 0, 0);
        }
    }

    const int orow = (lane >> 4) * 4;
    #pragma unroll
    for (int i = 0; i < 4; i++) {
        #pragma unroll
        for (int r = 0; r < 4; r++) {
            int l = m0 + i * 16 + orow + r;
            if (l >= LTOK) continue;
            float sc = nr[bh * LTOK + l] * nrref[bh * LTOK + l];
            #pragma unroll
            for (int j = 0; j < 4; j++) {
                int d = j * 16 + lr;
                out[obase + (size_t)l * DD + d] = f2b(acc[i][j][r] * sc);
            }
        }
    }
}

// ============ final: transpose from projb[NTOK,720] bf16, RevIN denorm ============
__global__ __launch_bounds__(256) void final_out(const ushort_t* __restrict__ p,
                                                 const float* __restrict__ mean,
                                                 const float* __restrict__ stdev,
                                                 const float* __restrict__ rw,
                                                 const float* __restrict__ rb,
                                                 float* __restrict__ out) {
    int b = blockIdx.z;
    int c0 = blockIdx.x * 32, t0 = blockIdx.y * 32;
    __shared__ float tile[32][33];
    int tx = threadIdx.x & 31, ty = threadIdx.x >> 5;
    #pragma unroll
    for (int kk = 0; kk < 4; kk++) {
        int c = c0 + ty + kk * 8, t = t0 + tx;
        float v = 0.f;
        if (c < CC && t < TT) v = b2f(p[((size_t)b * LTOK + c) * TT + t]);
        tile[ty + kk * 8][tx] = v;
    }
    __syncthreads();
    #pragma unroll
    for (int kk = 0; kk < 4; kk++) {
        int t = t0 + ty + kk * 8, c = c0 + tx;
        if (c < CC && t < TT) {
            float v = tile[tx][ty + kk * 8];
            v = (v - rb[c]) / (rw[c] + 1e-10f);
            v = v * stdev[b * CC + c] + mean[b * CC + c];
            out[((size_t)b * TT + t) * CC + c] = v;
        }
    }
}

extern "C" void kernel_launch(void* const* d_in, const int* in_sizes, int n_in,
                              void* d_out, int out_size, void* d_ws, size_t ws_size,
                              hipStream_t stream) {
    (void)in_sizes; (void)n_in; (void)out_size; (void)ws_size;
    const float* x_enc   = (const float*)d_in[0];
    const float* x_mark  = (const float*)d_in[1];
    const float* revin_w = (const float*)d_in[4];
    const float* revin_b = (const float*)d_in[5];
    const float* emb_W   = (const float*)d_in[6];
    const float* emb_b   = (const float*)d_in[7];
    const float* Wq = (const float*)d_in[8];
    const float* bq = (const float*)d_in[9];
    const float* Wk = (const float*)d_in[10];
    const float* bk = (const float*)d_in[11];
    const float* Wv = (const float*)d_in[12];
    const float* bv = (const float*)d_in[13];
    const float* Wo = (const float*)d_in[14];
    const float* bo = (const float*)d_in[15];
    const float* ff1_W = (const float*)d_in[16];
    const float* ff1_b = (const float*)d_in[17];
    const float* ff2_W = (const float*)d_in[18];
    const float* ff2_b = (const float*)d_in[19];
    const float* ln1_w = (const float*)d_in[20];
    const float* ln1_b = (const float*)d_in[21];
    const float* ln2_w = (const float*)d_in[22];
    const float* ln2_b = (const float*)d_in[23];
    const float* lnf_w = (const float*)d_in[24];
    const float* lnf_b = (const float*)d_in[25];
    const float* proj_W = (const float*)d_in[26];
    const float* proj_b = (const float*)d_in[27];
    float* out = (float*)d_out;

    // ---- workspace layout (~240 MB) ----
    char* wsb = (char*)d_ws;
    size_t off = 0;
    auto alloc = [&](size_t bytes) {
        off = (off + 63) & ~(size_t)63;
        void* p = wsb + off; off += bytes; return p;
    };
    float* mean  = (float*)alloc((size_t)BB * CC * 4);
    float* stdev = (float*)alloc((size_t)BB * CC * 4);
    float* pS    = (float*)alloc((size_t)TSPL * BB * CC * 4);
    float* pS2   = (float*)alloc((size_t)TSPL * BB * CC * 4);
    float* qsumP  = (float*)alloc((size_t)LSPLIT * NBH * 64 * 4);
    float* ksumP  = (float*)alloc((size_t)LSPLIT * NBH * 64 * 4);
    float* qnsumP = (float*)alloc((size_t)LSPLIT * NBH * 64 * 4);
    float* knsumP = (float*)alloc((size_t)LSPLIT * NBH * 64 * 4);
    float* nr    = (float*)alloc((size_t)NBH * LTOK * 4);
    float* nc    = (float*)alloc((size_t)NBH * LTOK * 4);
    float* nrref = (float*)alloc((size_t)NBH * LTOK * 4);
    float* ncref = (float*)alloc((size_t)NBH * LTOK * 4);
    ushort_t* kvtb = (ushort_t*)alloc((size_t)NBH * 4096 * 2); // reduced kv, transposed [d][e], bf16
    float* x     = (float*)alloc((size_t)NTOK * DD * 4);          // fp32 residual spine
    ushort_t* xb = (ushort_t*)alloc((size_t)NTOK * DD * 2);       // bf16 copy of x
    ushort_t* qkvb = (ushort_t*)alloc((size_t)NTOK * QS * 2);     // fused QKV [NTOK,1536]
    ushort_t* wbuf = (ushort_t*)alloc((size_t)10207232 * 2);      // all bf16 transposed weights
    ushort_t* U  = (ushort_t*)alloc((size_t)NTOK * KPAD * 2);     // union: tokb/ff-chunk/projb/kvpart/ab

    // weight sub-buffers
    ushort_t* embT = wbuf;                          // [512,736]
    ushort_t* qkvT = embT + (size_t)512 * KPAD;     // 3 layers x [1536,512] (q,k,v stacked)
    ushort_t* oT   = qkvT + (size_t)3 * 786432;     // 3 x [512,512]
    ushort_t* f1T  = oT + 3 * 262144;               // 3 x [2048,512]
    ushort_t* f2T  = f1T + (size_t)3 * 1048576;     // 3 x [512,2048]
    ushort_t* pT   = f2T + (size_t)3 * 1048576;     // [768,512]
    ushort_t* tokb  = U;                             // [NTOK, 736]
    ushort_t* ffb   = U;                             // chunk [6912, 2048]
    ushort_t* projb = U;                             // [NTOK, 720]
    float* kvpart   = (float*)U;                     // [KVSPLIT, NBH, 4096] = 33.5MB
    ushort_t* ab    = U;                             // attn output [NTOK,512] (after kvpart dead)
    ushort_t* tmpb  = qkvb;                          // Wo/FF2 output (qkv dead by then)

    dim3 blk(256);
    // ---- weight conversion (transpose to [N,K] bf16) ----
    auto cvt = [&](const float* W, ushort_t* Wt, int K, int N, int KP, int NP) {
        convT<<<dim3((KP + 31) / 32, (NP + 31) / 32), blk, 0, stream>>>(W, Wt, K, N, KP, NP);
    };
    cvt(emb_W, embT, TT, DD, KPAD, DD);
    for (int l = 0; l < 3; l++) {
        ushort_t* lb = qkvT + (size_t)l * 786432;
        cvt(Wq + (size_t)l * DD * DD, lb,          DD, DD, DD, DD);
        cvt(Wk + (size_t)l * DD * DD, lb + 262144, DD, DD, DD, DD);
        cvt(Wv + (size_t)l * DD * DD, lb + 524288, DD, DD, DD, DD);
        cvt(Wo + (size_t)l * DD * DD, oT + (size_t)l * 262144, DD, DD, DD, DD);
        cvt(ff1_W + (size_t)l * DD * FFD, f1T + (size_t)l * 1048576, DD, FFD, DD, FFD);
        cvt(ff2_W + (size_t)l * FFD * DD, f2T + (size_t)l * 1048576, FFD, DD, FFD, DD);
    }
    cvt(proj_W, pT, DD, TT, DD, NPADP);

    // ---- RevIN (t-split) + tokens + embedding ----
    revin_part<<<dim3((CC + 63) / 64, BB, TSPL), blk, 0, stream>>>(x_enc, pS, pS2);
    revin_fin<<<dim3((BB * CC + 255) / 256), blk, 0, stream>>>(pS, pS2, mean, stdev);
    build_tok<<<dim3((LTOK + 31) / 32, (KPAD + 31) / 32, BB), blk, 0, stream>>>(
        x_enc, x_mark, mean, stdev, revin_w, revin_b, tokb);
    const int MT = (NTOK + 127) / 128;   // 217
    bgemm<0, true, true><<<dim3(DD / 128, MT), blk, 0, stream>>>(
        tokb, embT, emb_b, x, xb, NTOK, KPAD, DD);

    int ltiles = (LTOK + 63) / 64;
    for (int l = 0; l < 3; l++) {
        bgemm_qkv<<<dim3(QS / 128, MT), blk, 0, stream>>>(
            xb, qkvT + (size_t)l * 786432, bq + l * DD, bk + l * DD, bv + l * DD,
            qkvb, NTOK);
        attn_sums<false><<<dim3(NBH, LSPLIT), blk, 0, stream>>>(
            qkvb, qkvb + 512, nullptr, nullptr, qsumP, ksumP);
        attn_dots<0><<<dim3(NBH, ltiles), blk, 0, stream>>>(
            qkvb, qkvb + 512, ksumP, qsumP, nr, nc);
        attn_sums<true><<<dim3(NBH, LSPLIT), blk, 0, stream>>>(
            qkvb, qkvb + 512, nr, nc, qnsumP, knsumP);
        attn_dots<1><<<dim3(NBH, ltiles), blk, 0, stream>>>(
            qkvb, qkvb + 512, knsumP, qnsumP, nrref, ncref);
        attn_softmax<<<NBH, blk, 0, stream>>>(ncref);
        attn_kv_part<<<dim3(NBH, KVSPLIT), blk, 0, stream>>>(
            qkvb + 512, qkvb + 1024, ncref, kvpart);
        kv_reduce<<<dim3((NBH * 4096) / 256), blk, 0, stream>>>(kvpart, kvtb);
        attn_out_mfma<<<dim3(NBH, 4), blk, 0, stream>>>(qkvb, kvtb, nr, nrref, ab);
        // Wo: A = attention output (ab), out -> tmpb (qkvb region, dead)
        bgemm<0, false, true><<<dim3(DD / 128, MT), blk, 0, stream>>>(
            ab, oT + (size_t)l * 262144, bo + l * DD, nullptr, tmpb, NTOK, DD, DD);
        ln_kernel<<<NTOK, blk, 0, stream>>>(x, tmpb, ln1_w + l * DD, ln1_b + l * DD, xb);
        // FF chunked over rows (ff activation fits in U)
        for (int t0 = 0; t0 < NTOK / 64; t0 += 108) {
            int nt = NTOK / 64 - t0; if (nt > 108) nt = 108;
            int rs = t0 * 64, mc = nt * 64;
            bgemm<1, false, true><<<dim3(FFD / 128, (mc + 127) / 128), blk, 0, stream>>>(
                xb + (size_t)rs * DD, f1T + (size_t)l * 1048576, ff1_b + l * FFD,
                nullptr, ffb, mc, DD, FFD);
            bgemm<0, false, true><<<dim3(DD / 128, (mc + 127) / 128), blk, 0, stream>>>(
                ffb, f2T + (size_t)l * 1048576, ff2_b + l * DD,
                nullptr, tmpb + (size_t)rs * DD, mc, FFD, DD);
        }
        ln_kernel<<<NTOK, blk, 0, stream>>>(x, tmpb, ln2_w + l * DD, ln2_b + l * DD, xb);
    }
    ln_kernel<<<NTOK, blk, 0, stream>>>(x, nullptr, lnf_w, lnf_b, xb);
    // projection: [NTOK,512] @ [512,768(pad)] -> projb [NTOK,720] bf16
    bgemm<0, false, true><<<dim3(NPADP / 128, MT), blk, 0, stream>>>(
        xb, pT, proj_b, nullptr, projb, NTOK, DD, TT);
    final_out<<<dim3((CC + 31) / 32, (TT + 31) / 32, BB), blk, 0, stream>>>(
        projb, mean, stdev, revin_w, revin_b, out);
}

// Round 7
// 2442.650 us; speedup vs baseline: 1.7346x; 1.1200x over previous
//
#include <hip/hip_runtime.h>
#include <math.h>

// ---- problem constants ----
#define BB 32
#define TT 720
#define CC 862
#define MM 4
#define LTOK 866          // C + M tokens
#define DD 512
#define HH 8
#define EE 64
#define FFD 2048
#define NTOK (BB * LTOK)  // 27712 = 433*64
#define NBH (BB * HH)     // 256
#define KPAD 736          // 720 padded to mult of 32 (embedding K)
#define NPADP 768         // 720 padded to mult of 128 (proj N tiles)
#define LSPLIT 4          // attn_sums l-split
#define LCHUNK 224        // ceil(866/4) rounded to mult of 32
#define KVSPLIT 8         // attn_kv s-split
#define KVCHUNK 112       // ceil(866/8) rounded to mult of 16
#define QS 1536           // fused QKV row stride
#define TSPL 8            // revin t-split
#define TCH 90            // 720 / TSPL
#define CSLD 136          // C-tile LDS row stride (ushorts); 272B = 17x16B aligned

typedef unsigned short ushort_t;
typedef short s8v __attribute__((ext_vector_type(8)));
typedef float f4v __attribute__((ext_vector_type(4)));

__device__ __forceinline__ float wave_sum(float v) {
    #pragma unroll
    for (int off = 32; off; off >>= 1) v += __shfl_xor(v, off, 64);
    return v;
}
__device__ __forceinline__ float b2f(ushort_t u) {
    return __uint_as_float(((unsigned int)u) << 16);
}
__device__ __forceinline__ ushort_t f2b(float f) {
    unsigned int u = __float_as_uint(f);
    u = (u + 0x7FFFu + ((u >> 16) & 1u)) >> 16;
    return (ushort_t)u;
}

// XCD-aware bijective block swizzle (m204): same-m blocks land on one XCD's L2.
__device__ __forceinline__ void xcd_tile(int gx, int* m_t, int* n_t) {
    int nwg = gx * gridDim.y;
    int bid = blockIdx.y * gx + blockIdx.x;
    int xcd = bid & 7;
    int lid = bid >> 3;
    int q = nwg >> 3, r = nwg & 7;
    int wgid = (xcd < r ? xcd * (q + 1) : r * (q + 1) + (xcd - r) * q) + lid;
    *m_t = wgid / gx;
    *n_t = wgid % gx;
}

// ============ RevIN stats stage 1: partial sums over t-chunk ============
__global__ __launch_bounds__(256) void revin_part(const float* __restrict__ x_enc,
                                                  float* __restrict__ pS,
                                                  float* __restrict__ pS2) {
    int b = blockIdx.y, tz = blockIdx.z;
    int c = blockIdx.x * 64 + (threadIdx.x & 63);
    int g = threadIdx.x >> 6;
    float s = 0.f, s2 = 0.f;
    if (c < CC) {
        int t0 = tz * TCH;
        for (int t = t0 + g; t < t0 + TCH; t += 4) {
            float v = x_enc[((size_t)b * TT + t) * CC + c];
            s += v; s2 += v * v;
        }
    }
    __shared__ float ls[4][64], ls2[4][64];
    ls[g][threadIdx.x & 63] = s; ls2[g][threadIdx.x & 63] = s2;
    __syncthreads();
    if (g == 0 && c < CC) {
        int cx = threadIdx.x & 63;
        s = ls[0][cx] + ls[1][cx] + ls[2][cx] + ls[3][cx];
        s2 = ls2[0][cx] + ls2[1][cx] + ls2[2][cx] + ls2[3][cx];
        pS[((size_t)tz * BB + b) * CC + c] = s;
        pS2[((size_t)tz * BB + b) * CC + c] = s2;
    }
}

// ============ RevIN stats stage 2: finalize mean/stdev ============
__global__ __launch_bounds__(256) void revin_fin(const float* __restrict__ pS,
                                                 const float* __restrict__ pS2,
                                                 float* __restrict__ mean,
                                                 float* __restrict__ stdev) {
    int idx = blockIdx.x * 256 + threadIdx.x;
    if (idx >= BB * CC) return;
    float s = 0.f, s2 = 0.f;
    #pragma unroll
    for (int tz = 0; tz < TSPL; tz++) {
        s += pS[(size_t)tz * BB * CC + idx];
        s2 += pS2[(size_t)tz * BB * CC + idx];
    }
    float mu = s / (float)TT;
    float var = s2 / (float)TT - mu * mu;
    mean[idx] = mu;
    stdev[idx] = sqrtf(var + 1e-5f);
}

// ============ build tokb[B,866,736] bf16: normalized channels + marks, K-padded ============
__global__ __launch_bounds__(256) void build_tok(const float* __restrict__ x_enc,
                                                 const float* __restrict__ x_mark,
                                                 const float* __restrict__ mean,
                                                 const float* __restrict__ stdev,
                                                 const float* __restrict__ rw,
                                                 const float* __restrict__ rb,
                                                 ushort_t* __restrict__ tok) {
    int b = blockIdx.z;
    int r0 = blockIdx.x * 32, t0 = blockIdx.y * 32;
    __shared__ float tile[32][33];
    int tx = threadIdx.x & 31, ty = threadIdx.x >> 5;
    #pragma unroll
    for (int kk = 0; kk < 4; kk++) {
        int t = t0 + ty + kk * 8, r = r0 + tx;
        float v = 0.f;
        if (t < TT && r < LTOK) {
            if (r < CC) {
                float xv = x_enc[((size_t)b * TT + t) * CC + r];
                v = (xv - mean[b * CC + r]) / stdev[b * CC + r] * rw[r] + rb[r];
            } else {
                v = x_mark[((size_t)b * TT + t) * MM + (r - CC)];
            }
        }
        tile[ty + kk * 8][tx] = v;
    }
    __syncthreads();
    #pragma unroll
    for (int kk = 0; kk < 4; kk++) {
        int r = r0 + ty + kk * 8, t = t0 + tx;
        if (r < LTOK && t < KPAD)
            tok[((size_t)b * LTOK + r) * KPAD + t] = f2b(tile[tx][ty + kk * 8]);
    }
}

// ============ weight convert+transpose: W[K,N] f32 -> Wt[NP,KP] bf16 (zero-padded) ============
__global__ __launch_bounds__(256) void convT(const float* __restrict__ W,
                                             ushort_t* __restrict__ Wt,
                                             int K, int N, int KP, int NP) {
    __shared__ float tile[32][33];
    int k0 = blockIdx.x * 32, n0 = blockIdx.y * 32;
    int tx = threadIdx.x & 31, ty = threadIdx.x >> 5;
    #pragma unroll
    for (int r = 0; r < 4; r++) {
        int k = k0 + ty + r * 8, n = n0 + tx;
        tile[ty + r * 8][tx] = (k < K && n < N) ? W[(size_t)k * N + n] : 0.f;
    }
    __syncthreads();
    #pragma unroll
    for (int r = 0; r < 4; r++) {
        int n = n0 + ty + r * 8, k = k0 + tx;
        if (n < NP && k < KP)
            Wt[(size_t)n * KP + k] = f2b(tile[tx][ty + r * 8]);
    }
}

// ============ bf16 MFMA GEMM: C = act(A[M,K] @ Bt[N,K]^T + bias) ============
// 128x128 tile, BK=32, 4 waves (2x2 of 64x64), mfma_f32_16x16x32_bf16.
// 2-phase double-buffered K-loop (T3 minimum): STAGE(t+1) issued before this
// tile's ds_read+MFMA, ONE barrier/K-step -- DMA latency hides under compute.
// XCD-aware block swizzle; LDS chunk-XOR swizzle; coalesced bf16 epilogue.
// ACT: 0 none, 1 gelu(exact), 2 sigmoid. OF: write f32 Cf. OB: write bf16 Cb.
#define GLL(g, l) __builtin_amdgcn_global_load_lds( \
    (const __attribute__((address_space(1))) void*)(g), \
    (__attribute__((address_space(3))) void*)(l), 16, 0, 0)

template <int ACT, bool OF, bool OB>
__global__ __launch_bounds__(256) void bgemm(const ushort_t* __restrict__ A,
                                             const ushort_t* __restrict__ Bt,
                                             const float* __restrict__ bias,
                                             float* __restrict__ Cf,
                                             ushort_t* __restrict__ Cb,
                                             int Mdim, int Kdim, int Nout) {
    __shared__ ushort_t smem[17408];  // dbuf A/B: [0,16384); epilogue C-tile [0,17408)
    const int tid = threadIdx.x;
    const int lane = tid & 63;
    const int wid = tid >> 6;
    int m_t, n_t;
    xcd_tile(gridDim.x, &m_t, &n_t);
    const int m0 = m_t * 128;
    const int n0 = n_t * 128;
    const int wm = wid & 1, wn = wid >> 1;

    f4v acc[4][4];
    #pragma unroll
    for (int i = 0; i < 4; i++)
        #pragma unroll
        for (int j = 0; j < 4; j++)
            acc[i][j] = (f4v){0.f, 0.f, 0.f, 0.f};

    // staging: per wave, 2 instructions for A (16 rows x 32k each) + 2 for B.
    // global k-chunk pre-swizzled so linear LDS holds slot = chunk ^ ((row>>1)&3).
    const int srow = wid * 16 + (lane >> 2);
    const int skq = ((lane & 3) ^ ((lane >> 3) & 3)) * 8;
    int ar0 = m0 + srow;       if (ar0 > Mdim - 1) ar0 = Mdim - 1;
    int ar1 = m0 + 64 + srow;  if (ar1 > Mdim - 1) ar1 = Mdim - 1;
    const ushort_t* gA0 = A + (size_t)ar0 * Kdim + skq;
    const ushort_t* gA1 = A + (size_t)ar1 * Kdim + skq;
    const ushort_t* gB0 = Bt + (size_t)(n0 + srow) * Kdim + skq;
    const ushort_t* gB1 = Bt + (size_t)(n0 + 64 + srow) * Kdim + skq;
    const int aoff0 = (wid * 16) * 32;
    const int aoff1 = (64 + wid * 16) * 32;

    const int lr = lane & 15;
    const int kc = (((lane >> 4) ^ ((lane >> 1) & 3))) * 8;  // swizzled read slot

    // buffer layout: buf base boff in {0, 8192}; A at boff, B at boff+4096
    #define STAGE_T(k0v, boffv) do { \
        GLL(gA0 + (k0v), smem + (boffv) + aoff0); \
        GLL(gA1 + (k0v), smem + (boffv) + aoff1); \
        GLL(gB0 + (k0v), smem + (boffv) + 4096 + aoff0); \
        GLL(gB1 + (k0v), smem + (boffv) + 4096 + aoff1); \
    } while (0)

    const int nt = Kdim >> 5;
    STAGE_T(0, 0);
    int boff = 0;
    for (int t = 0; t < nt; ++t) {
        __syncthreads();                       // buf[cur] DMA done; prev reads done
        if (t + 1 < nt) STAGE_T((t + 1) * 32, boff ^ 8192);
        const ushort_t* Asr = smem + boff;
        const ushort_t* Bsr = smem + boff + 4096;
        s8v af[4], bf[4];
        #pragma unroll
        for (int i = 0; i < 4; i++)
            af[i] = *(const s8v*)&Asr[(wm * 64 + i * 16 + lr) * 32 + kc];
        #pragma unroll
        for (int j = 0; j < 4; j++)
            bf[j] = *(const s8v*)&Bsr[(wn * 64 + j * 16 + lr) * 32 + kc];
        #pragma unroll
        for (int i = 0; i < 4; i++)
            #pragma unroll
            for (int j = 0; j < 4; j++)
                acc[i][j] = __builtin_amdgcn_mfma_f32_16x16x32_bf16(af[i], bf[j], acc[i][j], 0, 0, 0);
        boff ^= 8192;
    }
    #undef STAGE_T

    // epilogue: C/D layout col=lane&15, row=(lane>>4)*4+reg
    const int orow = (lane >> 4) * 4;
    if (OF) {
        #pragma unroll
        for (int j = 0; j < 4; j++) {
            int col = n0 + wn * 64 + j * 16 + lr;
            bool cok = col < Nout;
            float bb = cok ? bias[col] : 0.f;
            #pragma unroll
            for (int i = 0; i < 4; i++) {
                #pragma unroll
                for (int r = 0; r < 4; r++) {
                    int row = m0 + wm * 64 + i * 16 + orow + r;
                    if (cok && row < Mdim) {
                        float v = acc[i][j][r] + bb;
                        if (ACT == 1) v = 0.5f * v * (1.0f + erff(v * 0.70710678118654752f));
                        if (ACT == 2) v = 1.0f / (1.0f + expf(-v));
                        Cf[(size_t)row * Nout + col] = v;
                    }
                }
            }
        }
    }
    if (OB) {
        __syncthreads();   // all waves' last-tile ds_reads done before smem reuse
        #pragma unroll
        for (int j = 0; j < 4; j++) {
            int cl = wn * 64 + j * 16 + lr;
            int gcol = n0 + cl;
            float bb = (gcol < Nout) ? bias[gcol] : 0.f;
            #pragma unroll
            for (int i = 0; i < 4; i++) {
                #pragma unroll
                for (int r = 0; r < 4; r++) {
                    float v = acc[i][j][r] + bb;
                    if (ACT == 1) v = 0.5f * v * (1.0f + erff(v * 0.70710678118654752f));
                    if (ACT == 2) v = 1.0f / (1.0f + expf(-v));
                    smem[(wm * 64 + i * 16 + orow + r) * CSLD + cl] = f2b(v);
                }
            }
        }
        __syncthreads();
        // coalesced copy-out: 16B per lane, 256B contiguous per row
        #pragma unroll
        for (int c = 0; c < 8; c++) {
            int idx = c * 256 + tid;
            int row = idx >> 4, cs = idx & 15;
            int grow = m0 + row, gcol = n0 + cs * 8;
            if (grow < Mdim) {
                if (gcol + 8 <= Nout) {
                    *(s8v*)&Cb[(size_t)grow * Nout + gcol] = *(const s8v*)&smem[row * CSLD + cs * 8];
                } else if (gcol < Nout) {
                    for (int q = 0; q < Nout - gcol; q++)
                        Cb[(size_t)grow * Nout + gcol + q] = smem[row * CSLD + cs * 8 + q];
                }
            }
        }
    }
}

// ============ fused QKV GEMM: [NTOK,512] @ [1536,512]^T -> qkvb [NTOK,1536] bf16 ============
// sections: col<512 Q (sigmoid), <1024 K (sigmoid), else V (none). K=512, N=1536 exact.
__global__ __launch_bounds__(256) void bgemm_qkv(const ushort_t* __restrict__ A,
                                                 const ushort_t* __restrict__ Bt,
                                                 const float* __restrict__ bq_,
                                                 const float* __restrict__ bk_,
                                                 const float* __restrict__ bv_,
                                                 ushort_t* __restrict__ Cb,
                                                 int Mdim) {
    __shared__ ushort_t smem[17408];
    const int tid = threadIdx.x;
    const int lane = tid & 63;
    const int wid = tid >> 6;
    int m_t, n_t;
    xcd_tile(gridDim.x, &m_t, &n_t);
    const int m0 = m_t * 128;
    const int n0 = n_t * 128;
    const int wm = wid & 1, wn = wid >> 1;

    f4v acc[4][4];
    #pragma unroll
    for (int i = 0; i < 4; i++)
        #pragma unroll
        for (int j = 0; j < 4; j++)
            acc[i][j] = (f4v){0.f, 0.f, 0.f, 0.f};

    const int srow = wid * 16 + (lane >> 2);
    const int skq = ((lane & 3) ^ ((lane >> 3) & 3)) * 8;
    int ar0 = m0 + srow;       if (ar0 > Mdim - 1) ar0 = Mdim - 1;
    int ar1 = m0 + 64 + srow;  if (ar1 > Mdim - 1) ar1 = Mdim - 1;
    const ushort_t* gA0 = A + (size_t)ar0 * DD + skq;
    const ushort_t* gA1 = A + (size_t)ar1 * DD + skq;
    const ushort_t* gB0 = Bt + (size_t)(n0 + srow) * DD + skq;
    const ushort_t* gB1 = Bt + (size_t)(n0 + 64 + srow) * DD + skq;
    const int aoff0 = (wid * 16) * 32;
    const int aoff1 = (64 + wid * 16) * 32;

    const int lr = lane & 15;
    const int kc = (((lane >> 4) ^ ((lane >> 1) & 3))) * 8;

    #define STAGE_T(k0v, boffv) do { \
        GLL(gA0 + (k0v), smem + (boffv) + aoff0); \
        GLL(gA1 + (k0v), smem + (boffv) + aoff1); \
        GLL(gB0 + (k0v), smem + (boffv) + 4096 + aoff0); \
        GLL(gB1 + (k0v), smem + (boffv) + 4096 + aoff1); \
    } while (0)

    const int nt = DD >> 5;   // 16
    STAGE_T(0, 0);
    int boff = 0;
    for (int t = 0; t < nt; ++t) {
        __syncthreads();
        if (t + 1 < nt) STAGE_T((t + 1) * 32, boff ^ 8192);
        const ushort_t* Asr = smem + boff;
        const ushort_t* Bsr = smem + boff + 4096;
        s8v af[4], bf[4];
        #pragma unroll
        for (int i = 0; i < 4; i++)
            af[i] = *(const s8v*)&Asr[(wm * 64 + i * 16 + lr) * 32 + kc];
        #pragma unroll
        for (int j = 0; j < 4; j++)
            bf[j] = *(const s8v*)&Bsr[(wn * 64 + j * 16 + lr) * 32 + kc];
        #pragma unroll
        for (int i = 0; i < 4; i++)
            #pragma unroll
            for (int j = 0; j < 4; j++)
                acc[i][j] = __builtin_amdgcn_mfma_f32_16x16x32_bf16(af[i], bf[j], acc[i][j], 0, 0, 0);
        boff ^= 8192;
    }
    #undef STAGE_T

    const int orow = (lane >> 4) * 4;
    __syncthreads();   // before smem reuse as C-tile
    #pragma unroll
    for (int j = 0; j < 4; j++) {
        int cl = wn * 64 + j * 16 + lr;
        int col = n0 + cl;
        int sec = col >> 9;
        const float* bsel = (sec == 0) ? bq_ : ((sec == 1) ? bk_ : bv_);
        float bb = bsel[col & 511];
        #pragma unroll
        for (int i = 0; i < 4; i++) {
            #pragma unroll
            for (int r = 0; r < 4; r++) {
                float v = acc[i][j][r] + bb;
                if (sec < 2) v = 1.0f / (1.0f + expf(-v));
                smem[(wm * 64 + i * 16 + orow + r) * CSLD + cl] = f2b(v);
            }
        }
    }
    __syncthreads();
    #pragma unroll
    for (int c = 0; c < 8; c++) {
        int idx = c * 256 + tid;
        int row = idx >> 4, cs = idx & 15;
        int grow = m0 + row;
        if (grow < Mdim)
            *(s8v*)&Cb[(size_t)grow * QS + n0 + cs * 8] = *(const s8v*)&smem[row * CSLD + cs * 8];
    }
}

// ============ LayerNorm over D=512: x_f32 = LN(x + res_bf16); also write bf16 copy ============
__global__ __launch_bounds__(256) void ln_kernel(float* __restrict__ x,
                                                 const ushort_t* __restrict__ res,
                                                 const float* __restrict__ w,
                                                 const float* __restrict__ bp,
                                                 ushort_t* __restrict__ xb) {
    size_t base = (size_t)blockIdx.x * DD;
    int tid = threadIdx.x;
    float v0 = x[base + tid];
    float v1 = x[base + tid + 256];
    if (res != nullptr) { v0 += b2f(res[base + tid]); v1 += b2f(res[base + tid + 256]); }
    float s = wave_sum(v0 + v1);
    float s2 = wave_sum(v0 * v0 + v1 * v1);
    __shared__ float a1[4], a2[4];
    if ((tid & 63) == 0) { a1[tid >> 6] = s; a2[tid >> 6] = s2; }
    __syncthreads();
    s = a1[0] + a1[1] + a1[2] + a1[3];
    s2 = a2[0] + a2[1] + a2[2] + a2[3];
    float mu = s * (1.0f / DD);
    float var = s2 * (1.0f / DD) - mu * mu;
    float rs = rsqrtf(var + 1e-5f);
    float o0 = (v0 - mu) * rs * w[tid] + bp[tid];
    float o1 = (v1 - mu) * rs * w[tid + 256] + bp[tid + 256];
    x[base + tid] = o0;
    x[base + tid + 256] = o1;
    xb[base + tid] = f2b(o0);
    xb[base + tid + 256] = f2b(o1);
}

// ============ attention: per (b,h) column sums over l (optionally weighted) ============
// Q/Kp point into qkvb (stride QS). l-split LSPLIT-way: grid (NBH, LSPLIT).
template <bool WEIGHTED>
__global__ __launch_bounds__(256) void attn_sums(const ushort_t* __restrict__ Q,
                                                 const ushort_t* __restrict__ Kp,
                                                 const float* __restrict__ wq,
                                                 const float* __restrict__ wk,
                                                 float* __restrict__ qsumP,
                                                 float* __restrict__ ksumP) {
    int bh = blockIdx.x;
    int sp = blockIdx.y;
    int b = bh >> 3, h = bh & 7;
    int lane = threadIdx.x & 63, g = threadIdx.x >> 6;
    int eo = (lane & 7) * 8;
    int lofs = lane >> 3;
    const size_t base = ((size_t)b * LTOK) * QS + h * 64 + eo;
    float aq[8] = {}, ak[8] = {};
    int lend = sp * LCHUNK + LCHUNK; if (lend > LTOK) lend = LTOK;
    for (int l = sp * LCHUNK + g * 8 + lofs; l < lend; l += 32) {
        s8v q8 = *(const s8v*)&Q[base + (size_t)l * QS];
        s8v k8 = *(const s8v*)&Kp[base + (size_t)l * QS];
        float wqv = 1.f, wkv = 1.f;
        if (WEIGHTED) { wqv = wq[bh * LTOK + l]; wkv = wk[bh * LTOK + l]; }
        #pragma unroll
        for (int j = 0; j < 8; j++) {
            aq[j] += b2f((ushort_t)q8[j]) * wqv;
            ak[j] += b2f((ushort_t)k8[j]) * wkv;
        }
    }
    #pragma unroll
    for (int off = 8; off < 64; off <<= 1) {
        #pragma unroll
        for (int j = 0; j < 8; j++) {
            aq[j] += __shfl_xor(aq[j], off, 64);
            ak[j] += __shfl_xor(ak[j], off, 64);
        }
    }
    __shared__ float sqs[4][64], sks[4][64];
    if (lofs == 0) {
        #pragma unroll
        for (int j = 0; j < 8; j++) { sqs[g][eo + j] = aq[j]; sks[g][eo + j] = ak[j]; }
    }
    __syncthreads();
    if (threadIdx.x < 64) {
        int e = threadIdx.x;
        float fq = sqs[0][e] + sqs[1][e] + sqs[2][e] + sqs[3][e];
        float fk = sks[0][e] + sks[1][e] + sks[2][e] + sks[3][e];
        qsumP[((size_t)sp * NBH + bh) * 64 + e] = fq;
        ksumP[((size_t)sp * NBH + bh) * 64 + e] = fk;
    }
}

// ============ attention: per-l dot with summed vector (sums LSPLIT partials) ============
template <int MODE>
__global__ __launch_bounds__(256) void attn_dots(const ushort_t* __restrict__ Q,
                                                 const ushort_t* __restrict__ Kp,
                                                 const float* __restrict__ Sq,
                                                 const float* __restrict__ Sk,
                                                 float* __restrict__ outq,
                                                 float* __restrict__ outk) {
    int bh = blockIdx.x;
    int b = bh >> 3, h = bh & 7;
    int lane = threadIdx.x & 63, w = threadIdx.x >> 6;
    float sq = 0.f, sk = 0.f;
    #pragma unroll
    for (int sp = 0; sp < LSPLIT; sp++) {
        sq += Sq[((size_t)sp * NBH + bh) * 64 + lane];
        sk += Sk[((size_t)sp * NBH + bh) * 64 + lane];
    }
    sq += 1e-6f; sk += 1e-6f;
    const size_t base = ((size_t)b * LTOK) * QS + h * 64 + lane;
    int l0 = blockIdx.y * 64 + w * 16;
    for (int i = 0; i < 16; i++) {
        int l = l0 + i;
        if (l >= LTOK) break;
        float dq = (b2f(Q[base + (size_t)l * QS]) + 1e-6f) * sq;
        float dk = (b2f(Kp[base + (size_t)l * QS]) + 1e-6f) * sk;
        dq = wave_sum(dq);
        dk = wave_sum(dk);
        if (lane == 0) {
            if (MODE == 0) { outq[bh * LTOK + l] = 1.0f / dq; outk[bh * LTOK + l] = 1.0f / dk; }
            else { outq[bh * LTOK + l] = 1.0f / (1.0f + expf(-dq)); outk[bh * LTOK + l] = dk; }
        }
    }
}

// ============ attention: softmax over s (in place), scaled by Ls ============
__global__ __launch_bounds__(256) void attn_softmax(float* __restrict__ buf) {
    float* p = buf + (size_t)blockIdx.x * LTOK;
    int tid = threadIdx.x;
    __shared__ float red[4];
    float mx = -1e30f;
    for (int l = tid; l < LTOK; l += 256) mx = fmaxf(mx, p[l]);
    #pragma unroll
    for (int off = 32; off; off >>= 1) mx = fmaxf(mx, __shfl_xor(mx, off, 64));
    if ((tid & 63) == 0) red[tid >> 6] = mx;
    __syncthreads();
    mx = fmaxf(fmaxf(red[0], red[1]), fmaxf(red[2], red[3]));
    __syncthreads();
    float s = 0.f;
    for (int l = tid; l < LTOK; l += 256) s += expf(p[l] - mx);
    s = wave_sum(s);
    if ((tid & 63) == 0) red[tid >> 6] = s;
    __syncthreads();
    s = red[0] + red[1] + red[2] + red[3];
    float scale = (float)LTOK / s;
    for (int l = tid; l < LTOK; l += 256) p[l] = expf(p[l] - mx) * scale;
}

// ============ attention: kv[e,d] = sum_s k[s,e] * v[s,d] * ncref[s] ============
// Kp/V point into qkvb (stride QS). s-split: grid (NBH, KVSPLIT).
__global__ __launch_bounds__(256) void attn_kv_part(const ushort_t* __restrict__ Kp,
                                                    const ushort_t* __restrict__ V,
                                                    const float* __restrict__ ncref,
                                                    float* __restrict__ kvpart) {
    int bh = blockIdx.x;
    int sp = blockIdx.y;
    int b = bh >> 3, h = bh & 7;
    int d = threadIdx.x & 63, eg = threadIdx.x >> 6;
    __shared__ float ks[16][64], vs[16][64];
    float acc[16] = {};
    const size_t base = ((size_t)b * LTOK) * QS + h * 64;
    const int s_begin = sp * KVCHUNK;
    int s_end = s_begin + KVCHUNK; if (s_end > LTOK) s_end = LTOK;

    const bool isV = threadIdx.x >= 128;       // wave-uniform split
    const int slot = threadIdx.x & 127;        // 16 rows x 8 vec-slots
    const int srow = slot >> 3;
    const int e0 = (slot & 7) * 8;
    const ushort_t* src = isV ? V : Kp;

    for (int s0 = s_begin; s0 < s_end; s0 += 16) {
        __syncthreads();
        int s = s0 + srow;
        float vals[8] = {};
        if (s < s_end) {
            s8v raw = *(const s8v*)&src[base + (size_t)s * QS + e0];
            float mul = isV ? ncref[bh * LTOK + s] : 1.f;
            #pragma unroll
            for (int j = 0; j < 8; j++) vals[j] = b2f((ushort_t)raw[j]) * mul;
        }
        float (*dst)[64] = isV ? vs : ks;
        #pragma unroll
        for (int j = 0; j < 8; j++) dst[srow][e0 + j] = vals[j];
        __syncthreads();
        int nsi = s_end - s0; if (nsi > 16) nsi = 16;
        for (int si = 0; si < nsi; si++) {
            float vv = vs[si][d];
            #pragma unroll
            for (int i = 0; i < 16; i++) acc[i] += ks[si][eg * 16 + i] * vv;
        }
    }
    #pragma unroll
    for (int i = 0; i < 16; i++)
        kvpart[((size_t)sp * NBH + bh) * 4096 + (eg * 16 + i) * 64 + d] = acc[i];
}

// ============ reduce kv partials -> kvT bf16: kvtb[bh][d][e] = sum_sp part[sp][bh][e*64+d] ============
__global__ __launch_bounds__(256) void kv_reduce(const float* __restrict__ part,
                                                 ushort_t* __restrict__ kvtb) {
    size_t idx = (size_t)blockIdx.x * 256 + threadIdx.x;   // NBH*4096 total, idx = bh*4096 + e*64 + d
    float s = 0.f;
    #pragma unroll
    for (int sp = 0; sp < KVSPLIT; sp++)
        s += part[(size_t)sp * ((size_t)NBH * 4096) + idx];
    size_t bhbase = idx & ~(size_t)4095;
    int e = (int)((idx >> 6) & 63), d = (int)(idx & 63);
    kvtb[bhbase + (size_t)d * 64 + e] = f2b(s);
}

// ============ attention out via MFMA: out[l,d] = (Q[l,:] @ kv[:,d]) * nr[l]*nrref[l] ============
// Q from qkvb (stride QS); out (stride DD) bf16. grid (NBH, 4); 4 waves x 64 rows.
__global__ __launch_bounds__(256) void attn_out_mfma(const ushort_t* __restrict__ Q,
                                                     const ushort_t* __restrict__ kvtb,
                                                     const float* __restrict__ nr,
                                                     const float* __restrict__ nrref,
                                                     ushort_t* __restrict__ out) {
    int bh = blockIdx.x;
    int b = bh >> 3, h = bh & 7;
    const int lane = threadIdx.x & 63;
    const int wid = threadIdx.x >> 6;
    const int m0 = blockIdx.y * 256 + wid * 64;
    const int lr = lane & 15;
    const int kq = (lane >> 4) * 8;
    const size_t qbase = ((size_t)b * LTOK) * QS + h * 64;
    const size_t obase = ((size_t)b * LTOK) * DD + h * 64;

    s8v bf[2][4];
    #pragma unroll
    for (int ks = 0; ks < 2; ks++)
        #pragma unroll
        for (int j = 0; j < 4; j++)
            bf[ks][j] = *(const s8v*)&kvtb[(size_t)bh * 4096 + (size_t)(j * 16 + lr) * 64 + ks * 32 + kq];

    f4v acc[4][4];
    #pragma unroll
    for (int i = 0; i < 4; i++)
        #pragma unroll
        for (int j = 0; j < 4; j++)
            acc[i][j] = (f4v){0.f, 0.f, 0.f, 0.f};

    #pragma unroll
    for (int ks = 0; ks < 2; ks++) {
        #pragma unroll
        for (int i = 0; i < 4; i++) {
            int row = m0 + i * 16 + lr;
            if (row > LTOK - 1) row = LTOK - 1;   // clamp; those rows never written
            s8v af = *(const s8v*)&Q[qbase + (size_t)row * QS + ks * 32 + kq];
            #pragma unroll
            for (int j = 0; j < 4; j++)
                acc[i][j] = __builtin_amdgcn_mfma_f32_16x16x32_bf16(af, bf[ks][j], acc[i][j], 0, 0, 0);
        }
    }

    const int orow = (lane >> 4) * 4;
    #pragma unroll
    for (int i = 0; i < 4; i++) {
        #pragma unroll
        for (int r = 0; r < 4; r++) {
            int l = m0 + i * 16 + orow + r;
            if (l >= LTOK) continue;
            float sc = nr[bh * LTOK + l] * nrref[bh * LTOK + l];
            #pragma unroll
            for (int j = 0; j < 4; j++) {
                int d = j * 16 + lr;
                out[obase + (size_t)l * DD + d] = f2b(acc[i][j][r] * sc);
            }
        }
    }
}

// ============ final: transpose from projb[NTOK,720] bf16, RevIN denorm ============
__global__ __launch_bounds__(256) void final_out(const ushort_t* __restrict__ p,
                                                 const float* __restrict__ mean,
                                                 const float* __restrict__ stdev,
                                                 const float* __restrict__ rw,
                                                 const float* __restrict__ rb,
                                                 float* __restrict__ out) {
    int b = blockIdx.z;
    int c0 = blockIdx.x * 32, t0 = blockIdx.y * 32;
    __shared__ float tile[32][33];
    int tx = threadIdx.x & 31, ty = threadIdx.x >> 5;
    #pragma unroll
    for (int kk = 0; kk < 4; kk++) {
        int c = c0 + ty + kk * 8, t = t0 + tx;
        float v = 0.f;
        if (c < CC && t < TT) v = b2f(p[((size_t)b * LTOK + c) * TT + t]);
        tile[ty + kk * 8][tx] = v;
    }
    __syncthreads();
    #pragma unroll
    for (int kk = 0; kk < 4; kk++) {
        int t = t0 + ty + kk * 8, c = c0 + tx;
        if (c < CC && t < TT) {
            float v = tile[tx][ty + kk * 8];
            v = (v - rb[c]) / (rw[c] + 1e-10f);
            v = v * stdev[b * CC + c] + mean[b * CC + c];
            out[((size_t)b * TT + t) * CC + c] = v;
        }
    }
}

extern "C" void kernel_launch(void* const* d_in, const int* in_sizes, int n_in,
                              void* d_out, int out_size, void* d_ws, size_t ws_size,
                              hipStream_t stream) {
    (void)in_sizes; (void)n_in; (void)out_size; (void)ws_size;
    const float* x_enc   = (const float*)d_in[0];
    const float* x_mark  = (const float*)d_in[1];
    const float* revin_w = (const float*)d_in[4];
    const float* revin_b = (const float*)d_in[5];
    const float* emb_W   = (const float*)d_in[6];
    const float* emb_b   = (const float*)d_in[7];
    const float* Wq = (const float*)d_in[8];
    const float* bq = (const float*)d_in[9];
    const float* Wk = (const float*)d_in[10];
    const float* bk = (const float*)d_in[11];
    const float* Wv = (const float*)d_in[12];
    const float* bv = (const float*)d_in[13];
    const float* Wo = (const float*)d_in[14];
    const float* bo = (const float*)d_in[15];
    const float* ff1_W = (const float*)d_in[16];
    const float* ff1_b = (const float*)d_in[17];
    const float* ff2_W = (const float*)d_in[18];
    const float* ff2_b = (const float*)d_in[19];
    const float* ln1_w = (const float*)d_in[20];
    const float* ln1_b = (const float*)d_in[21];
    const float* ln2_w = (const float*)d_in[22];
    const float* ln2_b = (const float*)d_in[23];
    const float* lnf_w = (const float*)d_in[24];
    const float* lnf_b = (const float*)d_in[25];
    const float* proj_W = (const float*)d_in[26];
    const float* proj_b = (const float*)d_in[27];
    float* out = (float*)d_out;

    // ---- workspace layout (~240 MB) ----
    char* wsb = (char*)d_ws;
    size_t off = 0;
    auto alloc = [&](size_t bytes) {
        off = (off + 63) & ~(size_t)63;
        void* p = wsb + off; off += bytes; return p;
    };
    float* mean  = (float*)alloc((size_t)BB * CC * 4);
    float* stdev = (float*)alloc((size_t)BB * CC * 4);
    float* pS    = (float*)alloc((size_t)TSPL * BB * CC * 4);
    float* pS2   = (float*)alloc((size_t)TSPL * BB * CC * 4);
    float* qsumP  = (float*)alloc((size_t)LSPLIT * NBH * 64 * 4);
    float* ksumP  = (float*)alloc((size_t)LSPLIT * NBH * 64 * 4);
    float* qnsumP = (float*)alloc((size_t)LSPLIT * NBH * 64 * 4);
    float* knsumP = (float*)alloc((size_t)LSPLIT * NBH * 64 * 4);
    float* nr    = (float*)alloc((size_t)NBH * LTOK * 4);
    float* nc    = (float*)alloc((size_t)NBH * LTOK * 4);
    float* nrref = (float*)alloc((size_t)NBH * LTOK * 4);
    float* ncref = (float*)alloc((size_t)NBH * LTOK * 4);
    ushort_t* kvtb = (ushort_t*)alloc((size_t)NBH * 4096 * 2); // reduced kv, transposed [d][e], bf16
    float* x     = (float*)alloc((size_t)NTOK * DD * 4);          // fp32 residual spine
    ushort_t* xb = (ushort_t*)alloc((size_t)NTOK * DD * 2);       // bf16 copy of x
    ushort_t* qkvb = (ushort_t*)alloc((size_t)NTOK * QS * 2);     // fused QKV [NTOK,1536]
    ushort_t* wbuf = (ushort_t*)alloc((size_t)10207232 * 2);      // all bf16 transposed weights
    ushort_t* U  = (ushort_t*)alloc((size_t)NTOK * KPAD * 2);     // union: tokb/ff-chunk/projb/kvpart/ab

    // weight sub-buffers
    ushort_t* embT = wbuf;                          // [512,736]
    ushort_t* qkvT = embT + (size_t)512 * KPAD;     // 3 layers x [1536,512] (q,k,v stacked)
    ushort_t* oT   = qkvT + (size_t)3 * 786432;     // 3 x [512,512]
    ushort_t* f1T  = oT + 3 * 262144;               // 3 x [2048,512]
    ushort_t* f2T  = f1T + (size_t)3 * 1048576;     // 3 x [512,2048]
    ushort_t* pT   = f2T + (size_t)3 * 1048576;     // [768,512]
    ushort_t* tokb  = U;                             // [NTOK, 736]
    ushort_t* ffb   = U;                             // chunk [6912, 2048]
    ushort_t* projb = U;                             // [NTOK, 720]
    float* kvpart   = (float*)U;                     // [KVSPLIT, NBH, 4096] = 33.5MB
    ushort_t* ab    = U;                             // attn output [NTOK,512] (after kvpart dead)
    ushort_t* tmpb  = qkvb;                          // Wo/FF2 output (qkv dead by then)

    dim3 blk(256);
    // ---- weight conversion (transpose to [N,K] bf16) ----
    auto cvt = [&](const float* W, ushort_t* Wt, int K, int N, int KP, int NP) {
        convT<<<dim3((KP + 31) / 32, (NP + 31) / 32), blk, 0, stream>>>(W, Wt, K, N, KP, NP);
    };
    cvt(emb_W, embT, TT, DD, KPAD, DD);
    for (int l = 0; l < 3; l++) {
        ushort_t* lb = qkvT + (size_t)l * 786432;
        cvt(Wq + (size_t)l * DD * DD, lb,          DD, DD, DD, DD);
        cvt(Wk + (size_t)l * DD * DD, lb + 262144, DD, DD, DD, DD);
        cvt(Wv + (size_t)l * DD * DD, lb + 524288, DD, DD, DD, DD);
        cvt(Wo + (size_t)l * DD * DD, oT + (size_t)l * 262144, DD, DD, DD, DD);
        cvt(ff1_W + (size_t)l * DD * FFD, f1T + (size_t)l * 1048576, DD, FFD, DD, FFD);
        cvt(ff2_W + (size_t)l * FFD * DD, f2T + (size_t)l * 1048576, FFD, DD, FFD, DD);
    }
    cvt(proj_W, pT, DD, TT, DD, NPADP);

    // ---- RevIN (t-split) + tokens + embedding ----
    revin_part<<<dim3((CC + 63) / 64, BB, TSPL), blk, 0, stream>>>(x_enc, pS, pS2);
    revin_fin<<<dim3((BB * CC + 255) / 256), blk, 0, stream>>>(pS, pS2, mean, stdev);
    build_tok<<<dim3((LTOK + 31) / 32, (KPAD + 31) / 32, BB), blk, 0, stream>>>(
        x_enc, x_mark, mean, stdev, revin_w, revin_b, tokb);
    const int MT = (NTOK + 127) / 128;   // 217
    bgemm<0, true, true><<<dim3(DD / 128, MT), blk, 0, stream>>>(
        tokb, embT, emb_b, x, xb, NTOK, KPAD, DD);

    int ltiles = (LTOK + 63) / 64;
    for (int l = 0; l < 3; l++) {
        bgemm_qkv<<<dim3(QS / 128, MT), blk, 0, stream>>>(
            xb, qkvT + (size_t)l * 786432, bq + l * DD, bk + l * DD, bv + l * DD,
            qkvb, NTOK);
        attn_sums<false><<<dim3(NBH, LSPLIT), blk, 0, stream>>>(
            qkvb, qkvb + 512, nullptr, nullptr, qsumP, ksumP);
        attn_dots<0><<<dim3(NBH, ltiles), blk, 0, stream>>>(
            qkvb, qkvb + 512, ksumP, qsumP, nr, nc);
        attn_sums<true><<<dim3(NBH, LSPLIT), blk, 0, stream>>>(
            qkvb, qkvb + 512, nr, nc, qnsumP, knsumP);
        attn_dots<1><<<dim3(NBH, ltiles), blk, 0, stream>>>(
            qkvb, qkvb + 512, knsumP, qnsumP, nrref, ncref);
        attn_softmax<<<NBH, blk, 0, stream>>>(ncref);
        attn_kv_part<<<dim3(NBH, KVSPLIT), blk, 0, stream>>>(
            qkvb + 512, qkvb + 1024, ncref, kvpart);
        kv_reduce<<<dim3((NBH * 4096) / 256), blk, 0, stream>>>(kvpart, kvtb);
        attn_out_mfma<<<dim3(NBH, 4), blk, 0, stream>>>(qkvb, kvtb, nr, nrref, ab);
        // Wo: A = attention output (ab), out -> tmpb (qkvb region, dead)
        bgemm<0, false, true><<<dim3(DD / 128, MT), blk, 0, stream>>>(
            ab, oT + (size_t)l * 262144, bo + l * DD, nullptr, tmpb, NTOK, DD, DD);
        ln_kernel<<<NTOK, blk, 0, stream>>>(x, tmpb, ln1_w + l * DD, ln1_b + l * DD, xb);
        // FF chunked over rows (ff activation fits in U)
        for (int t0 = 0; t0 < NTOK / 64; t0 += 108) {
            int nt = NTOK / 64 - t0; if (nt > 108) nt = 108;
            int rs = t0 * 64, mc = nt * 64;
            bgemm<1, false, true><<<dim3(FFD / 128, (mc + 127) / 128), blk, 0, stream>>>(
                xb + (size_t)rs * DD, f1T + (size_t)l * 1048576, ff1_b + l * FFD,
                nullptr, ffb, mc, DD, FFD);
            bgemm<0, false, true><<<dim3(DD / 128, (mc + 127) / 128), blk, 0, stream>>>(
                ffb, f2T + (size_t)l * 1048576, ff2_b + l * DD,
                nullptr, tmpb + (size_t)rs * DD, mc, FFD, DD);
        }
        ln_kernel<<<NTOK, blk, 0, stream>>>(x, tmpb, ln2_w + l * DD, ln2_b + l * DD, xb);
    }
    ln_kernel<<<NTOK, blk, 0, stream>>>(x, nullptr, lnf_w, lnf_b, xb);
    // projection: [NTOK,512] @ [512,768(pad)] -> projb [NTOK,720] bf16
    bgemm<0, false, true><<<dim3(NPADP / 128, MT), blk, 0, stream>>>(
        xb, pT, proj_b, nullptr, projb, NTOK, DD, TT);
    final_out<<<dim3((CC + 31) / 32, (TT + 31) / 32, BB), blk, 0, stream>>>(
        projb, mean, stdev, revin_w, revin_b, out);
}